// Round 21
// baseline (860.445 us; speedup 1.0000x reference)
//
#include <hip/hip_runtime.h>
#include <hip/hip_bf16.h>
#include <math.h>

#define NN 131072
#define EE 524288
#define GG 4096
#define GCAP 640
#define ACAP 96

typedef __attribute__((ext_vector_type(8))) _Float16 half8;
typedef __attribute__((ext_vector_type(4))) _Float16 half4;
typedef __attribute__((ext_vector_type(4))) float f32x4;

__device__ __forceinline__ float sigmoidf_(float x){ return 1.0f/(1.0f+expf(-x)); }

// ---- grouping / CSR (integer atomics only) --------------------------------
__global__ void k_gptr(const int* batch, int* gptr){
  int g = blockIdx.x*256+threadIdx.x;
  if (g > GG) return;
  if (g == GG){ gptr[GG]=NN; return; }
  int lo=0, hi=NN;
  while(lo<hi){ int mid=(lo+hi)>>1; if(batch[mid]<g) lo=mid+1; else hi=mid; }
  gptr[g]=lo;
}

__global__ void k_deg(const int* dst, int* deg){
  int e = blockIdx.x*256+threadIdx.x;
  if(e<EE) atomicAdd(&deg[dst[e]], 1);
}

// hierarchical scan
__global__ __launch_bounds__(256) void k_scan_part(const int* deg, int* part){
  __shared__ int red[256];
  int b=blockIdx.x, t=threadIdx.x;
  red[t] = deg[b*256+t];
  __syncthreads();
  for(int off=128; off>0; off>>=1){
    if(t<off) red[t]+=red[t+off];
    __syncthreads();
  }
  if(t==0) part[b]=red[0];
}

__global__ __launch_bounds__(512) void k_scan_top(int* part){
  __shared__ int s[512];
  int t=threadIdx.x;
  s[t]=part[t];
  __syncthreads();
  for(int off=1; off<512; off<<=1){
    int v=s[t];
    int add=(t>=off)?s[t-off]:0;
    __syncthreads();
    s[t]=v+add;
    __syncthreads();
  }
  part[t] = (t==0)?0:s[t-1];
}

__global__ __launch_bounds__(256) void k_scan_apply(const int* deg, const int* part, int* rowptr){
  __shared__ int s[256];
  int b=blockIdx.x, t=threadIdx.x;
  int v0=deg[b*256+t];
  s[t]=v0;
  __syncthreads();
  for(int off=1; off<256; off<<=1){
    int v=s[t];
    int add=(t>=off)?s[t-off]:0;
    __syncthreads();
    s[t]=v+add;
    __syncthreads();
  }
  rowptr[b*256+t] = part[b] + s[t]-v0;
  if(b==511 && t==255) rowptr[NN] = part[b] + s[t];
}

// fill CSR-ordered edge streams (ea copy vectorized float2)
__global__ void k_fill(const int* dst, const int* src, const float* ea,
                       const int* rowptr, int* cursor, int* srcord, float* eaord){
  int e = blockIdx.x*256+threadIdx.x;
  if(e>=EE) return;
  int d = dst[e];
  int pos = atomicAdd(&cursor[d], 1);
  int idx = rowptr[d]+pos;
  srcord[idx] = src[e];
  float2 e0 = *(const float2*)&ea[(size_t)e*6];
  float2 e1 = *(const float2*)&ea[(size_t)e*6+2];
  float2 e2 = *(const float2*)&ea[(size_t)e*6+4];
  *(float2*)&eaord[(size_t)idx*6]   = e0;
  *(float2*)&eaord[(size_t)idx*6+2] = e1;
  *(float2*)&eaord[(size_t)idx*6+4] = e2;
}

// ---- per-layer Wf/bf precompute (1 block): Wf=W3@eW [64][6], bf=W3@eb+prb -
__global__ __launch_bounds__(448) void k_prepwf(const float* preW, const float* preb,
      const float* eW, const float* eb, float* WfG, float* bfG){
  int t=threadIdx.x;
  if(t<384){
    int j=t/6, d=t-j*6;
    float a=0.0f;
    for(int k=0;k<64;k++) a += preW[(size_t)j*192+128+k]*eW[k*6+d];
    WfG[t]=a;
  } else if(t<448){
    int j=t-384;
    float a=preb[j];
    for(int k=0;k<64;k++) a += preW[(size_t)j*192+128+k]*eb[k];
    bfG[j]=a;
  }
}

// ---- y0 = x @ lin1W.T + b (pre-activation, fp16); padded sW (bank-free) ---
__global__ __launch_bounds__(256) void k_lin1_s(const float* x, const float* W, const float* b, _Float16* y0){
  __shared__ float sW[2112];   // 64*33 padded
  __shared__ float sb[64];
  int t=threadIdx.x;
  for(int i=t;i<2048;i+=256){ int j=i>>5,k=i&31; sW[j*33+k]=W[i]; }
  if(t<64) sb[t]=b[t];
  __syncthreads();
  int n = blockIdx.x*4 + (t>>6);
  int j = t&63;
  float acc = sb[j];
  for(int k=0;k<32;k++) acc += x[n*32+k]*sW[j*33+k];
  y0[(size_t)n*64+j] = (_Float16)acc;
}

// ---- k_bnmsg: hy := relu(hy*sc+sh) in place; g12 = h @ [Wd|Ws].T (MFMA) ---
__global__ __launch_bounds__(256) void k_bnmsg(_Float16* hy, const float* sc, const float* sh,
      const float* preW, _Float16* g12){
  __shared__ _Float16 sAh[64][72];
  __shared__ _Float16 sB0[64][72];
  __shared__ _Float16 sB1[64][72];
  __shared__ float ssc[64], ssh[64];
  int t=threadIdx.x;
  int rb = blockIdx.x*64;
  if(t<64){ ssc[t] = sc? sc[t] : 1.0f; ssh[t] = sh? sh[t] : 0.0f; }
  __syncthreads();
  int sr = t>>2, c0 = (t&3)*16;
  {
    half8 y0 = *(const half8*)&hy[(size_t)(rb+sr)*64 + c0];
    half8 y1 = *(const half8*)&hy[(size_t)(rb+sr)*64 + c0 + 8];
    half8 h0, h1;
    #pragma unroll
    for(int q=0;q<8;q++){
      h0[q] = (_Float16)fmaxf((float)y0[q]*ssc[c0+q]   + ssh[c0+q],   0.0f);
      h1[q] = (_Float16)fmaxf((float)y1[q]*ssc[c0+8+q] + ssh[c0+8+q], 0.0f);
    }
    *(half8*)&sAh[sr][c0]   = h0;
    *(half8*)&sAh[sr][c0+8] = h1;
    *(half8*)&hy[(size_t)(rb+sr)*64 + c0]     = h0;
    *(half8*)&hy[(size_t)(rb+sr)*64 + c0 + 8] = h1;
    const float* w0 = &preW[(size_t)sr*192 + c0];
    const float* w1 = &preW[(size_t)sr*192 + 64 + c0];
    float4 a0=*(const float4*)&w0[0], a1=*(const float4*)&w0[4], a2=*(const float4*)&w0[8], a3=*(const float4*)&w0[12];
    float4 b0=*(const float4*)&w1[0], b1=*(const float4*)&w1[4], b2=*(const float4*)&w1[8], b3=*(const float4*)&w1[12];
    half8 w0h, w0h2, w1h, w1h2;
    float wa[16]={a0.x,a0.y,a0.z,a0.w,a1.x,a1.y,a1.z,a1.w,a2.x,a2.y,a2.z,a2.w,a3.x,a3.y,a3.z,a3.w};
    float wb[16]={b0.x,b0.y,b0.z,b0.w,b1.x,b1.y,b1.z,b1.w,b2.x,b2.y,b2.z,b2.w,b3.x,b3.y,b3.z,b3.w};
    #pragma unroll
    for(int q=0;q<8;q++){ w0h[q]=(_Float16)wa[q]; w0h2[q]=(_Float16)wa[8+q]; w1h[q]=(_Float16)wb[q]; w1h2[q]=(_Float16)wb[8+q]; }
    *(half8*)&sB0[sr][c0]   = w0h;  *(half8*)&sB0[sr][c0+8] = w0h2;
    *(half8*)&sB1[sr][c0]   = w1h;  *(half8*)&sB1[sr][c0+8] = w1h2;
  }
  __syncthreads();
  int w=t>>6, l=t&63;
  f32x4 acc0[4]={}, acc1[4]={};
  #pragma unroll
  for(int kk=0; kk<2; ++kk){
    half8 a = *(const half8*)&sAh[w*16+(l&15)][kk*32+(l>>4)*8];
    #pragma unroll
    for(int n16=0;n16<4;++n16){
      half8 b0 = *(const half8*)&sB0[n16*16+(l&15)][kk*32+(l>>4)*8];
      half8 b1 = *(const half8*)&sB1[n16*16+(l&15)][kk*32+(l>>4)*8];
      acc0[n16] = __builtin_amdgcn_mfma_f32_16x16x32_f16(a,b0,acc0[n16],0,0,0);
      acc1[n16] = __builtin_amdgcn_mfma_f32_16x16x32_f16(a,b1,acc1[n16],0,0,0);
    }
  }
  #pragma unroll
  for(int n16=0;n16<4;++n16){
    #pragma unroll
    for(int reg=0; reg<4; ++reg){
      int row = w*16+(l>>4)*4+reg;
      int col = n16*16+(l&15);
      g12[(size_t)(rb+row)*128 + col]      = (_Float16)acc0[n16][reg];
      g12[(size_t)(rb+row)*128 + 64 + col] = (_Float16)acc1[n16][reg];
    }
  }
}

// ---- gather: 64 contiguous nodes/block; edges prefetched; Wf/bf from global
__global__ __launch_bounds__(256) void k_gather_f(const int* rowptr, const int* srcord,
      const float* eaord, const _Float16* g12, const float* WfG, const float* bfG,
      _Float16* agg, float* s12, float avgdl){
  __shared__ float sWf[64][6];
  __shared__ float sbf[64];
  __shared__ int   sRow[65];
  __shared__ int   sSrc[GCAP];
  __shared__ float sEA[GCAP*6];
  int t=threadIdx.x;
  int rb = blockIdx.x*64;
  for(int i=t; i<384; i+=256) ((float*)sWf)[i]=WfG[i];
  if(t<64) sbf[t]=bfG[t];
  if(t<65) sRow[t]=rowptr[rb+t];
  __syncthreads();
  int eLo = sRow[0];
  int cnt = sRow[64]-eLo;
  int ccap = (cnt<GCAP)? cnt : GCAP;
  for(int i=t; i<ccap; i+=256) sSrc[i]=srcord[eLo+i];
  for(int f=t; f<ccap*6; f+=256) sEA[f]=eaord[(size_t)eLo*6+f];
  __syncthreads();
  int w=t>>6, j=t&63;
  float wf0=sWf[j][0], wf1=sWf[j][1], wf2=sWf[j][2];
  float wf3=sWf[j][3], wf4=sWf[j][4], wf5=sWf[j][5];
  float bfj=sbf[j];
  for(int q=0; q<16; ++q){
    int ln = w*16 + q;
    int n  = rb + ln;
    int lo = sRow[ln], hi = sRow[ln+1];
    float mdst = (float)g12[(size_t)n*128+j] + bfj;
    float sum=0.0f, sq=0.0f, mn=1e30f, mx=-1e30f;
    int idx=lo;
    for(; idx+1<hi; idx+=2){
      int r0 = idx-eLo, r1 = r0+1;
      int s0, s1;
      float e00,e01,e02,e03,e04,e05, e10,e11,e12,e13,e14,e15;
      if(r1 < GCAP){
        s0=sSrc[r0]; s1=sSrc[r1];
        e00=sEA[r0*6+0]; e01=sEA[r0*6+1]; e02=sEA[r0*6+2]; e03=sEA[r0*6+3]; e04=sEA[r0*6+4]; e05=sEA[r0*6+5];
        e10=sEA[r1*6+0]; e11=sEA[r1*6+1]; e12=sEA[r1*6+2]; e13=sEA[r1*6+3]; e14=sEA[r1*6+4]; e15=sEA[r1*6+5];
      } else {
        s0=srcord[idx]; s1=srcord[idx+1];
        e00=eaord[(size_t)idx*6+0]; e01=eaord[(size_t)idx*6+1]; e02=eaord[(size_t)idx*6+2];
        e03=eaord[(size_t)idx*6+3]; e04=eaord[(size_t)idx*6+4]; e05=eaord[(size_t)idx*6+5];
        e10=eaord[(size_t)(idx+1)*6+0]; e11=eaord[(size_t)(idx+1)*6+1]; e12=eaord[(size_t)(idx+1)*6+2];
        e13=eaord[(size_t)(idx+1)*6+3]; e14=eaord[(size_t)(idx+1)*6+4]; e15=eaord[(size_t)(idx+1)*6+5];
      }
      float g0 = (float)g12[(size_t)s0*128+64+j];
      float g1 = (float)g12[(size_t)s1*128+64+j];
      float m0 = mdst + g0 + e00*wf0 + e01*wf1 + e02*wf2 + e03*wf3 + e04*wf4 + e05*wf5;
      float m1 = mdst + g1 + e10*wf0 + e11*wf1 + e12*wf2 + e13*wf3 + e14*wf4 + e15*wf5;
      sum += m0; sq += m0*m0; mn = fminf(mn,m0); mx = fmaxf(mx,m0);
      sum += m1; sq += m1*m1; mn = fminf(mn,m1); mx = fmaxf(mx,m1);
    }
    if(idx<hi){
      int r0 = idx-eLo;
      int s0; float e00,e01,e02,e03,e04,e05;
      if(r0 < GCAP){
        s0=sSrc[r0];
        e00=sEA[r0*6+0]; e01=sEA[r0*6+1]; e02=sEA[r0*6+2]; e03=sEA[r0*6+3]; e04=sEA[r0*6+4]; e05=sEA[r0*6+5];
      } else {
        s0=srcord[idx];
        e00=eaord[(size_t)idx*6+0]; e01=eaord[(size_t)idx*6+1]; e02=eaord[(size_t)idx*6+2];
        e03=eaord[(size_t)idx*6+3]; e04=eaord[(size_t)idx*6+4]; e05=eaord[(size_t)idx*6+5];
      }
      float g0 = (float)g12[(size_t)s0*128+64+j];
      float m0 = mdst + g0 + e00*wf0 + e01*wf1 + e02*wf2 + e03*wf3 + e04*wf4 + e05*wf5;
      sum += m0; sq += m0*m0; mn = fminf(mn,m0); mx = fmaxf(mx,m0);
    }
    int c = hi-lo;
    float cm = fmaxf((float)c, 1.0f);
    float mean = sum/cm;
    float sd = sqrtf(fmaxf(sq/cm - mean*mean, 0.0f)+1e-5f);
    bool has = c>0;
    size_t base = (size_t)n*256;
    agg[base+j]     = (_Float16)mean;
    agg[base+64+j]  = (_Float16)(has?mn:0.0f);
    agg[base+128+j] = (_Float16)(has?mx:0.0f);
    agg[base+192+j] = (_Float16)sd;
    if(j==0){ float ld=logf(cm+1.0f); s12[n*2]=ld/avgdl; s12[n*2+1]=avgdl/ld; }
  }
}

// ---- k_tower_mfma v2: z-split (agg staged once/k-tile; s1,s2 in epilogue) -
__global__ __launch_bounds__(256) void k_tower_mfma(_Float16* hy, const _Float16* agg, const float* s12,
        const float* poW, const float* pob, const float* clW, const float* clb, float* part){
  __shared__ _Float16 sAh[64][72];
  __shared__ _Float16 sBh[64][72];
  __shared__ float sS[128];
  __shared__ float sredS[16][64];
  __shared__ float sredQ[16][64];
  int t = threadIdx.x;
  int rb = blockIdx.x*64;
  int w = t>>6, l = t&63;
  int sr = t>>2, c0 = (t&3)*16;
  if (t < 128) sS[t] = s12[(size_t)(rb+(t>>1))*2 + (t&1)];
  f32x4 hacc[4]={}, z0a[4]={}, z1a[4]={}, z2a[4]={};
  auto stageB = [&](const float* wr){
    float4 a0=*(const float4*)&wr[0], a1=*(const float4*)&wr[4], a2=*(const float4*)&wr[8], a3=*(const float4*)&wr[12];
    float wa[16]={a0.x,a0.y,a0.z,a0.w,a1.x,a1.y,a1.z,a1.w,a2.x,a2.y,a2.z,a2.w,a3.x,a3.y,a3.z,a3.w};
    half8 b0, b1;
    #pragma unroll
    for(int q=0;q<8;q++){ b0[q]=(_Float16)wa[q]; b1[q]=(_Float16)wa[8+q]; }
    *(half8*)&sBh[sr][c0]   = b0;
    *(half8*)&sBh[sr][c0+8] = b1;
  };
  auto mfma8 = [&](f32x4* acc){
    #pragma unroll
    for (int kk=0; kk<2; ++kk){
      half8 a = *(const half8*)&sAh[w*16 + (l&15)][kk*32 + (l>>4)*8];
      #pragma unroll
      for (int n16=0; n16<4; ++n16){
        half8 b = *(const half8*)&sBh[n16*16 + (l&15)][kk*32 + (l>>4)*8];
        acc[n16] = __builtin_amdgcn_mfma_f32_16x16x32_f16(a, b, acc[n16], 0, 0, 0);
      }
    }
  };
  {
    *(half8*)&sAh[sr][c0]   = *(const half8*)&hy[(size_t)(rb+sr)*64 + c0];
    *(half8*)&sAh[sr][c0+8] = *(const half8*)&hy[(size_t)(rb+sr)*64 + c0 + 8];
    stageB(&poW[(size_t)sr*832 + c0]);
  }
  __syncthreads();
  mfma8(hacc);
  for (int kt=0; kt<4; ++kt){
    __syncthreads();
    *(half8*)&sAh[sr][c0]   = *(const half8*)&agg[(size_t)(rb+sr)*256 + kt*64 + c0];
    *(half8*)&sAh[sr][c0+8] = *(const half8*)&agg[(size_t)(rb+sr)*256 + kt*64 + c0 + 8];
    stageB(&poW[(size_t)sr*832 + 64 + kt*64 + c0]);
    __syncthreads();
    mfma8(z0a);
    __syncthreads();
    stageB(&poW[(size_t)sr*832 + 64 + 256 + kt*64 + c0]);
    __syncthreads();
    mfma8(z1a);
    __syncthreads();
    stageB(&poW[(size_t)sr*832 + 64 + 512 + kt*64 + c0]);
    __syncthreads();
    mfma8(z2a);
  }
  __syncthreads();
  #pragma unroll
  for (int n16=0; n16<4; ++n16){
    #pragma unroll
    for (int reg=0; reg<4; ++reg){
      int row = w*16 + (l>>4)*4 + reg;
      int col = n16*16 + (l&15);
      float s1v = sS[row*2], s2v = sS[row*2+1];
      float v = hacc[n16][reg] + z0a[n16][reg] + s1v*z1a[n16][reg] + s2v*z2a[n16][reg] + pob[col];
      sAh[row][col] = (_Float16)v;
    }
  }
  stageB(&clW[(size_t)sr*64 + c0]);
  __syncthreads();
  f32x4 cacc[4] = {};
  mfma8(cacc);
  float cs_[4], cq_[4];
  #pragma unroll
  for (int n16=0; n16<4; ++n16){ cs_[n16]=0.0f; cq_[n16]=0.0f; }
  #pragma unroll
  for (int n16=0; n16<4; ++n16){
    #pragma unroll
    for (int reg=0; reg<4; ++reg){
      int row = w*16 + (l>>4)*4 + reg;
      int col = n16*16 + (l&15);
      float v = cacc[n16][reg] + clb[col];
      hy[(size_t)(rb+row)*64 + col] = (_Float16)v;
      cs_[n16] += v; cq_[n16] += v*v;
    }
  }
  int slot = w*4 + (l>>4);
  #pragma unroll
  for (int n16=0; n16<4; ++n16){
    int col = n16*16 + (l&15);
    sredS[slot][col] = cs_[n16];
    sredQ[slot][col] = cq_[n16];
  }
  __syncthreads();
  if (t < 64){
    float S=0.0f, Q=0.0f;
    #pragma unroll
    for(int q2=0;q2<16;q2++){ S += sredS[q2][t]; Q += sredQ[q2][t]; }
    part[(size_t)blockIdx.x*128 + t]      = S;
    part[(size_t)blockIdx.x*128 + 64 + t] = Q;
  }
}

// ---- BN finalize: hierarchical (1024 thr = 64 cols x 16 chunks) -----------
__global__ __launch_bounds__(1024) void k_bnfin(const float* part, const float* g, const float* bb,
                                                float* sc, float* sh){
  __shared__ double sS[16][64], sQ[16][64];
  int t = threadIdx.x;
  int c = t&63, chunk = t>>6;
  double S=0.0, Q=0.0;
  for(int b=chunk; b<2048; b+=16){
    S += (double)part[(size_t)b*128 + c];
    Q += (double)part[(size_t)b*128 + 64 + c];
  }
  sS[chunk][c]=S; sQ[chunk][c]=Q;
  __syncthreads();
  if(t<64){
    double St=0.0, Qt=0.0;
    #pragma unroll
    for(int q=0;q<16;q++){ St+=sS[q][t]; Qt+=sQ[q][t]; }
    double mean = St/(double)NN;
    double var  = Qt/(double)NN - mean*mean;
    float scale = g[t] * (float)(1.0/sqrt(var+1e-5));
    sc[t]=scale;
    sh[t]=bb[t] - (float)mean*scale;
  }
}

// ---- final BN apply in place on hy (fp16) ---------------------------------
__global__ void k_bnapply16(_Float16* hy, const float* sc, const float* sh){
  int idx = blockIdx.x*256+threadIdx.x;
  for(int i=idx; i<NN*8; i+=256*2048){
    int c0 = (i&7)*8;
    half8 v = *(const half8*)&hy[(size_t)i*8];
    half8 r;
    #pragma unroll
    for(int q=0;q<8;q++) r[q]=(_Float16)fmaxf((float)v[q]*sc[c0+q]+sh[c0+q],0.0f);
    *(half8*)&hy[(size_t)i*8] = r;
  }
}

// ---- set2set LSTM: 8 graphs/block, float4 weights reused x8, 8 acc chains -
__global__ __launch_bounds__(256) void k_lstm_lit(float* A, float* cs,
      const float* Wih, const float* Whh, const float* bih, const float* bhh){
  __shared__ float sA[8][128];
  __shared__ float sg[8][256];
  int t=threadIdx.x;
  int g0 = blockIdx.x*8;
  for(int i=t;i<1024;i+=256) sA[i>>7][i&127] = A[(size_t)(g0+(i>>7))*128 + (i&127)];
  __syncthreads();
  float bb2 = bih[t]+bhh[t];
  float acc[8];
  #pragma unroll
  for(int g=0;g<8;g++) acc[g]=bb2;
  for(int k=0;k<128;k+=4){
    float4 wv = *(const float4*)&Wih[(size_t)t*128+k];
    #pragma unroll
    for(int g=0;g<8;g++)
      acc[g] += wv.x*sA[g][k] + wv.y*sA[g][k+1] + wv.z*sA[g][k+2] + wv.w*sA[g][k+3];
  }
  for(int k=0;k<64;k+=4){
    float4 wv = *(const float4*)&Whh[(size_t)t*64+k];
    #pragma unroll
    for(int g=0;g<8;g++)
      acc[g] += wv.x*sA[g][k] + wv.y*sA[g][k+1] + wv.z*sA[g][k+2] + wv.w*sA[g][k+3];
  }
  #pragma unroll
  for(int g=0;g<8;g++) sg[g][t]=acc[g];
  __syncthreads();
  for(int i=t;i<512;i+=256){
    int g=i>>6, j=i&63;
    float ig=sg[g][j], fg=sg[g][64+j], gg=sg[g][128+j], og=sg[g][192+j];
    float c = sigmoidf_(fg)*cs[(size_t)(g0+g)*64+j] + sigmoidf_(ig)*tanhf(gg);
    float hv = sigmoidf_(og)*tanhf(c);
    cs[(size_t)(g0+g)*64+j]=c;
    A[(size_t)(g0+g)*128+j]=hv;
  }
}

// ---- fused edot+attn: one wave per graph; h rows + e cached in LDS --------
__global__ __launch_bounds__(64) void k_attn_f(const _Float16* h16, const int* gptr, float* A){
  __shared__ _Float16 sH[ACAP][64];
  __shared__ float sE[ACAP];
  int g=blockIdx.x, j=threadIdx.x;
  int lo=gptr[g], hi=gptr[g+1];
  int cnt=hi-lo;
  if(cnt<=0){ A[(size_t)g*128+64+j]=0.0f; return; }
  float aq = A[(size_t)g*128+j];
  if(cnt<=ACAP){
    for(int i=0;i<cnt;++i){
      _Float16 hv = h16[(size_t)(lo+i)*64+j];
      sH[i][j]=hv;
      float v=(float)hv*aq;
      #pragma unroll
      for(int m=32;m;m>>=1) v+=__shfl_xor(v,m,64);
      if(j==0) sE[i]=v;
    }
    float mx=-1e30f;
    for(int i=j;i<cnt;i+=64) mx=fmaxf(mx,sE[i]);
    #pragma unroll
    for(int m=32;m;m>>=1) mx=fmaxf(mx,__shfl_xor(mx,m,64));
    float s=0.0f;
    for(int i=j;i<cnt;i+=64) s+=expf(sE[i]-mx);
    #pragma unroll
    for(int m=32;m;m>>=1) s+=__shfl_xor(s,m,64);
    float inv=1.0f/(s+1e-16f);
    float r=0.0f;
    for(int i=0;i<cnt;++i){
      float a=expf(sE[i]-mx)*inv;
      r+=a*(float)sH[i][j];
    }
    A[(size_t)g*128+64+j]=r;
  } else {
    // fallback (statistically unreachable): recompute e per pass
    float mx=-1e30f;
    for(int n=lo;n<hi;++n){
      float v=(float)h16[(size_t)n*64+j]*aq;
      #pragma unroll
      for(int m=32;m;m>>=1) v+=__shfl_xor(v,m,64);
      mx=fmaxf(mx,v);
    }
    float s=0.0f;
    for(int n=lo;n<hi;++n){
      float v=(float)h16[(size_t)n*64+j]*aq;
      #pragma unroll
      for(int m=32;m;m>>=1) v+=__shfl_xor(v,m,64);
      s+=expf(v-mx);
    }
    float inv=1.0f/(s+1e-16f);
    float r=0.0f;
    for(int n=lo;n<hi;++n){
      float v=(float)h16[(size_t)n*64+j]*aq;
      #pragma unroll
      for(int m=32;m;m>>=1) v+=__shfl_xor(v,m,64);
      r+=expf(v-mx)*inv*(float)h16[(size_t)n*64+j];
    }
    A[(size_t)g*128+64+j]=r;
  }
}

__global__ __launch_bounds__(64) void k_mlp(const float* A, const float* tt, const float* pp,
     const float* W1,const float* b1,const float* W2,const float* b2,const float* W3,const float* b3,
     float* out){
  __shared__ float si[130]; __shared__ float o1[64]; __shared__ float o2[32];
  int g=blockIdx.x, t=threadIdx.x;
  si[t]=A[g*128+t]; si[64+t]=A[g*128+64+t];
  if(t==0){ si[128]=tt[g]; si[129]=pp[g]; }
  __syncthreads();
  float a=b1[t];
  for(int k=0;k<130;k++) a+=W1[t*130+k]*si[k];
  o1[t]=fmaxf(a,0.0f);
  __syncthreads();
  if(t<32){
    float a2=b2[t];
    #pragma unroll 4
    for(int k=0;k<64;k++) a2+=W2[t*64+k]*o1[k];
    o2[t]=fmaxf(a2,0.0f);
  }
  __syncthreads();
  float v = (t<32)? o2[t]*W3[t] : 0.0f;
  #pragma unroll
  for(int m=32;m;m>>=1) v+=__shfl_xor(v,m,64);
  if(t==0) out[g]=v+b3[0];
}

// ---- host -----------------------------------------------------------------
extern "C" void kernel_launch(void* const* d_in, const int* in_sizes, int n_in,
                              void* d_out, int out_size, void* d_ws, size_t ws_size,
                              hipStream_t stream) {
  static const int want[28] = {4194304,3145728,4096,4096,2048,64,1152,192,36864,192,
                               159744,192,12288,192,192,192,32768,16384,256,256,
                               8320,64,2048,32,32,1,1048576,131072};
  if (n_in != 28 || out_size != GG) return;
  for (int i=0;i<28;i++) if (in_sizes[i] != want[i]) return;

  const float* x     = (const float*)d_in[0];
  const float* ea    = (const float*)d_in[1];
  const float* tt    = (const float*)d_in[2];
  const float* pp    = (const float*)d_in[3];
  const float* lin1W = (const float*)d_in[4];
  const float* lin1b = (const float*)d_in[5];
  const float* edgeW = (const float*)d_in[6];
  const float* edgeb = (const float*)d_in[7];
  const float* preW  = (const float*)d_in[8];
  const float* preb  = (const float*)d_in[9];
  const float* postW = (const float*)d_in[10];
  const float* postb = (const float*)d_in[11];
  const float* clinW = (const float*)d_in[12];
  const float* clinb = (const float*)d_in[13];
  const float* bng   = (const float*)d_in[14];
  const float* bnb   = (const float*)d_in[15];
  const float* Wih   = (const float*)d_in[16];
  const float* Whh   = (const float*)d_in[17];
  const float* bih   = (const float*)d_in[18];
  const float* bhh   = (const float*)d_in[19];
  const float* W1    = (const float*)d_in[20];
  const float* b1    = (const float*)d_in[21];
  const float* W2    = (const float*)d_in[22];
  const float* b2    = (const float*)d_in[23];
  const float* W3    = (const float*)d_in[24];
  const float* b3    = (const float*)d_in[25];
  const int*   eidx  = (const int*)d_in[26];
  const int*   batch = (const int*)d_in[27];
  const int* esrc = eidx;
  const int* edst = eidx + EE;

  char* w = (char*)d_ws;
  auto alloc = [&](size_t bytes)->char*{ char* p=w; w += ((bytes+255)/256)*256; return p; };
  _Float16* agg  = (_Float16*)alloc((size_t)NN*256*2);  // 64MiB fp16
  _Float16* g12  = (_Float16*)alloc((size_t)NN*128*2);  // 32MiB fp16 (set2set scratch aliases)
  _Float16* hy   = (_Float16*)alloc((size_t)NN*64*2);   // 16MiB fp16: y2/h in place
  int*   deg    = (int*)alloc((size_t)NN*4);
  int*   cursor = (int*)alloc((size_t)NN*4);
  int*   rowptr = (int*)alloc((size_t)(NN+1)*4);
  int*   spart  = (int*)alloc(512*4);
  int*   srcord = (int*)alloc((size_t)EE*4);
  float* eaord  = (float*)alloc((size_t)EE*6*4);
  float* s12   = (float*)alloc((size_t)NN*2*4);
  float* part  = (float*)alloc((size_t)2048*128*4);
  float* bnsc  = (float*)alloc(256);
  float* bnsh  = (float*)alloc(256);
  float* WfG   = (float*)alloc(384*4);
  float* bfG   = (float*)alloc(64*4);
  int*   gptr  = (int*)alloc((GG+1)*4);
  size_t need = (size_t)(w - (char*)d_ws);
  if (need > ws_size) return;
  float* A    = (float*)g12;
  float* cs   = (float*)g12 + (size_t)GG*128;

  double num = 13107.0*log(2.0)+26214.0*log(3.0)+65536.0*log(4.0)+26215.0*log(5.0);
  float avgdl = (float)(num/131072.0);

  hipMemsetAsync(deg, 0, (size_t)NN*4, stream);
  hipMemsetAsync(cursor, 0, (size_t)NN*4, stream);
  hipLaunchKernelGGL(k_deg, dim3(2048), dim3(256), 0, stream, edst, deg);
  hipLaunchKernelGGL(k_scan_part, dim3(512), dim3(256), 0, stream, deg, spart);
  hipLaunchKernelGGL(k_scan_top, dim3(1), dim3(512), 0, stream, spart);
  hipLaunchKernelGGL(k_scan_apply, dim3(512), dim3(256), 0, stream, deg, spart, rowptr);
  hipLaunchKernelGGL(k_fill, dim3(2048), dim3(256), 0, stream, edst, esrc, ea, rowptr, cursor, srcord, eaord);

  hipLaunchKernelGGL(k_gptr, dim3(17), dim3(256), 0, stream, batch, gptr);
  hipLaunchKernelGGL(k_lin1_s, dim3(32768), dim3(256), 0, stream, x, lin1W, lin1b, hy);

  for (int i = 0; i < 3; ++i){
    const float* sc_i = (i==0)? nullptr : bnsc;
    const float* sh_i = (i==0)? nullptr : bnsh;
    hipLaunchKernelGGL(k_prepwf, dim3(1), dim3(448), 0, stream,
        preW + (size_t)i*64*192, preb + i*64, edgeW + (size_t)i*384, edgeb + i*64, WfG, bfG);
    hipLaunchKernelGGL(k_bnmsg, dim3(2048), dim3(256), 0, stream, hy, sc_i, sh_i,
        preW + (size_t)i*64*192, g12);
    hipLaunchKernelGGL(k_gather_f, dim3(2048), dim3(256), 0, stream, rowptr, srcord, eaord, g12,
        WfG, bfG, agg, s12, avgdl);
    hipLaunchKernelGGL(k_tower_mfma, dim3(2048), dim3(256), 0, stream, hy, agg, s12,
        postW + (size_t)i*64*832, postb + i*64, clinW + (size_t)i*4096, clinb + i*64, part);
    hipLaunchKernelGGL(k_bnfin, dim3(1), dim3(1024), 0, stream, part, bng + i*64, bnb + i*64, bnsc, bnsh);
  }
  hipLaunchKernelGGL(k_bnapply16, dim3(2048), dim3(256), 0, stream, hy, bnsc, bnsh);

  hipMemsetAsync(A, 0, (size_t)GG*128*4, stream);
  hipMemsetAsync(cs, 0, (size_t)GG*64*4, stream);
  for (int s = 0; s < 3; ++s){
    hipLaunchKernelGGL(k_lstm_lit, dim3(512), dim3(256), 0, stream, A, cs, Wih, Whh, bih, bhh);
    hipLaunchKernelGGL(k_attn_f, dim3(GG), dim3(64), 0, stream, hy, gptr, A);
  }
  hipLaunchKernelGGL(k_mlp, dim3(GG), dim3(64), 0, stream, A, tt, pp, W1, b1, W2, b2, W3, b3, (float*)d_out);
}

// Round 22
// 774.356 us; speedup vs baseline: 1.1112x; 1.1112x over previous
//
#include <hip/hip_runtime.h>
#include <hip/hip_bf16.h>
#include <math.h>

#define NN 131072
#define EE 524288
#define GG 4096
#define GCAP 640
#define ACAP 96

typedef __attribute__((ext_vector_type(8))) _Float16 half8;
typedef __attribute__((ext_vector_type(4))) _Float16 half4;
typedef __attribute__((ext_vector_type(4))) float f32x4;

__device__ __forceinline__ float sigmoidf_(float x){ return 1.0f/(1.0f+expf(-x)); }

// ---- grouping / CSR (integer atomics only) --------------------------------
__global__ void k_gptr(const int* batch, int* gptr){
  int g = blockIdx.x*256+threadIdx.x;
  if (g > GG) return;
  if (g == GG){ gptr[GG]=NN; return; }
  int lo=0, hi=NN;
  while(lo<hi){ int mid=(lo+hi)>>1; if(batch[mid]<g) lo=mid+1; else hi=mid; }
  gptr[g]=lo;
}

__global__ void k_deg(const int* dst, int* deg){
  int e = blockIdx.x*256+threadIdx.x;
  if(e<EE) atomicAdd(&deg[dst[e]], 1);
}

// hierarchical scan
__global__ __launch_bounds__(256) void k_scan_part(const int* deg, int* part){
  __shared__ int red[256];
  int b=blockIdx.x, t=threadIdx.x;
  red[t] = deg[b*256+t];
  __syncthreads();
  for(int off=128; off>0; off>>=1){
    if(t<off) red[t]+=red[t+off];
    __syncthreads();
  }
  if(t==0) part[b]=red[0];
}

__global__ __launch_bounds__(512) void k_scan_top(int* part){
  __shared__ int s[512];
  int t=threadIdx.x;
  s[t]=part[t];
  __syncthreads();
  for(int off=1; off<512; off<<=1){
    int v=s[t];
    int add=(t>=off)?s[t-off]:0;
    __syncthreads();
    s[t]=v+add;
    __syncthreads();
  }
  part[t] = (t==0)?0:s[t-1];
}

__global__ __launch_bounds__(256) void k_scan_apply(const int* deg, const int* part, int* rowptr){
  __shared__ int s[256];
  int b=blockIdx.x, t=threadIdx.x;
  int v0=deg[b*256+t];
  s[t]=v0;
  __syncthreads();
  for(int off=1; off<256; off<<=1){
    int v=s[t];
    int add=(t>=off)?s[t-off]:0;
    __syncthreads();
    s[t]=v+add;
    __syncthreads();
  }
  rowptr[b*256+t] = part[b] + s[t]-v0;
  if(b==511 && t==255) rowptr[NN] = part[b] + s[t];
}

// fill CSR-ordered edge streams (ea copy vectorized float2)
__global__ void k_fill(const int* dst, const int* src, const float* ea,
                       const int* rowptr, int* cursor, int* srcord, float* eaord){
  int e = blockIdx.x*256+threadIdx.x;
  if(e>=EE) return;
  int d = dst[e];
  int pos = atomicAdd(&cursor[d], 1);
  int idx = rowptr[d]+pos;
  srcord[idx] = src[e];
  float2 e0 = *(const float2*)&ea[(size_t)e*6];
  float2 e1 = *(const float2*)&ea[(size_t)e*6+2];
  float2 e2 = *(const float2*)&ea[(size_t)e*6+4];
  *(float2*)&eaord[(size_t)idx*6]   = e0;
  *(float2*)&eaord[(size_t)idx*6+2] = e1;
  *(float2*)&eaord[(size_t)idx*6+4] = e2;
}

// ---- per-layer Wf/bf precompute (1 block): Wf=W3@eW [64][6], bf=W3@eb+prb -
__global__ __launch_bounds__(448) void k_prepwf(const float* preW, const float* preb,
      const float* eW, const float* eb, float* WfG, float* bfG){
  int t=threadIdx.x;
  if(t<384){
    int j=t/6, d=t-j*6;
    float a=0.0f;
    for(int k=0;k<64;k++) a += preW[(size_t)j*192+128+k]*eW[k*6+d];
    WfG[t]=a;
  } else if(t<448){
    int j=t-384;
    float a=preb[j];
    for(int k=0;k<64;k++) a += preW[(size_t)j*192+128+k]*eb[k];
    bfG[j]=a;
  }
}

// ---- y0 = x @ lin1W.T + b (pre-activation, fp16); padded sW (bank-free) ---
__global__ __launch_bounds__(256) void k_lin1_s(const float* x, const float* W, const float* b, _Float16* y0){
  __shared__ float sW[2112];   // 64*33 padded
  __shared__ float sb[64];
  int t=threadIdx.x;
  for(int i=t;i<2048;i+=256){ int j=i>>5,k=i&31; sW[j*33+k]=W[i]; }
  if(t<64) sb[t]=b[t];
  __syncthreads();
  int n = blockIdx.x*4 + (t>>6);
  int j = t&63;
  float acc = sb[j];
  for(int k=0;k<32;k++) acc += x[n*32+k]*sW[j*33+k];
  y0[(size_t)n*64+j] = (_Float16)acc;
}

// ---- k_bnmsg: hy := relu(hy*sc+sh) in place; g12 = h @ [Wd|Ws].T (MFMA) ---
__global__ __launch_bounds__(256) void k_bnmsg(_Float16* hy, const float* sc, const float* sh,
      const float* preW, _Float16* g12){
  __shared__ _Float16 sAh[64][72];
  __shared__ _Float16 sB0[64][72];
  __shared__ _Float16 sB1[64][72];
  __shared__ float ssc[64], ssh[64];
  int t=threadIdx.x;
  int rb = blockIdx.x*64;
  if(t<64){ ssc[t] = sc? sc[t] : 1.0f; ssh[t] = sh? sh[t] : 0.0f; }
  __syncthreads();
  int sr = t>>2, c0 = (t&3)*16;
  {
    half8 y0 = *(const half8*)&hy[(size_t)(rb+sr)*64 + c0];
    half8 y1 = *(const half8*)&hy[(size_t)(rb+sr)*64 + c0 + 8];
    half8 h0, h1;
    #pragma unroll
    for(int q=0;q<8;q++){
      h0[q] = (_Float16)fmaxf((float)y0[q]*ssc[c0+q]   + ssh[c0+q],   0.0f);
      h1[q] = (_Float16)fmaxf((float)y1[q]*ssc[c0+8+q] + ssh[c0+8+q], 0.0f);
    }
    *(half8*)&sAh[sr][c0]   = h0;
    *(half8*)&sAh[sr][c0+8] = h1;
    *(half8*)&hy[(size_t)(rb+sr)*64 + c0]     = h0;
    *(half8*)&hy[(size_t)(rb+sr)*64 + c0 + 8] = h1;
    const float* w0 = &preW[(size_t)sr*192 + c0];
    const float* w1 = &preW[(size_t)sr*192 + 64 + c0];
    float4 a0=*(const float4*)&w0[0], a1=*(const float4*)&w0[4], a2=*(const float4*)&w0[8], a3=*(const float4*)&w0[12];
    float4 b0=*(const float4*)&w1[0], b1=*(const float4*)&w1[4], b2=*(const float4*)&w1[8], b3=*(const float4*)&w1[12];
    half8 w0h, w0h2, w1h, w1h2;
    float wa[16]={a0.x,a0.y,a0.z,a0.w,a1.x,a1.y,a1.z,a1.w,a2.x,a2.y,a2.z,a2.w,a3.x,a3.y,a3.z,a3.w};
    float wb[16]={b0.x,b0.y,b0.z,b0.w,b1.x,b1.y,b1.z,b1.w,b2.x,b2.y,b2.z,b2.w,b3.x,b3.y,b3.z,b3.w};
    #pragma unroll
    for(int q=0;q<8;q++){ w0h[q]=(_Float16)wa[q]; w0h2[q]=(_Float16)wa[8+q]; w1h[q]=(_Float16)wb[q]; w1h2[q]=(_Float16)wb[8+q]; }
    *(half8*)&sB0[sr][c0]   = w0h;  *(half8*)&sB0[sr][c0+8] = w0h2;
    *(half8*)&sB1[sr][c0]   = w1h;  *(half8*)&sB1[sr][c0+8] = w1h2;
  }
  __syncthreads();
  int w=t>>6, l=t&63;
  f32x4 acc0[4]={}, acc1[4]={};
  #pragma unroll
  for(int kk=0; kk<2; ++kk){
    half8 a = *(const half8*)&sAh[w*16+(l&15)][kk*32+(l>>4)*8];
    #pragma unroll
    for(int n16=0;n16<4;++n16){
      half8 b0 = *(const half8*)&sB0[n16*16+(l&15)][kk*32+(l>>4)*8];
      half8 b1 = *(const half8*)&sB1[n16*16+(l&15)][kk*32+(l>>4)*8];
      acc0[n16] = __builtin_amdgcn_mfma_f32_16x16x32_f16(a,b0,acc0[n16],0,0,0);
      acc1[n16] = __builtin_amdgcn_mfma_f32_16x16x32_f16(a,b1,acc1[n16],0,0,0);
    }
  }
  #pragma unroll
  for(int n16=0;n16<4;++n16){
    #pragma unroll
    for(int reg=0; reg<4; ++reg){
      int row = w*16+(l>>4)*4+reg;
      int col = n16*16+(l&15);
      g12[(size_t)(rb+row)*128 + col]      = (_Float16)acc0[n16][reg];
      g12[(size_t)(rb+row)*128 + 64 + col] = (_Float16)acc1[n16][reg];
    }
  }
}

// ---- gather: 64 contiguous nodes/block; edges prefetched; Wf/bf from global
__global__ __launch_bounds__(256) void k_gather_f(const int* rowptr, const int* srcord,
      const float* eaord, const _Float16* g12, const float* WfG, const float* bfG,
      _Float16* agg, float* s12, float avgdl){
  __shared__ float sWf[64][6];
  __shared__ float sbf[64];
  __shared__ int   sRow[65];
  __shared__ int   sSrc[GCAP];
  __shared__ float sEA[GCAP*6];
  int t=threadIdx.x;
  int rb = blockIdx.x*64;
  for(int i=t; i<384; i+=256) ((float*)sWf)[i]=WfG[i];
  if(t<64) sbf[t]=bfG[t];
  if(t<65) sRow[t]=rowptr[rb+t];
  __syncthreads();
  int eLo = sRow[0];
  int cnt = sRow[64]-eLo;
  int ccap = (cnt<GCAP)? cnt : GCAP;
  for(int i=t; i<ccap; i+=256) sSrc[i]=srcord[eLo+i];
  for(int f=t; f<ccap*6; f+=256) sEA[f]=eaord[(size_t)eLo*6+f];
  __syncthreads();
  int w=t>>6, j=t&63;
  float wf0=sWf[j][0], wf1=sWf[j][1], wf2=sWf[j][2];
  float wf3=sWf[j][3], wf4=sWf[j][4], wf5=sWf[j][5];
  float bfj=sbf[j];
  for(int q=0; q<16; ++q){
    int ln = w*16 + q;
    int n  = rb + ln;
    int lo = sRow[ln], hi = sRow[ln+1];
    float mdst = (float)g12[(size_t)n*128+j] + bfj;
    float sum=0.0f, sq=0.0f, mn=1e30f, mx=-1e30f;
    int idx=lo;
    for(; idx+1<hi; idx+=2){
      int r0 = idx-eLo, r1 = r0+1;
      int s0, s1;
      float e00,e01,e02,e03,e04,e05, e10,e11,e12,e13,e14,e15;
      if(r1 < GCAP){
        s0=sSrc[r0]; s1=sSrc[r1];
        e00=sEA[r0*6+0]; e01=sEA[r0*6+1]; e02=sEA[r0*6+2]; e03=sEA[r0*6+3]; e04=sEA[r0*6+4]; e05=sEA[r0*6+5];
        e10=sEA[r1*6+0]; e11=sEA[r1*6+1]; e12=sEA[r1*6+2]; e13=sEA[r1*6+3]; e14=sEA[r1*6+4]; e15=sEA[r1*6+5];
      } else {
        s0=srcord[idx]; s1=srcord[idx+1];
        e00=eaord[(size_t)idx*6+0]; e01=eaord[(size_t)idx*6+1]; e02=eaord[(size_t)idx*6+2];
        e03=eaord[(size_t)idx*6+3]; e04=eaord[(size_t)idx*6+4]; e05=eaord[(size_t)idx*6+5];
        e10=eaord[(size_t)(idx+1)*6+0]; e11=eaord[(size_t)(idx+1)*6+1]; e12=eaord[(size_t)(idx+1)*6+2];
        e13=eaord[(size_t)(idx+1)*6+3]; e14=eaord[(size_t)(idx+1)*6+4]; e15=eaord[(size_t)(idx+1)*6+5];
      }
      float g0 = (float)g12[(size_t)s0*128+64+j];
      float g1 = (float)g12[(size_t)s1*128+64+j];
      float m0 = mdst + g0 + e00*wf0 + e01*wf1 + e02*wf2 + e03*wf3 + e04*wf4 + e05*wf5;
      float m1 = mdst + g1 + e10*wf0 + e11*wf1 + e12*wf2 + e13*wf3 + e14*wf4 + e15*wf5;
      sum += m0; sq += m0*m0; mn = fminf(mn,m0); mx = fmaxf(mx,m0);
      sum += m1; sq += m1*m1; mn = fminf(mn,m1); mx = fmaxf(mx,m1);
    }
    if(idx<hi){
      int r0 = idx-eLo;
      int s0; float e00,e01,e02,e03,e04,e05;
      if(r0 < GCAP){
        s0=sSrc[r0];
        e00=sEA[r0*6+0]; e01=sEA[r0*6+1]; e02=sEA[r0*6+2]; e03=sEA[r0*6+3]; e04=sEA[r0*6+4]; e05=sEA[r0*6+5];
      } else {
        s0=srcord[idx];
        e00=eaord[(size_t)idx*6+0]; e01=eaord[(size_t)idx*6+1]; e02=eaord[(size_t)idx*6+2];
        e03=eaord[(size_t)idx*6+3]; e04=eaord[(size_t)idx*6+4]; e05=eaord[(size_t)idx*6+5];
      }
      float g0 = (float)g12[(size_t)s0*128+64+j];
      float m0 = mdst + g0 + e00*wf0 + e01*wf1 + e02*wf2 + e03*wf3 + e04*wf4 + e05*wf5;
      sum += m0; sq += m0*m0; mn = fminf(mn,m0); mx = fmaxf(mx,m0);
    }
    int c = hi-lo;
    float cm = fmaxf((float)c, 1.0f);
    float mean = sum/cm;
    float sd = sqrtf(fmaxf(sq/cm - mean*mean, 0.0f)+1e-5f);
    bool has = c>0;
    size_t base = (size_t)n*256;
    agg[base+j]     = (_Float16)mean;
    agg[base+64+j]  = (_Float16)(has?mn:0.0f);
    agg[base+128+j] = (_Float16)(has?mx:0.0f);
    agg[base+192+j] = (_Float16)sd;
    if(j==0){ float ld=logf(cm+1.0f); s12[n*2]=ld/avgdl; s12[n*2+1]=avgdl/ld; }
  }
}

// ---- k_tower_mfma v2: z-split (agg staged once/k-tile; s1,s2 in epilogue) -
__global__ __launch_bounds__(256) void k_tower_mfma(_Float16* hy, const _Float16* agg, const float* s12,
        const float* poW, const float* pob, const float* clW, const float* clb, float* part){
  __shared__ _Float16 sAh[64][72];
  __shared__ _Float16 sBh[64][72];
  __shared__ float sS[128];
  __shared__ float sredS[16][64];
  __shared__ float sredQ[16][64];
  int t = threadIdx.x;
  int rb = blockIdx.x*64;
  int w = t>>6, l = t&63;
  int sr = t>>2, c0 = (t&3)*16;
  if (t < 128) sS[t] = s12[(size_t)(rb+(t>>1))*2 + (t&1)];
  f32x4 hacc[4]={}, z0a[4]={}, z1a[4]={}, z2a[4]={};
  auto stageB = [&](const float* wr){
    float4 a0=*(const float4*)&wr[0], a1=*(const float4*)&wr[4], a2=*(const float4*)&wr[8], a3=*(const float4*)&wr[12];
    float wa[16]={a0.x,a0.y,a0.z,a0.w,a1.x,a1.y,a1.z,a1.w,a2.x,a2.y,a2.z,a2.w,a3.x,a3.y,a3.z,a3.w};
    half8 b0, b1;
    #pragma unroll
    for(int q=0;q<8;q++){ b0[q]=(_Float16)wa[q]; b1[q]=(_Float16)wa[8+q]; }
    *(half8*)&sBh[sr][c0]   = b0;
    *(half8*)&sBh[sr][c0+8] = b1;
  };
  auto mfma8 = [&](f32x4* acc){
    #pragma unroll
    for (int kk=0; kk<2; ++kk){
      half8 a = *(const half8*)&sAh[w*16 + (l&15)][kk*32 + (l>>4)*8];
      #pragma unroll
      for (int n16=0; n16<4; ++n16){
        half8 b = *(const half8*)&sBh[n16*16 + (l&15)][kk*32 + (l>>4)*8];
        acc[n16] = __builtin_amdgcn_mfma_f32_16x16x32_f16(a, b, acc[n16], 0, 0, 0);
      }
    }
  };
  {
    *(half8*)&sAh[sr][c0]   = *(const half8*)&hy[(size_t)(rb+sr)*64 + c0];
    *(half8*)&sAh[sr][c0+8] = *(const half8*)&hy[(size_t)(rb+sr)*64 + c0 + 8];
    stageB(&poW[(size_t)sr*832 + c0]);
  }
  __syncthreads();
  mfma8(hacc);
  for (int kt=0; kt<4; ++kt){
    __syncthreads();
    *(half8*)&sAh[sr][c0]   = *(const half8*)&agg[(size_t)(rb+sr)*256 + kt*64 + c0];
    *(half8*)&sAh[sr][c0+8] = *(const half8*)&agg[(size_t)(rb+sr)*256 + kt*64 + c0 + 8];
    stageB(&poW[(size_t)sr*832 + 64 + kt*64 + c0]);
    __syncthreads();
    mfma8(z0a);
    __syncthreads();
    stageB(&poW[(size_t)sr*832 + 64 + 256 + kt*64 + c0]);
    __syncthreads();
    mfma8(z1a);
    __syncthreads();
    stageB(&poW[(size_t)sr*832 + 64 + 512 + kt*64 + c0]);
    __syncthreads();
    mfma8(z2a);
  }
  __syncthreads();
  #pragma unroll
  for (int n16=0; n16<4; ++n16){
    #pragma unroll
    for (int reg=0; reg<4; ++reg){
      int row = w*16 + (l>>4)*4 + reg;
      int col = n16*16 + (l&15);
      float s1v = sS[row*2], s2v = sS[row*2+1];
      float v = hacc[n16][reg] + z0a[n16][reg] + s1v*z1a[n16][reg] + s2v*z2a[n16][reg] + pob[col];
      sAh[row][col] = (_Float16)v;
    }
  }
  stageB(&clW[(size_t)sr*64 + c0]);
  __syncthreads();
  f32x4 cacc[4] = {};
  mfma8(cacc);
  float cs_[4], cq_[4];
  #pragma unroll
  for (int n16=0; n16<4; ++n16){ cs_[n16]=0.0f; cq_[n16]=0.0f; }
  #pragma unroll
  for (int n16=0; n16<4; ++n16){
    #pragma unroll
    for (int reg=0; reg<4; ++reg){
      int row = w*16 + (l>>4)*4 + reg;
      int col = n16*16 + (l&15);
      float v = cacc[n16][reg] + clb[col];
      hy[(size_t)(rb+row)*64 + col] = (_Float16)v;
      cs_[n16] += v; cq_[n16] += v*v;
    }
  }
  int slot = w*4 + (l>>4);
  #pragma unroll
  for (int n16=0; n16<4; ++n16){
    int col = n16*16 + (l&15);
    sredS[slot][col] = cs_[n16];
    sredQ[slot][col] = cq_[n16];
  }
  __syncthreads();
  if (t < 64){
    float S=0.0f, Q=0.0f;
    #pragma unroll
    for(int q2=0;q2<16;q2++){ S += sredS[q2][t]; Q += sredQ[q2][t]; }
    part[(size_t)blockIdx.x*128 + t]      = S;
    part[(size_t)blockIdx.x*128 + 64 + t] = Q;
  }
}

// ---- BN finalize: hierarchical (1024 thr = 64 cols x 16 chunks) -----------
__global__ __launch_bounds__(1024) void k_bnfin(const float* part, const float* g, const float* bb,
                                                float* sc, float* sh){
  __shared__ double sS[16][64], sQ[16][64];
  int t = threadIdx.x;
  int c = t&63, chunk = t>>6;
  double S=0.0, Q=0.0;
  for(int b=chunk; b<2048; b+=16){
    S += (double)part[(size_t)b*128 + c];
    Q += (double)part[(size_t)b*128 + 64 + c];
  }
  sS[chunk][c]=S; sQ[chunk][c]=Q;
  __syncthreads();
  if(t<64){
    double St=0.0, Qt=0.0;
    #pragma unroll
    for(int q=0;q<16;q++){ St+=sS[q][t]; Qt+=sQ[q][t]; }
    double mean = St/(double)NN;
    double var  = Qt/(double)NN - mean*mean;
    float scale = g[t] * (float)(1.0/sqrt(var+1e-5));
    sc[t]=scale;
    sh[t]=bb[t] - (float)mean*scale;
  }
}

// ---- final BN apply in place on hy (fp16) ---------------------------------
__global__ void k_bnapply16(_Float16* hy, const float* sc, const float* sh){
  int idx = blockIdx.x*256+threadIdx.x;
  for(int i=idx; i<NN*8; i+=256*2048){
    int c0 = (i&7)*8;
    half8 v = *(const half8*)&hy[(size_t)i*8];
    half8 r;
    #pragma unroll
    for(int q=0;q<8;q++) r[q]=(_Float16)fmaxf((float)v[q]*sc[c0+q]+sh[c0+q],0.0f);
    *(half8*)&hy[(size_t)i*8] = r;
  }
}

// ---- set2set LSTM: 8 graphs/block, float4 weights reused x8, 8 acc chains -
__global__ __launch_bounds__(256) void k_lstm_lit(float* A, float* cs,
      const float* Wih, const float* Whh, const float* bih, const float* bhh){
  __shared__ float sA[8][128];
  __shared__ float sg[8][256];
  int t=threadIdx.x;
  int g0 = blockIdx.x*8;
  for(int i=t;i<1024;i+=256) sA[i>>7][i&127] = A[(size_t)(g0+(i>>7))*128 + (i&127)];
  __syncthreads();
  float bb2 = bih[t]+bhh[t];
  float acc[8];
  #pragma unroll
  for(int g=0;g<8;g++) acc[g]=bb2;
  for(int k=0;k<128;k+=4){
    float4 wv = *(const float4*)&Wih[(size_t)t*128+k];
    #pragma unroll
    for(int g=0;g<8;g++)
      acc[g] += wv.x*sA[g][k] + wv.y*sA[g][k+1] + wv.z*sA[g][k+2] + wv.w*sA[g][k+3];
  }
  for(int k=0;k<64;k+=4){
    float4 wv = *(const float4*)&Whh[(size_t)t*64+k];
    #pragma unroll
    for(int g=0;g<8;g++)
      acc[g] += wv.x*sA[g][k] + wv.y*sA[g][k+1] + wv.z*sA[g][k+2] + wv.w*sA[g][k+3];
  }
  #pragma unroll
  for(int g=0;g<8;g++) sg[g][t]=acc[g];
  __syncthreads();
  for(int i=t;i<512;i+=256){
    int g=i>>6, j=i&63;
    float ig=sg[g][j], fg=sg[g][64+j], gg=sg[g][128+j], og=sg[g][192+j];
    float c = sigmoidf_(fg)*cs[(size_t)(g0+g)*64+j] + sigmoidf_(ig)*tanhf(gg);
    float hv = sigmoidf_(og)*tanhf(c);
    cs[(size_t)(g0+g)*64+j]=c;
    A[(size_t)(g0+g)*128+j]=hv;
  }
}

// ---- fused edot+attn v2: parallel e-compute (lane i owns node i) ----------
__global__ __launch_bounds__(64) void k_attn_f(const _Float16* h16, const int* gptr, float* A){
  __shared__ _Float16 sH[ACAP][66];   // padded: row stride 132B -> 2-way max
  __shared__ float sE[ACAP];
  __shared__ float saq[64];
  int g=blockIdx.x, j=threadIdx.x;
  int lo=gptr[g], hi=gptr[g+1];
  int cnt=hi-lo;
  if(cnt<=0){ A[(size_t)g*128+64+j]=0.0f; return; }
  float aq = A[(size_t)g*128+j];
  saq[j]=aq;
  if(cnt<=ACAP){
    for(int i=0;i<cnt;++i) sH[i][j] = h16[(size_t)(lo+i)*64+j];
    __syncthreads();
    // parallel e: lane i computes e[i] = sum_k h[i][k]*aq[k]
    for(int i=j;i<cnt;i+=64){
      float v=0.0f;
      for(int k=0;k<64;k++) v += (float)sH[i][k]*saq[k];
      sE[i]=v;
    }
    __syncthreads();
    float mx=-1e30f;
    for(int i=j;i<cnt;i+=64) mx=fmaxf(mx,sE[i]);
    #pragma unroll
    for(int m=32;m;m>>=1) mx=fmaxf(mx,__shfl_xor(mx,m,64));
    float s=0.0f;
    for(int i=j;i<cnt;i+=64) s+=expf(sE[i]-mx);
    #pragma unroll
    for(int m=32;m;m>>=1) s+=__shfl_xor(s,m,64);
    float inv=1.0f/(s+1e-16f);
    // parallel attention weights (lane-owned i; no cross-lane hazard)
    for(int i=j;i<cnt;i+=64) sE[i]=expf(sE[i]-mx)*inv;
    __syncthreads();
    float r=0.0f;
    for(int i=0;i<cnt;++i) r += sE[i]*(float)sH[i][j];
    A[(size_t)g*128+64+j]=r;
  } else {
    // fallback (statistically unreachable): recompute e per pass
    float mx=-1e30f;
    for(int n=lo;n<hi;++n){
      float v=(float)h16[(size_t)n*64+j]*aq;
      #pragma unroll
      for(int m=32;m;m>>=1) v+=__shfl_xor(v,m,64);
      mx=fmaxf(mx,v);
    }
    float s=0.0f;
    for(int n=lo;n<hi;++n){
      float v=(float)h16[(size_t)n*64+j]*aq;
      #pragma unroll
      for(int m=32;m;m>>=1) v+=__shfl_xor(v,m,64);
      s+=expf(v-mx);
    }
    float inv=1.0f/(s+1e-16f);
    float r=0.0f;
    for(int n=lo;n<hi;++n){
      float v=(float)h16[(size_t)n*64+j]*aq;
      #pragma unroll
      for(int m=32;m;m>>=1) v+=__shfl_xor(v,m,64);
      r+=expf(v-mx)*inv*(float)h16[(size_t)n*64+j];
    }
    A[(size_t)g*128+64+j]=r;
  }
}

__global__ __launch_bounds__(64) void k_mlp(const float* A, const float* tt, const float* pp,
     const float* W1,const float* b1,const float* W2,const float* b2,const float* W3,const float* b3,
     float* out){
  __shared__ float si[130]; __shared__ float o1[64]; __shared__ float o2[32];
  int g=blockIdx.x, t=threadIdx.x;
  si[t]=A[g*128+t]; si[64+t]=A[g*128+64+t];
  if(t==0){ si[128]=tt[g]; si[129]=pp[g]; }
  __syncthreads();
  float a=b1[t];
  for(int k=0;k<130;k++) a+=W1[t*130+k]*si[k];
  o1[t]=fmaxf(a,0.0f);
  __syncthreads();
  if(t<32){
    float a2=b2[t];
    #pragma unroll 4
    for(int k=0;k<64;k++) a2+=W2[t*64+k]*o1[k];
    o2[t]=fmaxf(a2,0.0f);
  }
  __syncthreads();
  float v = (t<32)? o2[t]*W3[t] : 0.0f;
  #pragma unroll
  for(int m=32;m;m>>=1) v+=__shfl_xor(v,m,64);
  if(t==0) out[g]=v+b3[0];
}

// ---- host -----------------------------------------------------------------
extern "C" void kernel_launch(void* const* d_in, const int* in_sizes, int n_in,
                              void* d_out, int out_size, void* d_ws, size_t ws_size,
                              hipStream_t stream) {
  static const int want[28] = {4194304,3145728,4096,4096,2048,64,1152,192,36864,192,
                               159744,192,12288,192,192,192,32768,16384,256,256,
                               8320,64,2048,32,32,1,1048576,131072};
  if (n_in != 28 || out_size != GG) return;
  for (int i=0;i<28;i++) if (in_sizes[i] != want[i]) return;

  const float* x     = (const float*)d_in[0];
  const float* ea    = (const float*)d_in[1];
  const float* tt    = (const float*)d_in[2];
  const float* pp    = (const float*)d_in[3];
  const float* lin1W = (const float*)d_in[4];
  const float* lin1b = (const float*)d_in[5];
  const float* edgeW = (const float*)d_in[6];
  const float* edgeb = (const float*)d_in[7];
  const float* preW  = (const float*)d_in[8];
  const float* preb  = (const float*)d_in[9];
  const float* postW = (const float*)d_in[10];
  const float* postb = (const float*)d_in[11];
  const float* clinW = (const float*)d_in[12];
  const float* clinb = (const float*)d_in[13];
  const float* bng   = (const float*)d_in[14];
  const float* bnb   = (const float*)d_in[15];
  const float* Wih   = (const float*)d_in[16];
  const float* Whh   = (const float*)d_in[17];
  const float* bih   = (const float*)d_in[18];
  const float* bhh   = (const float*)d_in[19];
  const float* W1    = (const float*)d_in[20];
  const float* b1    = (const float*)d_in[21];
  const float* W2    = (const float*)d_in[22];
  const float* b2    = (const float*)d_in[23];
  const float* W3    = (const float*)d_in[24];
  const float* b3    = (const float*)d_in[25];
  const int*   eidx  = (const int*)d_in[26];
  const int*   batch = (const int*)d_in[27];
  const int* esrc = eidx;
  const int* edst = eidx + EE;

  char* w = (char*)d_ws;
  auto alloc = [&](size_t bytes)->char*{ char* p=w; w += ((bytes+255)/256)*256; return p; };
  _Float16* agg  = (_Float16*)alloc((size_t)NN*256*2);  // 64MiB fp16
  _Float16* g12  = (_Float16*)alloc((size_t)NN*128*2);  // 32MiB fp16 (set2set scratch aliases)
  _Float16* hy   = (_Float16*)alloc((size_t)NN*64*2);   // 16MiB fp16: y2/h in place
  int*   deg    = (int*)alloc((size_t)NN*4);
  int*   cursor = (int*)alloc((size_t)NN*4);
  int*   rowptr = (int*)alloc((size_t)(NN+1)*4);
  int*   spart  = (int*)alloc(512*4);
  int*   srcord = (int*)alloc((size_t)EE*4);
  float* eaord  = (float*)alloc((size_t)EE*6*4);
  float* s12   = (float*)alloc((size_t)NN*2*4);
  float* part  = (float*)alloc((size_t)2048*128*4);
  float* bnsc  = (float*)alloc(256);
  float* bnsh  = (float*)alloc(256);
  float* WfG   = (float*)alloc(384*4);
  float* bfG   = (float*)alloc(64*4);
  int*   gptr  = (int*)alloc((GG+1)*4);
  size_t need = (size_t)(w - (char*)d_ws);
  if (need > ws_size) return;
  float* A    = (float*)g12;
  float* cs   = (float*)g12 + (size_t)GG*128;

  double num = 13107.0*log(2.0)+26214.0*log(3.0)+65536.0*log(4.0)+26215.0*log(5.0);
  float avgdl = (float)(num/131072.0);

  hipMemsetAsync(deg, 0, (size_t)NN*4, stream);
  hipMemsetAsync(cursor, 0, (size_t)NN*4, stream);
  hipLaunchKernelGGL(k_deg, dim3(2048), dim3(256), 0, stream, edst, deg);
  hipLaunchKernelGGL(k_scan_part, dim3(512), dim3(256), 0, stream, deg, spart);
  hipLaunchKernelGGL(k_scan_top, dim3(1), dim3(512), 0, stream, spart);
  hipLaunchKernelGGL(k_scan_apply, dim3(512), dim3(256), 0, stream, deg, spart, rowptr);
  hipLaunchKernelGGL(k_fill, dim3(2048), dim3(256), 0, stream, edst, esrc, ea, rowptr, cursor, srcord, eaord);

  hipLaunchKernelGGL(k_gptr, dim3(17), dim3(256), 0, stream, batch, gptr);
  hipLaunchKernelGGL(k_lin1_s, dim3(32768), dim3(256), 0, stream, x, lin1W, lin1b, hy);

  for (int i = 0; i < 3; ++i){
    const float* sc_i = (i==0)? nullptr : bnsc;
    const float* sh_i = (i==0)? nullptr : bnsh;
    hipLaunchKernelGGL(k_prepwf, dim3(1), dim3(448), 0, stream,
        preW + (size_t)i*64*192, preb + i*64, edgeW + (size_t)i*384, edgeb + i*64, WfG, bfG);
    hipLaunchKernelGGL(k_bnmsg, dim3(2048), dim3(256), 0, stream, hy, sc_i, sh_i,
        preW + (size_t)i*64*192, g12);
    hipLaunchKernelGGL(k_gather_f, dim3(2048), dim3(256), 0, stream, rowptr, srcord, eaord, g12,
        WfG, bfG, agg, s12, avgdl);
    hipLaunchKernelGGL(k_tower_mfma, dim3(2048), dim3(256), 0, stream, hy, agg, s12,
        postW + (size_t)i*64*832, postb + i*64, clinW + (size_t)i*4096, clinb + i*64, part);
    hipLaunchKernelGGL(k_bnfin, dim3(1), dim3(1024), 0, stream, part, bng + i*64, bnb + i*64, bnsc, bnsh);
  }
  hipLaunchKernelGGL(k_bnapply16, dim3(2048), dim3(256), 0, stream, hy, bnsc, bnsh);

  hipMemsetAsync(A, 0, (size_t)GG*128*4, stream);
  hipMemsetAsync(cs, 0, (size_t)GG*64*4, stream);
  for (int s = 0; s < 3; ++s){
    hipLaunchKernelGGL(k_lstm_lit, dim3(512), dim3(256), 0, stream, A, cs, Wih, Whh, bih, bhh);
    hipLaunchKernelGGL(k_attn_f, dim3(GG), dim3(64), 0, stream, hy, gptr, A);
  }
  hipLaunchKernelGGL(k_mlp, dim3(GG), dim3(64), 0, stream, A, tt, pp, W1, b1, W2, b2, W3, b3, (float*)d_out);
}

// Round 23
// 755.885 us; speedup vs baseline: 1.1383x; 1.0244x over previous
//
#include <hip/hip_runtime.h>
#include <hip/hip_bf16.h>
#include <math.h>

#define NN 131072
#define EE 524288
#define GG 4096
#define GCAP 320
#define ACAP 96

typedef __attribute__((ext_vector_type(8))) _Float16 half8;
typedef __attribute__((ext_vector_type(4))) _Float16 half4;
typedef __attribute__((ext_vector_type(4))) float f32x4;

__device__ __forceinline__ float sigmoidf_(float x){ return 1.0f/(1.0f+expf(-x)); }

// ---- grouping / CSR (integer atomics only) --------------------------------
__global__ void k_gptr(const int* batch, int* gptr){
  int g = blockIdx.x*256+threadIdx.x;
  if (g > GG) return;
  if (g == GG){ gptr[GG]=NN; return; }
  int lo=0, hi=NN;
  while(lo<hi){ int mid=(lo+hi)>>1; if(batch[mid]<g) lo=mid+1; else hi=mid; }
  gptr[g]=lo;
}

__global__ void k_deg(const int* dst, int* deg){
  int e = blockIdx.x*256+threadIdx.x;
  if(e<EE) atomicAdd(&deg[dst[e]], 1);
}

// hierarchical scan
__global__ __launch_bounds__(256) void k_scan_part(const int* deg, int* part){
  __shared__ int red[256];
  int b=blockIdx.x, t=threadIdx.x;
  red[t] = deg[b*256+t];
  __syncthreads();
  for(int off=128; off>0; off>>=1){
    if(t<off) red[t]+=red[t+off];
    __syncthreads();
  }
  if(t==0) part[b]=red[0];
}

__global__ __launch_bounds__(512) void k_scan_top(int* part){
  __shared__ int s[512];
  int t=threadIdx.x;
  s[t]=part[t];
  __syncthreads();
  for(int off=1; off<512; off<<=1){
    int v=s[t];
    int add=(t>=off)?s[t-off]:0;
    __syncthreads();
    s[t]=v+add;
    __syncthreads();
  }
  part[t] = (t==0)?0:s[t-1];
}

__global__ __launch_bounds__(256) void k_scan_apply(const int* deg, const int* part, int* rowptr){
  __shared__ int s[256];
  int b=blockIdx.x, t=threadIdx.x;
  int v0=deg[b*256+t];
  s[t]=v0;
  __syncthreads();
  for(int off=1; off<256; off<<=1){
    int v=s[t];
    int add=(t>=off)?s[t-off]:0;
    __syncthreads();
    s[t]=v+add;
    __syncthreads();
  }
  rowptr[b*256+t] = part[b] + s[t]-v0;
  if(b==511 && t==255) rowptr[NN] = part[b] + s[t];
}

// fill CSR-ordered edge streams (ea copy vectorized float2)
__global__ void k_fill(const int* dst, const int* src, const float* ea,
                       const int* rowptr, int* cursor, int* srcord, float* eaord){
  int e = blockIdx.x*256+threadIdx.x;
  if(e>=EE) return;
  int d = dst[e];
  int pos = atomicAdd(&cursor[d], 1);
  int idx = rowptr[d]+pos;
  srcord[idx] = src[e];
  float2 e0 = *(const float2*)&ea[(size_t)e*6];
  float2 e1 = *(const float2*)&ea[(size_t)e*6+2];
  float2 e2 = *(const float2*)&ea[(size_t)e*6+4];
  *(float2*)&eaord[(size_t)idx*6]   = e0;
  *(float2*)&eaord[(size_t)idx*6+2] = e1;
  *(float2*)&eaord[(size_t)idx*6+4] = e2;
}

// ---- all-layers Wf/bf precompute (3 blocks): Wf=W3@eW [64][6], bf=W3@eb+prb
__global__ __launch_bounds__(448) void k_prepwf(const float* preW, const float* preb,
      const float* eW, const float* eb, float* WfG, float* bfG){
  int i = blockIdx.x;            // layer
  const float* pW = preW + (size_t)i*64*192;
  const float* pb = preb + i*64;
  const float* eWl = eW + (size_t)i*384;
  const float* ebl = eb + i*64;
  int t=threadIdx.x;
  if(t<384){
    int j=t/6, d=t-j*6;
    float a=0.0f;
    for(int k=0;k<64;k++) a += pW[(size_t)j*192+128+k]*eWl[k*6+d];
    WfG[i*384+t]=a;
  } else if(t<448){
    int j=t-384;
    float a=pb[j];
    for(int k=0;k<64;k++) a += pW[(size_t)j*192+128+k]*ebl[k];
    bfG[i*64+j]=a;
  }
}

// ---- y0 = x @ lin1W.T + b (pre-activation, fp16); padded sW (bank-free) ---
__global__ __launch_bounds__(256) void k_lin1_s(const float* x, const float* W, const float* b, _Float16* y0){
  __shared__ float sW[2112];   // 64*33 padded
  __shared__ float sb[64];
  int t=threadIdx.x;
  for(int i=t;i<2048;i+=256){ int j=i>>5,k=i&31; sW[j*33+k]=W[i]; }
  if(t<64) sb[t]=b[t];
  __syncthreads();
  int n = blockIdx.x*4 + (t>>6);
  int j = t&63;
  float acc = sb[j];
  for(int k=0;k<32;k++) acc += x[n*32+k]*sW[j*33+k];
  y0[(size_t)n*64+j] = (_Float16)acc;
}

// ---- k_bnmsg: hy := relu(hy*sc+sh) in place; g12 = h @ [Wd|Ws].T (MFMA) ---
__global__ __launch_bounds__(256) void k_bnmsg(_Float16* hy, const float* sc, const float* sh,
      const float* preW, _Float16* g12){
  __shared__ _Float16 sAh[64][72];
  __shared__ _Float16 sB0[64][72];
  __shared__ _Float16 sB1[64][72];
  __shared__ float ssc[64], ssh[64];
  int t=threadIdx.x;
  int rb = blockIdx.x*64;
  if(t<64){ ssc[t] = sc? sc[t] : 1.0f; ssh[t] = sh? sh[t] : 0.0f; }
  __syncthreads();
  int sr = t>>2, c0 = (t&3)*16;
  {
    half8 y0 = *(const half8*)&hy[(size_t)(rb+sr)*64 + c0];
    half8 y1 = *(const half8*)&hy[(size_t)(rb+sr)*64 + c0 + 8];
    half8 h0, h1;
    #pragma unroll
    for(int q=0;q<8;q++){
      h0[q] = (_Float16)fmaxf((float)y0[q]*ssc[c0+q]   + ssh[c0+q],   0.0f);
      h1[q] = (_Float16)fmaxf((float)y1[q]*ssc[c0+8+q] + ssh[c0+8+q], 0.0f);
    }
    *(half8*)&sAh[sr][c0]   = h0;
    *(half8*)&sAh[sr][c0+8] = h1;
    *(half8*)&hy[(size_t)(rb+sr)*64 + c0]     = h0;
    *(half8*)&hy[(size_t)(rb+sr)*64 + c0 + 8] = h1;
    const float* w0 = &preW[(size_t)sr*192 + c0];
    const float* w1 = &preW[(size_t)sr*192 + 64 + c0];
    float4 a0=*(const float4*)&w0[0], a1=*(const float4*)&w0[4], a2=*(const float4*)&w0[8], a3=*(const float4*)&w0[12];
    float4 b0=*(const float4*)&w1[0], b1=*(const float4*)&w1[4], b2=*(const float4*)&w1[8], b3=*(const float4*)&w1[12];
    half8 w0h, w0h2, w1h, w1h2;
    float wa[16]={a0.x,a0.y,a0.z,a0.w,a1.x,a1.y,a1.z,a1.w,a2.x,a2.y,a2.z,a2.w,a3.x,a3.y,a3.z,a3.w};
    float wb[16]={b0.x,b0.y,b0.z,b0.w,b1.x,b1.y,b1.z,b1.w,b2.x,b2.y,b2.z,b2.w,b3.x,b3.y,b3.z,b3.w};
    #pragma unroll
    for(int q=0;q<8;q++){ w0h[q]=(_Float16)wa[q]; w0h2[q]=(_Float16)wa[8+q]; w1h[q]=(_Float16)wb[q]; w1h2[q]=(_Float16)wb[8+q]; }
    *(half8*)&sB0[sr][c0]   = w0h;  *(half8*)&sB0[sr][c0+8] = w0h2;
    *(half8*)&sB1[sr][c0]   = w1h;  *(half8*)&sB1[sr][c0+8] = w1h2;
  }
  __syncthreads();
  int w=t>>6, l=t&63;
  f32x4 acc0[4]={}, acc1[4]={};
  #pragma unroll
  for(int kk=0; kk<2; ++kk){
    half8 a = *(const half8*)&sAh[w*16+(l&15)][kk*32+(l>>4)*8];
    #pragma unroll
    for(int n16=0;n16<4;++n16){
      half8 b0 = *(const half8*)&sB0[n16*16+(l&15)][kk*32+(l>>4)*8];
      half8 b1 = *(const half8*)&sB1[n16*16+(l&15)][kk*32+(l>>4)*8];
      acc0[n16] = __builtin_amdgcn_mfma_f32_16x16x32_f16(a,b0,acc0[n16],0,0,0);
      acc1[n16] = __builtin_amdgcn_mfma_f32_16x16x32_f16(a,b1,acc1[n16],0,0,0);
    }
  }
  #pragma unroll
  for(int n16=0;n16<4;++n16){
    #pragma unroll
    for(int reg=0; reg<4; ++reg){
      int row = w*16+(l>>4)*4+reg;
      int col = n16*16+(l&15);
      g12[(size_t)(rb+row)*128 + col]      = (_Float16)acc0[n16][reg];
      g12[(size_t)(rb+row)*128 + 64 + col] = (_Float16)acc1[n16][reg];
    }
  }
}

// ---- gather: 32 contiguous nodes/block (4096 blocks); edges prefetched ----
__global__ __launch_bounds__(256) void k_gather_f(const int* rowptr, const int* srcord,
      const float* eaord, const _Float16* g12, const float* WfG, const float* bfG,
      _Float16* agg, float* s12, float avgdl){
  __shared__ float sWf[64][6];
  __shared__ float sbf[64];
  __shared__ int   sRow[33];
  __shared__ int   sSrc[GCAP];
  __shared__ float sEA[GCAP*6];
  int t=threadIdx.x;
  int rb = blockIdx.x*32;
  for(int i=t; i<384; i+=256) ((float*)sWf)[i]=WfG[i];
  if(t<64) sbf[t]=bfG[t];
  if(t<33) sRow[t]=rowptr[rb+t];
  __syncthreads();
  int eLo = sRow[0];
  int cnt = sRow[32]-eLo;
  int ccap = (cnt<GCAP)? cnt : GCAP;
  for(int i=t; i<ccap; i+=256) sSrc[i]=srcord[eLo+i];
  for(int f=t; f<ccap*6; f+=256) sEA[f]=eaord[(size_t)eLo*6+f];
  __syncthreads();
  int w=t>>6, j=t&63;
  float wf0=sWf[j][0], wf1=sWf[j][1], wf2=sWf[j][2];
  float wf3=sWf[j][3], wf4=sWf[j][4], wf5=sWf[j][5];
  float bfj=sbf[j];
  for(int q=0; q<8; ++q){
    int ln = w*8 + q;
    int n  = rb + ln;
    int lo = sRow[ln], hi = sRow[ln+1];
    float mdst = (float)g12[(size_t)n*128+j] + bfj;
    float sum=0.0f, sq=0.0f, mn=1e30f, mx=-1e30f;
    int idx=lo;
    for(; idx+1<hi; idx+=2){
      int r0 = idx-eLo, r1 = r0+1;
      int s0, s1;
      float e00,e01,e02,e03,e04,e05, e10,e11,e12,e13,e14,e15;
      if(r1 < GCAP){
        s0=sSrc[r0]; s1=sSrc[r1];
        e00=sEA[r0*6+0]; e01=sEA[r0*6+1]; e02=sEA[r0*6+2]; e03=sEA[r0*6+3]; e04=sEA[r0*6+4]; e05=sEA[r0*6+5];
        e10=sEA[r1*6+0]; e11=sEA[r1*6+1]; e12=sEA[r1*6+2]; e13=sEA[r1*6+3]; e14=sEA[r1*6+4]; e15=sEA[r1*6+5];
      } else {
        s0=srcord[idx]; s1=srcord[idx+1];
        e00=eaord[(size_t)idx*6+0]; e01=eaord[(size_t)idx*6+1]; e02=eaord[(size_t)idx*6+2];
        e03=eaord[(size_t)idx*6+3]; e04=eaord[(size_t)idx*6+4]; e05=eaord[(size_t)idx*6+5];
        e10=eaord[(size_t)(idx+1)*6+0]; e11=eaord[(size_t)(idx+1)*6+1]; e12=eaord[(size_t)(idx+1)*6+2];
        e13=eaord[(size_t)(idx+1)*6+3]; e14=eaord[(size_t)(idx+1)*6+4]; e15=eaord[(size_t)(idx+1)*6+5];
      }
      float g0 = (float)g12[(size_t)s0*128+64+j];
      float g1 = (float)g12[(size_t)s1*128+64+j];
      float m0 = mdst + g0 + e00*wf0 + e01*wf1 + e02*wf2 + e03*wf3 + e04*wf4 + e05*wf5;
      float m1 = mdst + g1 + e10*wf0 + e11*wf1 + e12*wf2 + e13*wf3 + e14*wf4 + e15*wf5;
      sum += m0; sq += m0*m0; mn = fminf(mn,m0); mx = fmaxf(mx,m0);
      sum += m1; sq += m1*m1; mn = fminf(mn,m1); mx = fmaxf(mx,m1);
    }
    if(idx<hi){
      int r0 = idx-eLo;
      int s0; float e00,e01,e02,e03,e04,e05;
      if(r0 < GCAP){
        s0=sSrc[r0];
        e00=sEA[r0*6+0]; e01=sEA[r0*6+1]; e02=sEA[r0*6+2]; e03=sEA[r0*6+3]; e04=sEA[r0*6+4]; e05=sEA[r0*6+5];
      } else {
        s0=srcord[idx];
        e00=eaord[(size_t)idx*6+0]; e01=eaord[(size_t)idx*6+1]; e02=eaord[(size_t)idx*6+2];
        e03=eaord[(size_t)idx*6+3]; e04=eaord[(size_t)idx*6+4]; e05=eaord[(size_t)idx*6+5];
      }
      float g0 = (float)g12[(size_t)s0*128+64+j];
      float m0 = mdst + g0 + e00*wf0 + e01*wf1 + e02*wf2 + e03*wf3 + e04*wf4 + e05*wf5;
      sum += m0; sq += m0*m0; mn = fminf(mn,m0); mx = fmaxf(mx,m0);
    }
    int c = hi-lo;
    float cm = fmaxf((float)c, 1.0f);
    float mean = sum/cm;
    float sd = sqrtf(fmaxf(sq/cm - mean*mean, 0.0f)+1e-5f);
    bool has = c>0;
    size_t base = (size_t)n*256;
    agg[base+j]     = (_Float16)mean;
    agg[base+64+j]  = (_Float16)(has?mn:0.0f);
    agg[base+128+j] = (_Float16)(has?mx:0.0f);
    agg[base+192+j] = (_Float16)sd;
    if(j==0){ float ld=logf(cm+1.0f); s12[n*2]=ld/avgdl; s12[n*2+1]=avgdl/ld; }
  }
}

// ---- k_tower_mfma v2: z-split (agg staged once/k-tile; s1,s2 in epilogue) -
__global__ __launch_bounds__(256) void k_tower_mfma(_Float16* hy, const _Float16* agg, const float* s12,
        const float* poW, const float* pob, const float* clW, const float* clb, float* part){
  __shared__ _Float16 sAh[64][72];
  __shared__ _Float16 sBh[64][72];
  __shared__ float sS[128];
  __shared__ float sredS[16][64];
  __shared__ float sredQ[16][64];
  int t = threadIdx.x;
  int rb = blockIdx.x*64;
  int w = t>>6, l = t&63;
  int sr = t>>2, c0 = (t&3)*16;
  if (t < 128) sS[t] = s12[(size_t)(rb+(t>>1))*2 + (t&1)];
  f32x4 hacc[4]={}, z0a[4]={}, z1a[4]={}, z2a[4]={};
  auto stageB = [&](const float* wr){
    float4 a0=*(const float4*)&wr[0], a1=*(const float4*)&wr[4], a2=*(const float4*)&wr[8], a3=*(const float4*)&wr[12];
    float wa[16]={a0.x,a0.y,a0.z,a0.w,a1.x,a1.y,a1.z,a1.w,a2.x,a2.y,a2.z,a2.w,a3.x,a3.y,a3.z,a3.w};
    half8 b0, b1;
    #pragma unroll
    for(int q=0;q<8;q++){ b0[q]=(_Float16)wa[q]; b1[q]=(_Float16)wa[8+q]; }
    *(half8*)&sBh[sr][c0]   = b0;
    *(half8*)&sBh[sr][c0+8] = b1;
  };
  auto mfma8 = [&](f32x4* acc){
    #pragma unroll
    for (int kk=0; kk<2; ++kk){
      half8 a = *(const half8*)&sAh[w*16 + (l&15)][kk*32 + (l>>4)*8];
      #pragma unroll
      for (int n16=0; n16<4; ++n16){
        half8 b = *(const half8*)&sBh[n16*16 + (l&15)][kk*32 + (l>>4)*8];
        acc[n16] = __builtin_amdgcn_mfma_f32_16x16x32_f16(a, b, acc[n16], 0, 0, 0);
      }
    }
  };
  {
    *(half8*)&sAh[sr][c0]   = *(const half8*)&hy[(size_t)(rb+sr)*64 + c0];
    *(half8*)&sAh[sr][c0+8] = *(const half8*)&hy[(size_t)(rb+sr)*64 + c0 + 8];
    stageB(&poW[(size_t)sr*832 + c0]);
  }
  __syncthreads();
  mfma8(hacc);
  for (int kt=0; kt<4; ++kt){
    __syncthreads();
    *(half8*)&sAh[sr][c0]   = *(const half8*)&agg[(size_t)(rb+sr)*256 + kt*64 + c0];
    *(half8*)&sAh[sr][c0+8] = *(const half8*)&agg[(size_t)(rb+sr)*256 + kt*64 + c0 + 8];
    stageB(&poW[(size_t)sr*832 + 64 + kt*64 + c0]);
    __syncthreads();
    mfma8(z0a);
    __syncthreads();
    stageB(&poW[(size_t)sr*832 + 64 + 256 + kt*64 + c0]);
    __syncthreads();
    mfma8(z1a);
    __syncthreads();
    stageB(&poW[(size_t)sr*832 + 64 + 512 + kt*64 + c0]);
    __syncthreads();
    mfma8(z2a);
  }
  __syncthreads();
  #pragma unroll
  for (int n16=0; n16<4; ++n16){
    #pragma unroll
    for (int reg=0; reg<4; ++reg){
      int row = w*16 + (l>>4)*4 + reg;
      int col = n16*16 + (l&15);
      float s1v = sS[row*2], s2v = sS[row*2+1];
      float v = hacc[n16][reg] + z0a[n16][reg] + s1v*z1a[n16][reg] + s2v*z2a[n16][reg] + pob[col];
      sAh[row][col] = (_Float16)v;
    }
  }
  stageB(&clW[(size_t)sr*64 + c0]);
  __syncthreads();
  f32x4 cacc[4] = {};
  mfma8(cacc);
  float cs_[4], cq_[4];
  #pragma unroll
  for (int n16=0; n16<4; ++n16){ cs_[n16]=0.0f; cq_[n16]=0.0f; }
  #pragma unroll
  for (int n16=0; n16<4; ++n16){
    #pragma unroll
    for (int reg=0; reg<4; ++reg){
      int row = w*16 + (l>>4)*4 + reg;
      int col = n16*16 + (l&15);
      float v = cacc[n16][reg] + clb[col];
      hy[(size_t)(rb+row)*64 + col] = (_Float16)v;
      cs_[n16] += v; cq_[n16] += v*v;
    }
  }
  int slot = w*4 + (l>>4);
  #pragma unroll
  for (int n16=0; n16<4; ++n16){
    int col = n16*16 + (l&15);
    sredS[slot][col] = cs_[n16];
    sredQ[slot][col] = cq_[n16];
  }
  __syncthreads();
  if (t < 64){
    float S=0.0f, Q=0.0f;
    #pragma unroll
    for(int q2=0;q2<16;q2++){ S += sredS[q2][t]; Q += sredQ[q2][t]; }
    part[(size_t)blockIdx.x*128 + t]      = S;
    part[(size_t)blockIdx.x*128 + 64 + t] = Q;
  }
}

// ---- BN finalize: hierarchical (1024 thr = 64 cols x 16 chunks) -----------
__global__ __launch_bounds__(1024) void k_bnfin(const float* part, const float* g, const float* bb,
                                                float* sc, float* sh){
  __shared__ double sS[16][64], sQ[16][64];
  int t = threadIdx.x;
  int c = t&63, chunk = t>>6;
  double S=0.0, Q=0.0;
  for(int b=chunk; b<2048; b+=16){
    S += (double)part[(size_t)b*128 + c];
    Q += (double)part[(size_t)b*128 + 64 + c];
  }
  sS[chunk][c]=S; sQ[chunk][c]=Q;
  __syncthreads();
  if(t<64){
    double St=0.0, Qt=0.0;
    #pragma unroll
    for(int q=0;q<16;q++){ St+=sS[q][t]; Qt+=sQ[q][t]; }
    double mean = St/(double)NN;
    double var  = Qt/(double)NN - mean*mean;
    float scale = g[t] * (float)(1.0/sqrt(var+1e-5));
    sc[t]=scale;
    sh[t]=bb[t] - (float)mean*scale;
  }
}

// ---- final BN apply in place on hy (fp16) ---------------------------------
__global__ void k_bnapply16(_Float16* hy, const float* sc, const float* sh){
  int idx = blockIdx.x*256+threadIdx.x;
  for(int i=idx; i<NN*8; i+=256*2048){
    int c0 = (i&7)*8;
    half8 v = *(const half8*)&hy[(size_t)i*8];
    half8 r;
    #pragma unroll
    for(int q=0;q<8;q++) r[q]=(_Float16)fmaxf((float)v[q]*sc[c0+q]+sh[c0+q],0.0f);
    *(half8*)&hy[(size_t)i*8] = r;
  }
}

// ---- set2set LSTM: 8 graphs/block, float4 weights reused x8, 8 acc chains -
__global__ __launch_bounds__(256) void k_lstm_lit(float* A, float* cs,
      const float* Wih, const float* Whh, const float* bih, const float* bhh){
  __shared__ float sA[8][128];
  __shared__ float sg[8][256];
  int t=threadIdx.x;
  int g0 = blockIdx.x*8;
  for(int i=t;i<1024;i+=256) sA[i>>7][i&127] = A[(size_t)(g0+(i>>7))*128 + (i&127)];
  __syncthreads();
  float bb2 = bih[t]+bhh[t];
  float acc[8];
  #pragma unroll
  for(int g=0;g<8;g++) acc[g]=bb2;
  for(int k=0;k<128;k+=4){
    float4 wv = *(const float4*)&Wih[(size_t)t*128+k];
    #pragma unroll
    for(int g=0;g<8;g++)
      acc[g] += wv.x*sA[g][k] + wv.y*sA[g][k+1] + wv.z*sA[g][k+2] + wv.w*sA[g][k+3];
  }
  for(int k=0;k<64;k+=4){
    float4 wv = *(const float4*)&Whh[(size_t)t*64+k];
    #pragma unroll
    for(int g=0;g<8;g++)
      acc[g] += wv.x*sA[g][k] + wv.y*sA[g][k+1] + wv.z*sA[g][k+2] + wv.w*sA[g][k+3];
  }
  #pragma unroll
  for(int g=0;g<8;g++) sg[g][t]=acc[g];
  __syncthreads();
  for(int i=t;i<512;i+=256){
    int g=i>>6, j=i&63;
    float ig=sg[g][j], fg=sg[g][64+j], gg=sg[g][128+j], og=sg[g][192+j];
    float c = sigmoidf_(fg)*cs[(size_t)(g0+g)*64+j] + sigmoidf_(ig)*tanhf(gg);
    float hv = sigmoidf_(og)*tanhf(c);
    cs[(size_t)(g0+g)*64+j]=c;
    A[(size_t)(g0+g)*128+j]=hv;
  }
}

// ---- fused edot+attn v2: parallel e-compute (lane i owns node i) ----------
__global__ __launch_bounds__(64) void k_attn_f(const _Float16* h16, const int* gptr, float* A){
  __shared__ _Float16 sH[ACAP][66];   // padded: row stride 132B -> 2-way max
  __shared__ float sE[ACAP];
  __shared__ float saq[64];
  int g=blockIdx.x, j=threadIdx.x;
  int lo=gptr[g], hi=gptr[g+1];
  int cnt=hi-lo;
  if(cnt<=0){ A[(size_t)g*128+64+j]=0.0f; return; }
  float aq = A[(size_t)g*128+j];
  saq[j]=aq;
  if(cnt<=ACAP){
    for(int i=0;i<cnt;++i) sH[i][j] = h16[(size_t)(lo+i)*64+j];
    __syncthreads();
    for(int i=j;i<cnt;i+=64){
      float v=0.0f;
      for(int k=0;k<64;k++) v += (float)sH[i][k]*saq[k];
      sE[i]=v;
    }
    __syncthreads();
    float mx=-1e30f;
    for(int i=j;i<cnt;i+=64) mx=fmaxf(mx,sE[i]);
    #pragma unroll
    for(int m=32;m;m>>=1) mx=fmaxf(mx,__shfl_xor(mx,m,64));
    float s=0.0f;
    for(int i=j;i<cnt;i+=64) s+=expf(sE[i]-mx);
    #pragma unroll
    for(int m=32;m;m>>=1) s+=__shfl_xor(s,m,64);
    float inv=1.0f/(s+1e-16f);
    for(int i=j;i<cnt;i+=64) sE[i]=expf(sE[i]-mx)*inv;
    __syncthreads();
    float r=0.0f;
    for(int i=0;i<cnt;++i) r += sE[i]*(float)sH[i][j];
    A[(size_t)g*128+64+j]=r;
  } else {
    float mx=-1e30f;
    for(int n=lo;n<hi;++n){
      float v=(float)h16[(size_t)n*64+j]*aq;
      #pragma unroll
      for(int m=32;m;m>>=1) v+=__shfl_xor(v,m,64);
      mx=fmaxf(mx,v);
    }
    float s=0.0f;
    for(int n=lo;n<hi;++n){
      float v=(float)h16[(size_t)n*64+j]*aq;
      #pragma unroll
      for(int m=32;m;m>>=1) v+=__shfl_xor(v,m,64);
      s+=expf(v-mx);
    }
    float inv=1.0f/(s+1e-16f);
    float r=0.0f;
    for(int n=lo;n<hi;++n){
      float v=(float)h16[(size_t)n*64+j]*aq;
      #pragma unroll
      for(int m=32;m;m>>=1) v+=__shfl_xor(v,m,64);
      r+=expf(v-mx)*inv*(float)h16[(size_t)n*64+j];
    }
    A[(size_t)g*128+64+j]=r;
  }
}

__global__ __launch_bounds__(64) void k_mlp(const float* A, const float* tt, const float* pp,
     const float* W1,const float* b1,const float* W2,const float* b2,const float* W3,const float* b3,
     float* out){
  __shared__ float si[130]; __shared__ float o1[64]; __shared__ float o2[32];
  int g=blockIdx.x, t=threadIdx.x;
  si[t]=A[g*128+t]; si[64+t]=A[g*128+64+t];
  if(t==0){ si[128]=tt[g]; si[129]=pp[g]; }
  __syncthreads();
  float a=b1[t];
  for(int k=0;k<130;k++) a+=W1[t*130+k]*si[k];
  o1[t]=fmaxf(a,0.0f);
  __syncthreads();
  if(t<32){
    float a2=b2[t];
    #pragma unroll 4
    for(int k=0;k<64;k++) a2+=W2[t*64+k]*o1[k];
    o2[t]=fmaxf(a2,0.0f);
  }
  __syncthreads();
  float v = (t<32)? o2[t]*W3[t] : 0.0f;
  #pragma unroll
  for(int m=32;m;m>>=1) v+=__shfl_xor(v,m,64);
  if(t==0) out[g]=v+b3[0];
}

// ---- host -----------------------------------------------------------------
extern "C" void kernel_launch(void* const* d_in, const int* in_sizes, int n_in,
                              void* d_out, int out_size, void* d_ws, size_t ws_size,
                              hipStream_t stream) {
  static const int want[28] = {4194304,3145728,4096,4096,2048,64,1152,192,36864,192,
                               159744,192,12288,192,192,192,32768,16384,256,256,
                               8320,64,2048,32,32,1,1048576,131072};
  if (n_in != 28 || out_size != GG) return;
  for (int i=0;i<28;i++) if (in_sizes[i] != want[i]) return;

  const float* x     = (const float*)d_in[0];
  const float* ea    = (const float*)d_in[1];
  const float* tt    = (const float*)d_in[2];
  const float* pp    = (const float*)d_in[3];
  const float* lin1W = (const float*)d_in[4];
  const float* lin1b = (const float*)d_in[5];
  const float* edgeW = (const float*)d_in[6];
  const float* edgeb = (const float*)d_in[7];
  const float* preW  = (const float*)d_in[8];
  const float* preb  = (const float*)d_in[9];
  const float* postW = (const float*)d_in[10];
  const float* postb = (const float*)d_in[11];
  const float* clinW = (const float*)d_in[12];
  const float* clinb = (const float*)d_in[13];
  const float* bng   = (const float*)d_in[14];
  const float* bnb   = (const float*)d_in[15];
  const float* Wih   = (const float*)d_in[16];
  const float* Whh   = (const float*)d_in[17];
  const float* bih   = (const float*)d_in[18];
  const float* bhh   = (const float*)d_in[19];
  const float* W1    = (const float*)d_in[20];
  const float* b1    = (const float*)d_in[21];
  const float* W2    = (const float*)d_in[22];
  const float* b2    = (const float*)d_in[23];
  const float* W3    = (const float*)d_in[24];
  const float* b3    = (const float*)d_in[25];
  const int*   eidx  = (const int*)d_in[26];
  const int*   batch = (const int*)d_in[27];
  const int* esrc = eidx;
  const int* edst = eidx + EE;

  char* w = (char*)d_ws;
  auto alloc = [&](size_t bytes)->char*{ char* p=w; w += ((bytes+255)/256)*256; return p; };
  _Float16* agg  = (_Float16*)alloc((size_t)NN*256*2);  // 64MiB fp16
  _Float16* g12  = (_Float16*)alloc((size_t)NN*128*2);  // 32MiB fp16 (set2set scratch aliases)
  _Float16* hy   = (_Float16*)alloc((size_t)NN*64*2);   // 16MiB fp16: y2/h in place
  int*   deg    = (int*)alloc((size_t)NN*4);
  int*   cursor = (int*)alloc((size_t)NN*4);
  int*   rowptr = (int*)alloc((size_t)(NN+1)*4);
  int*   spart  = (int*)alloc(512*4);
  int*   srcord = (int*)alloc((size_t)EE*4);
  float* eaord  = (float*)alloc((size_t)EE*6*4);
  float* s12   = (float*)alloc((size_t)NN*2*4);
  float* part  = (float*)alloc((size_t)2048*128*4);
  float* bnsc  = (float*)alloc(256);
  float* bnsh  = (float*)alloc(256);
  float* WfG   = (float*)alloc(3*384*4);
  float* bfG   = (float*)alloc(3*64*4);
  int*   gptr  = (int*)alloc((GG+1)*4);
  size_t need = (size_t)(w - (char*)d_ws);
  if (need > ws_size) return;
  float* A    = (float*)g12;
  float* cs   = (float*)g12 + (size_t)GG*128;

  double num = 13107.0*log(2.0)+26214.0*log(3.0)+65536.0*log(4.0)+26215.0*log(5.0);
  float avgdl = (float)(num/131072.0);

  hipMemsetAsync(deg, 0, (size_t)NN*4, stream);
  hipMemsetAsync(cursor, 0, (size_t)NN*4, stream);
  hipLaunchKernelGGL(k_deg, dim3(2048), dim3(256), 0, stream, edst, deg);
  hipLaunchKernelGGL(k_scan_part, dim3(512), dim3(256), 0, stream, deg, spart);
  hipLaunchKernelGGL(k_scan_top, dim3(1), dim3(512), 0, stream, spart);
  hipLaunchKernelGGL(k_scan_apply, dim3(512), dim3(256), 0, stream, deg, spart, rowptr);
  hipLaunchKernelGGL(k_fill, dim3(2048), dim3(256), 0, stream, edst, esrc, ea, rowptr, cursor, srcord, eaord);

  hipLaunchKernelGGL(k_gptr, dim3(17), dim3(256), 0, stream, batch, gptr);
  hipLaunchKernelGGL(k_prepwf, dim3(3), dim3(448), 0, stream, preW, preb, edgeW, edgeb, WfG, bfG);
  hipLaunchKernelGGL(k_lin1_s, dim3(32768), dim3(256), 0, stream, x, lin1W, lin1b, hy);

  for (int i = 0; i < 3; ++i){
    const float* sc_i = (i==0)? nullptr : bnsc;
    const float* sh_i = (i==0)? nullptr : bnsh;
    hipLaunchKernelGGL(k_bnmsg, dim3(2048), dim3(256), 0, stream, hy, sc_i, sh_i,
        preW + (size_t)i*64*192, g12);
    hipLaunchKernelGGL(k_gather_f, dim3(4096), dim3(256), 0, stream, rowptr, srcord, eaord, g12,
        WfG + (size_t)i*384, bfG + (size_t)i*64, agg, s12, avgdl);
    hipLaunchKernelGGL(k_tower_mfma, dim3(2048), dim3(256), 0, stream, hy, agg, s12,
        postW + (size_t)i*64*832, postb + i*64, clinW + (size_t)i*4096, clinb + i*64, part);
    hipLaunchKernelGGL(k_bnfin, dim3(1), dim3(1024), 0, stream, part, bng + i*64, bnb + i*64, bnsc, bnsh);
  }
  hipLaunchKernelGGL(k_bnapply16, dim3(2048), dim3(256), 0, stream, hy, bnsc, bnsh);

  hipMemsetAsync(A, 0, (size_t)GG*128*4, stream);
  hipMemsetAsync(cs, 0, (size_t)GG*64*4, stream);
  for (int s = 0; s < 3; ++s){
    hipLaunchKernelGGL(k_lstm_lit, dim3(512), dim3(256), 0, stream, A, cs, Wih, Whh, bih, bhh);
    hipLaunchKernelGGL(k_attn_f, dim3(GG), dim3(64), 0, stream, hy, gptr, A);
  }
  hipLaunchKernelGGL(k_mlp, dim3(GG), dim3(64), 0, stream, A, tt, pp, W1, b1, W2, b2, W3, b3, (float*)d_out);
}

// Round 24
// 739.611 us; speedup vs baseline: 1.1634x; 1.0220x over previous
//
#include <hip/hip_runtime.h>
#include <hip/hip_bf16.h>
#include <math.h>

#define NN 131072
#define EE 524288
#define GG 4096
#define GCAP 320
#define ACAP 96

typedef __attribute__((ext_vector_type(8))) _Float16 half8;
typedef __attribute__((ext_vector_type(4))) _Float16 half4;
typedef __attribute__((ext_vector_type(4))) float f32x4;

__device__ __forceinline__ float sigmoidf_(float x){ return 1.0f/(1.0f+expf(-x)); }

// ---- grouping / CSR (integer atomics only) --------------------------------
__global__ void k_gptr(const int* batch, int* gptr){
  int g = blockIdx.x*256+threadIdx.x;
  if (g > GG) return;
  if (g == GG){ gptr[GG]=NN; return; }
  int lo=0, hi=NN;
  while(lo<hi){ int mid=(lo+hi)>>1; if(batch[mid]<g) lo=mid+1; else hi=mid; }
  gptr[g]=lo;
}

__global__ void k_deg(const int* dst, int* deg){
  int e = blockIdx.x*256+threadIdx.x;
  if(e<EE) atomicAdd(&deg[dst[e]], 1);
}

// hierarchical scan
__global__ __launch_bounds__(256) void k_scan_part(const int* deg, int* part){
  __shared__ int red[256];
  int b=blockIdx.x, t=threadIdx.x;
  red[t] = deg[b*256+t];
  __syncthreads();
  for(int off=128; off>0; off>>=1){
    if(t<off) red[t]+=red[t+off];
    __syncthreads();
  }
  if(t==0) part[b]=red[0];
}

__global__ __launch_bounds__(512) void k_scan_top(int* part){
  __shared__ int s[512];
  int t=threadIdx.x;
  s[t]=part[t];
  __syncthreads();
  for(int off=1; off<512; off<<=1){
    int v=s[t];
    int add=(t>=off)?s[t-off]:0;
    __syncthreads();
    s[t]=v+add;
    __syncthreads();
  }
  part[t] = (t==0)?0:s[t-1];
}

__global__ __launch_bounds__(256) void k_scan_apply(const int* deg, const int* part, int* rowptr){
  __shared__ int s[256];
  int b=blockIdx.x, t=threadIdx.x;
  int v0=deg[b*256+t];
  s[t]=v0;
  __syncthreads();
  for(int off=1; off<256; off<<=1){
    int v=s[t];
    int add=(t>=off)?s[t-off]:0;
    __syncthreads();
    s[t]=v+add;
    __syncthreads();
  }
  rowptr[b*256+t] = part[b] + s[t]-v0;
  if(b==511 && t==255) rowptr[NN] = part[b] + s[t];
}

// fill CSR-ordered edge streams (ea copy vectorized float2)
__global__ void k_fill(const int* dst, const int* src, const float* ea,
                       const int* rowptr, int* cursor, int* srcord, float* eaord){
  int e = blockIdx.x*256+threadIdx.x;
  if(e>=EE) return;
  int d = dst[e];
  int pos = atomicAdd(&cursor[d], 1);
  int idx = rowptr[d]+pos;
  srcord[idx] = src[e];
  float2 e0 = *(const float2*)&ea[(size_t)e*6];
  float2 e1 = *(const float2*)&ea[(size_t)e*6+2];
  float2 e2 = *(const float2*)&ea[(size_t)e*6+4];
  *(float2*)&eaord[(size_t)idx*6]   = e0;
  *(float2*)&eaord[(size_t)idx*6+2] = e1;
  *(float2*)&eaord[(size_t)idx*6+4] = e2;
}

// ---- all-layers Wf/bf precompute (3 blocks): Wf=W3@eW [64][6], bf=W3@eb+prb
__global__ __launch_bounds__(448) void k_prepwf(const float* preW, const float* preb,
      const float* eW, const float* eb, float* WfG, float* bfG){
  int i = blockIdx.x;            // layer
  const float* pW = preW + (size_t)i*64*192;
  const float* pb = preb + i*64;
  const float* eWl = eW + (size_t)i*384;
  const float* ebl = eb + i*64;
  int t=threadIdx.x;
  if(t<384){
    int j=t/6, d=t-j*6;
    float a=0.0f;
    for(int k=0;k<64;k++) a += pW[(size_t)j*192+128+k]*eWl[k*6+d];
    WfG[i*384+t]=a;
  } else if(t<448){
    int j=t-384;
    float a=pb[j];
    for(int k=0;k<64;k++) a += pW[(size_t)j*192+128+k]*ebl[k];
    bfG[i*64+j]=a;
  }
}

// ---- y0 = x @ lin1W.T + b (pre-activation, fp16); grid-stride, padded sW --
__global__ __launch_bounds__(256) void k_lin1_s(const float* x, const float* W, const float* b, _Float16* y0){
  __shared__ float sW[2112];   // 64*33 padded
  __shared__ float sb[64];
  int t=threadIdx.x;
  for(int i=t;i<2048;i+=256){ int j=i>>5,k=i&31; sW[j*33+k]=W[i]; }
  if(t<64) sb[t]=b[t];
  __syncthreads();
  int w = t>>6, j = t&63;
  // 1024 blocks x 4 waves x 32 iters = 131072 rows; weights staged once/block
  for(int it=0; it<32; ++it){
    int n = (blockIdx.x*4 + w) + it*4096;
    float acc = sb[j];
    #pragma unroll 8
    for(int k=0;k<32;k++) acc += x[(size_t)n*32+k]*sW[j*33+k];
    y0[(size_t)n*64+j] = (_Float16)acc;
  }
}

// ---- k_bnmsg: hy := relu(hy*sc+sh) in place; g12 = h @ [Wd|Ws].T (MFMA) ---
__global__ __launch_bounds__(256) void k_bnmsg(_Float16* hy, const float* sc, const float* sh,
      const float* preW, _Float16* g12){
  __shared__ _Float16 sAh[64][72];
  __shared__ _Float16 sB0[64][72];
  __shared__ _Float16 sB1[64][72];
  __shared__ float ssc[64], ssh[64];
  int t=threadIdx.x;
  int rb = blockIdx.x*64;
  if(t<64){ ssc[t] = sc? sc[t] : 1.0f; ssh[t] = sh? sh[t] : 0.0f; }
  __syncthreads();
  int sr = t>>2, c0 = (t&3)*16;
  {
    half8 y0 = *(const half8*)&hy[(size_t)(rb+sr)*64 + c0];
    half8 y1 = *(const half8*)&hy[(size_t)(rb+sr)*64 + c0 + 8];
    half8 h0, h1;
    #pragma unroll
    for(int q=0;q<8;q++){
      h0[q] = (_Float16)fmaxf((float)y0[q]*ssc[c0+q]   + ssh[c0+q],   0.0f);
      h1[q] = (_Float16)fmaxf((float)y1[q]*ssc[c0+8+q] + ssh[c0+8+q], 0.0f);
    }
    *(half8*)&sAh[sr][c0]   = h0;
    *(half8*)&sAh[sr][c0+8] = h1;
    *(half8*)&hy[(size_t)(rb+sr)*64 + c0]     = h0;
    *(half8*)&hy[(size_t)(rb+sr)*64 + c0 + 8] = h1;
    const float* w0 = &preW[(size_t)sr*192 + c0];
    const float* w1 = &preW[(size_t)sr*192 + 64 + c0];
    float4 a0=*(const float4*)&w0[0], a1=*(const float4*)&w0[4], a2=*(const float4*)&w0[8], a3=*(const float4*)&w0[12];
    float4 b0=*(const float4*)&w1[0], b1=*(const float4*)&w1[4], b2=*(const float4*)&w1[8], b3=*(const float4*)&w1[12];
    half8 w0h, w0h2, w1h, w1h2;
    float wa[16]={a0.x,a0.y,a0.z,a0.w,a1.x,a1.y,a1.z,a1.w,a2.x,a2.y,a2.z,a2.w,a3.x,a3.y,a3.z,a3.w};
    float wb[16]={b0.x,b0.y,b0.z,b0.w,b1.x,b1.y,b1.z,b1.w,b2.x,b2.y,b2.z,b2.w,b3.x,b3.y,b3.z,b3.w};
    #pragma unroll
    for(int q=0;q<8;q++){ w0h[q]=(_Float16)wa[q]; w0h2[q]=(_Float16)wa[8+q]; w1h[q]=(_Float16)wb[q]; w1h2[q]=(_Float16)wb[8+q]; }
    *(half8*)&sB0[sr][c0]   = w0h;  *(half8*)&sB0[sr][c0+8] = w0h2;
    *(half8*)&sB1[sr][c0]   = w1h;  *(half8*)&sB1[sr][c0+8] = w1h2;
  }
  __syncthreads();
  int w=t>>6, l=t&63;
  f32x4 acc0[4]={}, acc1[4]={};
  #pragma unroll
  for(int kk=0; kk<2; ++kk){
    half8 a = *(const half8*)&sAh[w*16+(l&15)][kk*32+(l>>4)*8];
    #pragma unroll
    for(int n16=0;n16<4;++n16){
      half8 b0 = *(const half8*)&sB0[n16*16+(l&15)][kk*32+(l>>4)*8];
      half8 b1 = *(const half8*)&sB1[n16*16+(l&15)][kk*32+(l>>4)*8];
      acc0[n16] = __builtin_amdgcn_mfma_f32_16x16x32_f16(a,b0,acc0[n16],0,0,0);
      acc1[n16] = __builtin_amdgcn_mfma_f32_16x16x32_f16(a,b1,acc1[n16],0,0,0);
    }
  }
  #pragma unroll
  for(int n16=0;n16<4;++n16){
    #pragma unroll
    for(int reg=0; reg<4; ++reg){
      int row = w*16+(l>>4)*4+reg;
      int col = n16*16+(l&15);
      g12[(size_t)(rb+row)*128 + col]      = (_Float16)acc0[n16][reg];
      g12[(size_t)(rb+row)*128 + 64 + col] = (_Float16)acc1[n16][reg];
    }
  }
}

// ---- gather: 32 contiguous nodes/block (4096 blocks); edges prefetched ----
__global__ __launch_bounds__(256) void k_gather_f(const int* rowptr, const int* srcord,
      const float* eaord, const _Float16* g12, const float* WfG, const float* bfG,
      _Float16* agg, float* s12, float avgdl){
  __shared__ float sWf[64][6];
  __shared__ float sbf[64];
  __shared__ int   sRow[33];
  __shared__ int   sSrc[GCAP];
  __shared__ float sEA[GCAP*6];
  int t=threadIdx.x;
  int rb = blockIdx.x*32;
  for(int i=t; i<384; i+=256) ((float*)sWf)[i]=WfG[i];
  if(t<64) sbf[t]=bfG[t];
  if(t<33) sRow[t]=rowptr[rb+t];
  __syncthreads();
  int eLo = sRow[0];
  int cnt = sRow[32]-eLo;
  int ccap = (cnt<GCAP)? cnt : GCAP;
  for(int i=t; i<ccap; i+=256) sSrc[i]=srcord[eLo+i];
  for(int f=t; f<ccap*6; f+=256) sEA[f]=eaord[(size_t)eLo*6+f];
  __syncthreads();
  int w=t>>6, j=t&63;
  float wf0=sWf[j][0], wf1=sWf[j][1], wf2=sWf[j][2];
  float wf3=sWf[j][3], wf4=sWf[j][4], wf5=sWf[j][5];
  float bfj=sbf[j];
  for(int q=0; q<8; ++q){
    int ln = w*8 + q;
    int n  = rb + ln;
    int lo = sRow[ln], hi = sRow[ln+1];
    float mdst = (float)g12[(size_t)n*128+j] + bfj;
    float sum=0.0f, sq=0.0f, mn=1e30f, mx=-1e30f;
    int idx=lo;
    for(; idx+1<hi; idx+=2){
      int r0 = idx-eLo, r1 = r0+1;
      int s0, s1;
      float e00,e01,e02,e03,e04,e05, e10,e11,e12,e13,e14,e15;
      if(r1 < GCAP){
        s0=sSrc[r0]; s1=sSrc[r1];
        e00=sEA[r0*6+0]; e01=sEA[r0*6+1]; e02=sEA[r0*6+2]; e03=sEA[r0*6+3]; e04=sEA[r0*6+4]; e05=sEA[r0*6+5];
        e10=sEA[r1*6+0]; e11=sEA[r1*6+1]; e12=sEA[r1*6+2]; e13=sEA[r1*6+3]; e14=sEA[r1*6+4]; e15=sEA[r1*6+5];
      } else {
        s0=srcord[idx]; s1=srcord[idx+1];
        e00=eaord[(size_t)idx*6+0]; e01=eaord[(size_t)idx*6+1]; e02=eaord[(size_t)idx*6+2];
        e03=eaord[(size_t)idx*6+3]; e04=eaord[(size_t)idx*6+4]; e05=eaord[(size_t)idx*6+5];
        e10=eaord[(size_t)(idx+1)*6+0]; e11=eaord[(size_t)(idx+1)*6+1]; e12=eaord[(size_t)(idx+1)*6+2];
        e13=eaord[(size_t)(idx+1)*6+3]; e14=eaord[(size_t)(idx+1)*6+4]; e15=eaord[(size_t)(idx+1)*6+5];
      }
      float g0 = (float)g12[(size_t)s0*128+64+j];
      float g1 = (float)g12[(size_t)s1*128+64+j];
      float m0 = mdst + g0 + e00*wf0 + e01*wf1 + e02*wf2 + e03*wf3 + e04*wf4 + e05*wf5;
      float m1 = mdst + g1 + e10*wf0 + e11*wf1 + e12*wf2 + e13*wf3 + e14*wf4 + e15*wf5;
      sum += m0; sq += m0*m0; mn = fminf(mn,m0); mx = fmaxf(mx,m0);
      sum += m1; sq += m1*m1; mn = fminf(mn,m1); mx = fmaxf(mx,m1);
    }
    if(idx<hi){
      int r0 = idx-eLo;
      int s0; float e00,e01,e02,e03,e04,e05;
      if(r0 < GCAP){
        s0=sSrc[r0];
        e00=sEA[r0*6+0]; e01=sEA[r0*6+1]; e02=sEA[r0*6+2]; e03=sEA[r0*6+3]; e04=sEA[r0*6+4]; e05=sEA[r0*6+5];
      } else {
        s0=srcord[idx];
        e00=eaord[(size_t)idx*6+0]; e01=eaord[(size_t)idx*6+1]; e02=eaord[(size_t)idx*6+2];
        e03=eaord[(size_t)idx*6+3]; e04=eaord[(size_t)idx*6+4]; e05=eaord[(size_t)idx*6+5];
      }
      float g0 = (float)g12[(size_t)s0*128+64+j];
      float m0 = mdst + g0 + e00*wf0 + e01*wf1 + e02*wf2 + e03*wf3 + e04*wf4 + e05*wf5;
      sum += m0; sq += m0*m0; mn = fminf(mn,m0); mx = fmaxf(mx,m0);
    }
    int c = hi-lo;
    float cm = fmaxf((float)c, 1.0f);
    float mean = sum/cm;
    float sd = sqrtf(fmaxf(sq/cm - mean*mean, 0.0f)+1e-5f);
    bool has = c>0;
    size_t base = (size_t)n*256;
    agg[base+j]     = (_Float16)mean;
    agg[base+64+j]  = (_Float16)(has?mn:0.0f);
    agg[base+128+j] = (_Float16)(has?mx:0.0f);
    agg[base+192+j] = (_Float16)sd;
    if(j==0){ float ld=logf(cm+1.0f); s12[n*2]=ld/avgdl; s12[n*2+1]=avgdl/ld; }
  }
}

// ---- k_tower_mfma v2: z-split (agg staged once/k-tile; s1,s2 in epilogue) -
__global__ __launch_bounds__(256) void k_tower_mfma(_Float16* hy, const _Float16* agg, const float* s12,
        const float* poW, const float* pob, const float* clW, const float* clb, float* part){
  __shared__ _Float16 sAh[64][72];
  __shared__ _Float16 sBh[64][72];
  __shared__ float sS[128];
  __shared__ float sredS[16][64];
  __shared__ float sredQ[16][64];
  int t = threadIdx.x;
  int rb = blockIdx.x*64;
  int w = t>>6, l = t&63;
  int sr = t>>2, c0 = (t&3)*16;
  if (t < 128) sS[t] = s12[(size_t)(rb+(t>>1))*2 + (t&1)];
  f32x4 hacc[4]={}, z0a[4]={}, z1a[4]={}, z2a[4]={};
  auto stageB = [&](const float* wr){
    float4 a0=*(const float4*)&wr[0], a1=*(const float4*)&wr[4], a2=*(const float4*)&wr[8], a3=*(const float4*)&wr[12];
    float wa[16]={a0.x,a0.y,a0.z,a0.w,a1.x,a1.y,a1.z,a1.w,a2.x,a2.y,a2.z,a2.w,a3.x,a3.y,a3.z,a3.w};
    half8 b0, b1;
    #pragma unroll
    for(int q=0;q<8;q++){ b0[q]=(_Float16)wa[q]; b1[q]=(_Float16)wa[8+q]; }
    *(half8*)&sBh[sr][c0]   = b0;
    *(half8*)&sBh[sr][c0+8] = b1;
  };
  auto mfma8 = [&](f32x4* acc){
    #pragma unroll
    for (int kk=0; kk<2; ++kk){
      half8 a = *(const half8*)&sAh[w*16 + (l&15)][kk*32 + (l>>4)*8];
      #pragma unroll
      for (int n16=0; n16<4; ++n16){
        half8 b = *(const half8*)&sBh[n16*16 + (l&15)][kk*32 + (l>>4)*8];
        acc[n16] = __builtin_amdgcn_mfma_f32_16x16x32_f16(a, b, acc[n16], 0, 0, 0);
      }
    }
  };
  {
    *(half8*)&sAh[sr][c0]   = *(const half8*)&hy[(size_t)(rb+sr)*64 + c0];
    *(half8*)&sAh[sr][c0+8] = *(const half8*)&hy[(size_t)(rb+sr)*64 + c0 + 8];
    stageB(&poW[(size_t)sr*832 + c0]);
  }
  __syncthreads();
  mfma8(hacc);
  for (int kt=0; kt<4; ++kt){
    __syncthreads();
    *(half8*)&sAh[sr][c0]   = *(const half8*)&agg[(size_t)(rb+sr)*256 + kt*64 + c0];
    *(half8*)&sAh[sr][c0+8] = *(const half8*)&agg[(size_t)(rb+sr)*256 + kt*64 + c0 + 8];
    stageB(&poW[(size_t)sr*832 + 64 + kt*64 + c0]);
    __syncthreads();
    mfma8(z0a);
    __syncthreads();
    stageB(&poW[(size_t)sr*832 + 64 + 256 + kt*64 + c0]);
    __syncthreads();
    mfma8(z1a);
    __syncthreads();
    stageB(&poW[(size_t)sr*832 + 64 + 512 + kt*64 + c0]);
    __syncthreads();
    mfma8(z2a);
  }
  __syncthreads();
  #pragma unroll
  for (int n16=0; n16<4; ++n16){
    #pragma unroll
    for (int reg=0; reg<4; ++reg){
      int row = w*16 + (l>>4)*4 + reg;
      int col = n16*16 + (l&15);
      float s1v = sS[row*2], s2v = sS[row*2+1];
      float v = hacc[n16][reg] + z0a[n16][reg] + s1v*z1a[n16][reg] + s2v*z2a[n16][reg] + pob[col];
      sAh[row][col] = (_Float16)v;
    }
  }
  stageB(&clW[(size_t)sr*64 + c0]);
  __syncthreads();
  f32x4 cacc[4] = {};
  mfma8(cacc);
  float cs_[4], cq_[4];
  #pragma unroll
  for (int n16=0; n16<4; ++n16){ cs_[n16]=0.0f; cq_[n16]=0.0f; }
  #pragma unroll
  for (int n16=0; n16<4; ++n16){
    #pragma unroll
    for (int reg=0; reg<4; ++reg){
      int row = w*16 + (l>>4)*4 + reg;
      int col = n16*16 + (l&15);
      float v = cacc[n16][reg] + clb[col];
      hy[(size_t)(rb+row)*64 + col] = (_Float16)v;
      cs_[n16] += v; cq_[n16] += v*v;
    }
  }
  int slot = w*4 + (l>>4);
  #pragma unroll
  for (int n16=0; n16<4; ++n16){
    int col = n16*16 + (l&15);
    sredS[slot][col] = cs_[n16];
    sredQ[slot][col] = cq_[n16];
  }
  __syncthreads();
  if (t < 64){
    float S=0.0f, Q=0.0f;
    #pragma unroll
    for(int q2=0;q2<16;q2++){ S += sredS[q2][t]; Q += sredQ[q2][t]; }
    part[(size_t)blockIdx.x*128 + t]      = S;
    part[(size_t)blockIdx.x*128 + 64 + t] = Q;
  }
}

// ---- BN finalize: hierarchical (1024 thr = 64 cols x 16 chunks) -----------
__global__ __launch_bounds__(1024) void k_bnfin(const float* part, const float* g, const float* bb,
                                                float* sc, float* sh){
  __shared__ double sS[16][64], sQ[16][64];
  int t = threadIdx.x;
  int c = t&63, chunk = t>>6;
  double S=0.0, Q=0.0;
  for(int b=chunk; b<2048; b+=16){
    S += (double)part[(size_t)b*128 + c];
    Q += (double)part[(size_t)b*128 + 64 + c];
  }
  sS[chunk][c]=S; sQ[chunk][c]=Q;
  __syncthreads();
  if(t<64){
    double St=0.0, Qt=0.0;
    #pragma unroll
    for(int q=0;q<16;q++){ St+=sS[q][t]; Qt+=sQ[q][t]; }
    double mean = St/(double)NN;
    double var  = Qt/(double)NN - mean*mean;
    float scale = g[t] * (float)(1.0/sqrt(var+1e-5));
    sc[t]=scale;
    sh[t]=bb[t] - (float)mean*scale;
  }
}

// ---- final BN apply in place on hy (fp16) ---------------------------------
__global__ void k_bnapply16(_Float16* hy, const float* sc, const float* sh){
  int idx = blockIdx.x*256+threadIdx.x;
  for(int i=idx; i<NN*8; i+=256*2048){
    int c0 = (i&7)*8;
    half8 v = *(const half8*)&hy[(size_t)i*8];
    half8 r;
    #pragma unroll
    for(int q=0;q<8;q++) r[q]=(_Float16)fmaxf((float)v[q]*sc[c0+q]+sh[c0+q],0.0f);
    *(half8*)&hy[(size_t)i*8] = r;
  }
}

// ---- set2set LSTM: 8 graphs/block, float4 weights reused x8, 8 acc chains -
__global__ __launch_bounds__(256) void k_lstm_lit(float* A, float* cs,
      const float* Wih, const float* Whh, const float* bih, const float* bhh){
  __shared__ float sA[8][128];
  __shared__ float sg[8][256];
  int t=threadIdx.x;
  int g0 = blockIdx.x*8;
  for(int i=t;i<1024;i+=256) sA[i>>7][i&127] = A[(size_t)(g0+(i>>7))*128 + (i&127)];
  __syncthreads();
  float bb2 = bih[t]+bhh[t];
  float acc[8];
  #pragma unroll
  for(int g=0;g<8;g++) acc[g]=bb2;
  for(int k=0;k<128;k+=4){
    float4 wv = *(const float4*)&Wih[(size_t)t*128+k];
    #pragma unroll
    for(int g=0;g<8;g++)
      acc[g] += wv.x*sA[g][k] + wv.y*sA[g][k+1] + wv.z*sA[g][k+2] + wv.w*sA[g][k+3];
  }
  for(int k=0;k<64;k+=4){
    float4 wv = *(const float4*)&Whh[(size_t)t*64+k];
    #pragma unroll
    for(int g=0;g<8;g++)
      acc[g] += wv.x*sA[g][k] + wv.y*sA[g][k+1] + wv.z*sA[g][k+2] + wv.w*sA[g][k+3];
  }
  #pragma unroll
  for(int g=0;g<8;g++) sg[g][t]=acc[g];
  __syncthreads();
  for(int i=t;i<512;i+=256){
    int g=i>>6, j=i&63;
    float ig=sg[g][j], fg=sg[g][64+j], gg=sg[g][128+j], og=sg[g][192+j];
    float c = sigmoidf_(fg)*cs[(size_t)(g0+g)*64+j] + sigmoidf_(ig)*tanhf(gg);
    float hv = sigmoidf_(og)*tanhf(c);
    cs[(size_t)(g0+g)*64+j]=c;
    A[(size_t)(g0+g)*128+j]=hv;
  }
}

// ---- fused edot+attn v2: parallel e-compute (lane i owns node i) ----------
__global__ __launch_bounds__(64) void k_attn_f(const _Float16* h16, const int* gptr, float* A){
  __shared__ _Float16 sH[ACAP][66];   // padded: row stride 132B -> 2-way max
  __shared__ float sE[ACAP];
  __shared__ float saq[64];
  int g=blockIdx.x, j=threadIdx.x;
  int lo=gptr[g], hi=gptr[g+1];
  int cnt=hi-lo;
  if(cnt<=0){ A[(size_t)g*128+64+j]=0.0f; return; }
  float aq = A[(size_t)g*128+j];
  saq[j]=aq;
  if(cnt<=ACAP){
    for(int i=0;i<cnt;++i) sH[i][j] = h16[(size_t)(lo+i)*64+j];
    __syncthreads();
    for(int i=j;i<cnt;i+=64){
      float v=0.0f;
      for(int k=0;k<64;k++) v += (float)sH[i][k]*saq[k];
      sE[i]=v;
    }
    __syncthreads();
    float mx=-1e30f;
    for(int i=j;i<cnt;i+=64) mx=fmaxf(mx,sE[i]);
    #pragma unroll
    for(int m=32;m;m>>=1) mx=fmaxf(mx,__shfl_xor(mx,m,64));
    float s=0.0f;
    for(int i=j;i<cnt;i+=64) s+=expf(sE[i]-mx);
    #pragma unroll
    for(int m=32;m;m>>=1) s+=__shfl_xor(s,m,64);
    float inv=1.0f/(s+1e-16f);
    for(int i=j;i<cnt;i+=64) sE[i]=expf(sE[i]-mx)*inv;
    __syncthreads();
    float r=0.0f;
    for(int i=0;i<cnt;++i) r += sE[i]*(float)sH[i][j];
    A[(size_t)g*128+64+j]=r;
  } else {
    float mx=-1e30f;
    for(int n=lo;n<hi;++n){
      float v=(float)h16[(size_t)n*64+j]*aq;
      #pragma unroll
      for(int m=32;m;m>>=1) v+=__shfl_xor(v,m,64);
      mx=fmaxf(mx,v);
    }
    float s=0.0f;
    for(int n=lo;n<hi;++n){
      float v=(float)h16[(size_t)n*64+j]*aq;
      #pragma unroll
      for(int m=32;m;m>>=1) v+=__shfl_xor(v,m,64);
      s+=expf(v-mx);
    }
    float inv=1.0f/(s+1e-16f);
    float r=0.0f;
    for(int n=lo;n<hi;++n){
      float v=(float)h16[(size_t)n*64+j]*aq;
      #pragma unroll
      for(int m=32;m;m>>=1) v+=__shfl_xor(v,m,64);
      r+=expf(v-mx)*inv*(float)h16[(size_t)n*64+j];
    }
    A[(size_t)g*128+64+j]=r;
  }
}

__global__ __launch_bounds__(64) void k_mlp(const float* A, const float* tt, const float* pp,
     const float* W1,const float* b1,const float* W2,const float* b2,const float* W3,const float* b3,
     float* out){
  __shared__ float si[130]; __shared__ float o1[64]; __shared__ float o2[32];
  int g=blockIdx.x, t=threadIdx.x;
  si[t]=A[g*128+t]; si[64+t]=A[g*128+64+t];
  if(t==0){ si[128]=tt[g]; si[129]=pp[g]; }
  __syncthreads();
  float a=b1[t];
  for(int k=0;k<130;k++) a+=W1[t*130+k]*si[k];
  o1[t]=fmaxf(a,0.0f);
  __syncthreads();
  if(t<32){
    float a2=b2[t];
    #pragma unroll 4
    for(int k=0;k<64;k++) a2+=W2[t*64+k]*o1[k];
    o2[t]=fmaxf(a2,0.0f);
  }
  __syncthreads();
  float v = (t<32)? o2[t]*W3[t] : 0.0f;
  #pragma unroll
  for(int m=32;m;m>>=1) v+=__shfl_xor(v,m,64);
  if(t==0) out[g]=v+b3[0];
}

// ---- host -----------------------------------------------------------------
extern "C" void kernel_launch(void* const* d_in, const int* in_sizes, int n_in,
                              void* d_out, int out_size, void* d_ws, size_t ws_size,
                              hipStream_t stream) {
  static const int want[28] = {4194304,3145728,4096,4096,2048,64,1152,192,36864,192,
                               159744,192,12288,192,192,192,32768,16384,256,256,
                               8320,64,2048,32,32,1,1048576,131072};
  if (n_in != 28 || out_size != GG) return;
  for (int i=0;i<28;i++) if (in_sizes[i] != want[i]) return;

  const float* x     = (const float*)d_in[0];
  const float* ea    = (const float*)d_in[1];
  const float* tt    = (const float*)d_in[2];
  const float* pp    = (const float*)d_in[3];
  const float* lin1W = (const float*)d_in[4];
  const float* lin1b = (const float*)d_in[5];
  const float* edgeW = (const float*)d_in[6];
  const float* edgeb = (const float*)d_in[7];
  const float* preW  = (const float*)d_in[8];
  const float* preb  = (const float*)d_in[9];
  const float* postW = (const float*)d_in[10];
  const float* postb = (const float*)d_in[11];
  const float* clinW = (const float*)d_in[12];
  const float* clinb = (const float*)d_in[13];
  const float* bng   = (const float*)d_in[14];
  const float* bnb   = (const float*)d_in[15];
  const float* Wih   = (const float*)d_in[16];
  const float* Whh   = (const float*)d_in[17];
  const float* bih   = (const float*)d_in[18];
  const float* bhh   = (const float*)d_in[19];
  const float* W1    = (const float*)d_in[20];
  const float* b1    = (const float*)d_in[21];
  const float* W2    = (const float*)d_in[22];
  const float* b2    = (const float*)d_in[23];
  const float* W3    = (const float*)d_in[24];
  const float* b3    = (const float*)d_in[25];
  const int*   eidx  = (const int*)d_in[26];
  const int*   batch = (const int*)d_in[27];
  const int* esrc = eidx;
  const int* edst = eidx + EE;

  char* w = (char*)d_ws;
  auto alloc = [&](size_t bytes)->char*{ char* p=w; w += ((bytes+255)/256)*256; return p; };
  _Float16* agg  = (_Float16*)alloc((size_t)NN*256*2);  // 64MiB fp16
  _Float16* g12  = (_Float16*)alloc((size_t)NN*128*2);  // 32MiB fp16 (set2set scratch aliases)
  _Float16* hy   = (_Float16*)alloc((size_t)NN*64*2);   // 16MiB fp16: y2/h in place
  int*   deg    = (int*)alloc((size_t)NN*4);
  int*   cursor = (int*)alloc((size_t)NN*4);
  int*   rowptr = (int*)alloc((size_t)(NN+1)*4);
  int*   spart  = (int*)alloc(512*4);
  int*   srcord = (int*)alloc((size_t)EE*4);
  float* eaord  = (float*)alloc((size_t)EE*6*4);
  float* s12   = (float*)alloc((size_t)NN*2*4);
  float* part  = (float*)alloc((size_t)2048*128*4);
  float* bnsc  = (float*)alloc(256);
  float* bnsh  = (float*)alloc(256);
  float* WfG   = (float*)alloc(3*384*4);
  float* bfG   = (float*)alloc(3*64*4);
  int*   gptr  = (int*)alloc((GG+1)*4);
  size_t need = (size_t)(w - (char*)d_ws);
  if (need > ws_size) return;
  float* A    = (float*)g12;
  float* cs   = (float*)g12 + (size_t)GG*128;

  double num = 13107.0*log(2.0)+26214.0*log(3.0)+65536.0*log(4.0)+26215.0*log(5.0);
  float avgdl = (float)(num/131072.0);

  hipMemsetAsync(deg, 0, (size_t)NN*4, stream);
  hipMemsetAsync(cursor, 0, (size_t)NN*4, stream);
  hipLaunchKernelGGL(k_deg, dim3(2048), dim3(256), 0, stream, edst, deg);
  hipLaunchKernelGGL(k_scan_part, dim3(512), dim3(256), 0, stream, deg, spart);
  hipLaunchKernelGGL(k_scan_top, dim3(1), dim3(512), 0, stream, spart);
  hipLaunchKernelGGL(k_scan_apply, dim3(512), dim3(256), 0, stream, deg, spart, rowptr);
  hipLaunchKernelGGL(k_fill, dim3(2048), dim3(256), 0, stream, edst, esrc, ea, rowptr, cursor, srcord, eaord);

  hipLaunchKernelGGL(k_gptr, dim3(17), dim3(256), 0, stream, batch, gptr);
  hipLaunchKernelGGL(k_prepwf, dim3(3), dim3(448), 0, stream, preW, preb, edgeW, edgeb, WfG, bfG);
  hipLaunchKernelGGL(k_lin1_s, dim3(1024), dim3(256), 0, stream, x, lin1W, lin1b, hy);

  for (int i = 0; i < 3; ++i){
    const float* sc_i = (i==0)? nullptr : bnsc;
    const float* sh_i = (i==0)? nullptr : bnsh;
    hipLaunchKernelGGL(k_bnmsg, dim3(2048), dim3(256), 0, stream, hy, sc_i, sh_i,
        preW + (size_t)i*64*192, g12);
    hipLaunchKernelGGL(k_gather_f, dim3(4096), dim3(256), 0, stream, rowptr, srcord, eaord, g12,
        WfG + (size_t)i*384, bfG + (size_t)i*64, agg, s12, avgdl);
    hipLaunchKernelGGL(k_tower_mfma, dim3(2048), dim3(256), 0, stream, hy, agg, s12,
        postW + (size_t)i*64*832, postb + i*64, clinW + (size_t)i*4096, clinb + i*64, part);
    hipLaunchKernelGGL(k_bnfin, dim3(1), dim3(1024), 0, stream, part, bng + i*64, bnb + i*64, bnsc, bnsh);
  }
  hipLaunchKernelGGL(k_bnapply16, dim3(2048), dim3(256), 0, stream, hy, bnsc, bnsh);

  hipMemsetAsync(A, 0, (size_t)GG*128*4, stream);
  hipMemsetAsync(cs, 0, (size_t)GG*64*4, stream);
  for (int s = 0; s < 3; ++s){
    hipLaunchKernelGGL(k_lstm_lit, dim3(512), dim3(256), 0, stream, A, cs, Wih, Whh, bih, bhh);
    hipLaunchKernelGGL(k_attn_f, dim3(GG), dim3(64), 0, stream, hy, gptr, A);
  }
  hipLaunchKernelGGL(k_mlp, dim3(GG), dim3(64), 0, stream, A, tt, pp, W1, b1, W2, b2, W3, b3, (float*)d_out);
}

// Round 25
// 694.660 us; speedup vs baseline: 1.2387x; 1.0647x over previous
//
#include <hip/hip_runtime.h>
#include <hip/hip_bf16.h>
#include <math.h>

#define NN 131072
#define EE 524288
#define GG 4096
#define GCAP 320
#define ACAP 96

typedef __attribute__((ext_vector_type(8))) _Float16 half8;
typedef __attribute__((ext_vector_type(4))) _Float16 half4;
typedef __attribute__((ext_vector_type(4))) float f32x4;

__device__ __forceinline__ float sigmoidf_(float x){ return 1.0f/(1.0f+expf(-x)); }

// ---- grouping / CSR (integer atomics only) --------------------------------
__global__ void k_gptr(const int* batch, int* gptr){
  int g = blockIdx.x*256+threadIdx.x;
  if (g > GG) return;
  if (g == GG){ gptr[GG]=NN; return; }
  int lo=0, hi=NN;
  while(lo<hi){ int mid=(lo+hi)>>1; if(batch[mid]<g) lo=mid+1; else hi=mid; }
  gptr[g]=lo;
}

__global__ void k_deg(const int* dst, int* deg){
  int e = blockIdx.x*256+threadIdx.x;
  if(e<EE) atomicAdd(&deg[dst[e]], 1);
}

// hierarchical scan
__global__ __launch_bounds__(256) void k_scan_part(const int* deg, int* part){
  __shared__ int red[256];
  int b=blockIdx.x, t=threadIdx.x;
  red[t] = deg[b*256+t];
  __syncthreads();
  for(int off=128; off>0; off>>=1){
    if(t<off) red[t]+=red[t+off];
    __syncthreads();
  }
  if(t==0) part[b]=red[0];
}

__global__ __launch_bounds__(512) void k_scan_top(int* part){
  __shared__ int s[512];
  int t=threadIdx.x;
  s[t]=part[t];
  __syncthreads();
  for(int off=1; off<512; off<<=1){
    int v=s[t];
    int add=(t>=off)?s[t-off]:0;
    __syncthreads();
    s[t]=v+add;
    __syncthreads();
  }
  part[t] = (t==0)?0:s[t-1];
}

__global__ __launch_bounds__(256) void k_scan_apply(const int* deg, const int* part, int* rowptr){
  __shared__ int s[256];
  int b=blockIdx.x, t=threadIdx.x;
  int v0=deg[b*256+t];
  s[t]=v0;
  __syncthreads();
  for(int off=1; off<256; off<<=1){
    int v=s[t];
    int add=(t>=off)?s[t-off]:0;
    __syncthreads();
    s[t]=v+add;
    __syncthreads();
  }
  rowptr[b*256+t] = part[b] + s[t]-v0;
  if(b==511 && t==255) rowptr[NN] = part[b] + s[t];
}

// fill CSR-ordered edge streams (ea copy vectorized float2)
__global__ void k_fill(const int* dst, const int* src, const float* ea,
                       const int* rowptr, int* cursor, int* srcord, float* eaord){
  int e = blockIdx.x*256+threadIdx.x;
  if(e>=EE) return;
  int d = dst[e];
  int pos = atomicAdd(&cursor[d], 1);
  int idx = rowptr[d]+pos;
  srcord[idx] = src[e];
  float2 e0 = *(const float2*)&ea[(size_t)e*6];
  float2 e1 = *(const float2*)&ea[(size_t)e*6+2];
  float2 e2 = *(const float2*)&ea[(size_t)e*6+4];
  *(float2*)&eaord[(size_t)idx*6]   = e0;
  *(float2*)&eaord[(size_t)idx*6+2] = e1;
  *(float2*)&eaord[(size_t)idx*6+4] = e2;
}

// ---- all-layers Wf/bf precompute (3 blocks) -------------------------------
__global__ __launch_bounds__(448) void k_prepwf(const float* preW, const float* preb,
      const float* eW, const float* eb, float* WfG, float* bfG){
  int i = blockIdx.x;
  const float* pW = preW + (size_t)i*64*192;
  const float* pb = preb + i*64;
  const float* eWl = eW + (size_t)i*384;
  const float* ebl = eb + i*64;
  int t=threadIdx.x;
  if(t<384){
    int j=t/6, d=t-j*6;
    float a=0.0f;
    for(int k=0;k<64;k++) a += pW[(size_t)j*192+128+k]*eWl[k*6+d];
    WfG[i*384+t]=a;
  } else if(t<448){
    int j=t-384;
    float a=pb[j];
    for(int k=0;k<64;k++) a += pW[(size_t)j*192+128+k]*ebl[k];
    bfG[i*64+j]=a;
  }
}

// ---- weights -> fp16 once (bit-identical to per-use conversion) -----------
__global__ void k_prepw16(const float* preW, const float* poW, const float* clW,
                          _Float16* preW16, _Float16* poW16, _Float16* clW16){
  int i = blockIdx.x*256 + threadIdx.x;
  if(i < 36864) preW16[i] = (_Float16)preW[i];
  else if(i < 36864+159744) poW16[i-36864] = (_Float16)poW[i-36864];
  else if(i < 36864+159744+12288) clW16[i-196608] = (_Float16)clW[i-196608];
}

// ---- y0 = x @ lin1W.T + b (pre-activation, fp16); grid-stride, padded sW --
__global__ __launch_bounds__(256) void k_lin1_s(const float* x, const float* W, const float* b, _Float16* y0){
  __shared__ float sW[2112];
  __shared__ float sb[64];
  int t=threadIdx.x;
  for(int i=t;i<2048;i+=256){ int j=i>>5,k=i&31; sW[j*33+k]=W[i]; }
  if(t<64) sb[t]=b[t];
  __syncthreads();
  int w = t>>6, j = t&63;
  for(int it=0; it<32; ++it){
    int n = (blockIdx.x*4 + w) + it*4096;
    float acc = sb[j];
    #pragma unroll 8
    for(int k=0;k<32;k++) acc += x[(size_t)n*32+k]*sW[j*33+k];
    y0[(size_t)n*64+j] = (_Float16)acc;
  }
}

// ---- k_bnmsg: hy := relu(hy*sc+sh) in place; g12 = h @ [Wd|Ws].T (MFMA) ---
__global__ __launch_bounds__(256) void k_bnmsg(_Float16* hy, const float* sc, const float* sh,
      const _Float16* preW16, _Float16* g12){
  __shared__ _Float16 sAh[64][72];
  __shared__ _Float16 sB0[64][72];
  __shared__ _Float16 sB1[64][72];
  __shared__ float ssc[64], ssh[64];
  int t=threadIdx.x;
  int rb = blockIdx.x*64;
  if(t<64){ ssc[t] = sc? sc[t] : 1.0f; ssh[t] = sh? sh[t] : 0.0f; }
  __syncthreads();
  int sr = t>>2, c0 = (t&3)*16;
  {
    half8 y0 = *(const half8*)&hy[(size_t)(rb+sr)*64 + c0];
    half8 y1 = *(const half8*)&hy[(size_t)(rb+sr)*64 + c0 + 8];
    half8 h0, h1;
    #pragma unroll
    for(int q=0;q<8;q++){
      h0[q] = (_Float16)fmaxf((float)y0[q]*ssc[c0+q]   + ssh[c0+q],   0.0f);
      h1[q] = (_Float16)fmaxf((float)y1[q]*ssc[c0+8+q] + ssh[c0+8+q], 0.0f);
    }
    *(half8*)&sAh[sr][c0]   = h0;
    *(half8*)&sAh[sr][c0+8] = h1;
    *(half8*)&hy[(size_t)(rb+sr)*64 + c0]     = h0;
    *(half8*)&hy[(size_t)(rb+sr)*64 + c0 + 8] = h1;
    const _Float16* w0 = &preW16[(size_t)sr*192 + c0];
    const _Float16* w1 = &preW16[(size_t)sr*192 + 64 + c0];
    *(half8*)&sB0[sr][c0]   = *(const half8*)&w0[0];
    *(half8*)&sB0[sr][c0+8] = *(const half8*)&w0[8];
    *(half8*)&sB1[sr][c0]   = *(const half8*)&w1[0];
    *(half8*)&sB1[sr][c0+8] = *(const half8*)&w1[8];
  }
  __syncthreads();
  int w=t>>6, l=t&63;
  f32x4 acc0[4]={}, acc1[4]={};
  #pragma unroll
  for(int kk=0; kk<2; ++kk){
    half8 a = *(const half8*)&sAh[w*16+(l&15)][kk*32+(l>>4)*8];
    #pragma unroll
    for(int n16=0;n16<4;++n16){
      half8 b0 = *(const half8*)&sB0[n16*16+(l&15)][kk*32+(l>>4)*8];
      half8 b1 = *(const half8*)&sB1[n16*16+(l&15)][kk*32+(l>>4)*8];
      acc0[n16] = __builtin_amdgcn_mfma_f32_16x16x32_f16(a,b0,acc0[n16],0,0,0);
      acc1[n16] = __builtin_amdgcn_mfma_f32_16x16x32_f16(a,b1,acc1[n16],0,0,0);
    }
  }
  #pragma unroll
  for(int n16=0;n16<4;++n16){
    #pragma unroll
    for(int reg=0; reg<4; ++reg){
      int row = w*16+(l>>4)*4+reg;
      int col = n16*16+(l&15);
      g12[(size_t)(rb+row)*128 + col]      = (_Float16)acc0[n16][reg];
      g12[(size_t)(rb+row)*128 + 64 + col] = (_Float16)acc1[n16][reg];
    }
  }
}

// ---- gather: 32 contiguous nodes/block; edges prefetched; sEA stride-8 ----
__global__ __launch_bounds__(256) void k_gather_f(const int* rowptr, const int* srcord,
      const float* eaord, const _Float16* g12, const float* WfG, const float* bfG,
      _Float16* agg, float* s12, float avgdl){
  __shared__ float sWf[64][6];
  __shared__ float sbf[64];
  __shared__ int   sRow[33];
  __shared__ int   sSrc[GCAP];
  __shared__ float sEA[GCAP][8];
  int t=threadIdx.x;
  int rb = blockIdx.x*32;
  for(int i=t; i<384; i+=256) ((float*)sWf)[i]=WfG[i];
  if(t<64) sbf[t]=bfG[t];
  if(t<33) sRow[t]=rowptr[rb+t];
  __syncthreads();
  int eLo = sRow[0];
  int cnt = sRow[32]-eLo;
  int ccap = (cnt<GCAP)? cnt : GCAP;
  for(int i=t; i<ccap; i+=256) sSrc[i]=srcord[eLo+i];
  for(int i=t; i<ccap; i+=256){
    float2 e0 = *(const float2*)&eaord[(size_t)(eLo+i)*6];
    float2 e1 = *(const float2*)&eaord[(size_t)(eLo+i)*6+2];
    float2 e2 = *(const float2*)&eaord[(size_t)(eLo+i)*6+4];
    *(float2*)&sEA[i][0]=e0;
    *(float2*)&sEA[i][2]=e1;
    *(float2*)&sEA[i][4]=e2;
  }
  __syncthreads();
  int w=t>>6, j=t&63;
  float wf0=sWf[j][0], wf1=sWf[j][1], wf2=sWf[j][2];
  float wf3=sWf[j][3], wf4=sWf[j][4], wf5=sWf[j][5];
  float bfj=sbf[j];
  for(int q=0; q<8; ++q){
    int ln = w*8 + q;
    int n  = rb + ln;
    int lo = sRow[ln], hi = sRow[ln+1];
    float mdst = (float)g12[(size_t)n*128+j] + bfj;
    float sum=0.0f, sq=0.0f, mn=1e30f, mx=-1e30f;
    int idx=lo;
    for(; idx+1<hi; idx+=2){
      int r0 = idx-eLo, r1 = r0+1;
      int s0, s1;
      float e00,e01,e02,e03,e04,e05, e10,e11,e12,e13,e14,e15;
      if(r1 < GCAP){
        s0=sSrc[r0]; s1=sSrc[r1];
        float4 va = *(const float4*)&sEA[r0][0];
        float2 vb = *(const float2*)&sEA[r0][4];
        float4 wa = *(const float4*)&sEA[r1][0];
        float2 wb = *(const float2*)&sEA[r1][4];
        e00=va.x; e01=va.y; e02=va.z; e03=va.w; e04=vb.x; e05=vb.y;
        e10=wa.x; e11=wa.y; e12=wa.z; e13=wa.w; e14=wb.x; e15=wb.y;
      } else {
        s0=srcord[idx]; s1=srcord[idx+1];
        e00=eaord[(size_t)idx*6+0]; e01=eaord[(size_t)idx*6+1]; e02=eaord[(size_t)idx*6+2];
        e03=eaord[(size_t)idx*6+3]; e04=eaord[(size_t)idx*6+4]; e05=eaord[(size_t)idx*6+5];
        e10=eaord[(size_t)(idx+1)*6+0]; e11=eaord[(size_t)(idx+1)*6+1]; e12=eaord[(size_t)(idx+1)*6+2];
        e13=eaord[(size_t)(idx+1)*6+3]; e14=eaord[(size_t)(idx+1)*6+4]; e15=eaord[(size_t)(idx+1)*6+5];
      }
      float g0 = (float)g12[(size_t)s0*128+64+j];
      float g1 = (float)g12[(size_t)s1*128+64+j];
      float m0 = mdst + g0 + e00*wf0 + e01*wf1 + e02*wf2 + e03*wf3 + e04*wf4 + e05*wf5;
      float m1 = mdst + g1 + e10*wf0 + e11*wf1 + e12*wf2 + e13*wf3 + e14*wf4 + e15*wf5;
      sum += m0; sq += m0*m0; mn = fminf(mn,m0); mx = fmaxf(mx,m0);
      sum += m1; sq += m1*m1; mn = fminf(mn,m1); mx = fmaxf(mx,m1);
    }
    if(idx<hi){
      int r0 = idx-eLo;
      int s0; float e00,e01,e02,e03,e04,e05;
      if(r0 < GCAP){
        s0=sSrc[r0];
        float4 va = *(const float4*)&sEA[r0][0];
        float2 vb = *(const float2*)&sEA[r0][4];
        e00=va.x; e01=va.y; e02=va.z; e03=va.w; e04=vb.x; e05=vb.y;
      } else {
        s0=srcord[idx];
        e00=eaord[(size_t)idx*6+0]; e01=eaord[(size_t)idx*6+1]; e02=eaord[(size_t)idx*6+2];
        e03=eaord[(size_t)idx*6+3]; e04=eaord[(size_t)idx*6+4]; e05=eaord[(size_t)idx*6+5];
      }
      float g0 = (float)g12[(size_t)s0*128+64+j];
      float m0 = mdst + g0 + e00*wf0 + e01*wf1 + e02*wf2 + e03*wf3 + e04*wf4 + e05*wf5;
      sum += m0; sq += m0*m0; mn = fminf(mn,m0); mx = fmaxf(mx,m0);
    }
    int c = hi-lo;
    float cm = fmaxf((float)c, 1.0f);
    float mean = sum/cm;
    float sd = sqrtf(fmaxf(sq/cm - mean*mean, 0.0f)+1e-5f);
    bool has = c>0;
    size_t base = (size_t)n*256;
    agg[base+j]     = (_Float16)mean;
    agg[base+64+j]  = (_Float16)(has?mn:0.0f);
    agg[base+128+j] = (_Float16)(has?mx:0.0f);
    agg[base+192+j] = (_Float16)sd;
    if(j==0){ float ld=logf(cm+1.0f); s12[n*2]=ld/avgdl; s12[n*2+1]=avgdl/ld; }
  }
}

// ---- k_tower_mfma: z-split; fp16 weights (2x half8 staging) ---------------
__global__ __launch_bounds__(256) void k_tower_mfma(_Float16* hy, const _Float16* agg, const float* s12,
        const _Float16* poW16, const float* pob, const _Float16* clW16, const float* clb, float* part){
  __shared__ _Float16 sAh[64][72];
  __shared__ _Float16 sBh[64][72];
  __shared__ float sS[128];
  __shared__ float sredS[16][64];
  __shared__ float sredQ[16][64];
  int t = threadIdx.x;
  int rb = blockIdx.x*64;
  int w = t>>6, l = t&63;
  int sr = t>>2, c0 = (t&3)*16;
  if (t < 128) sS[t] = s12[(size_t)(rb+(t>>1))*2 + (t&1)];
  f32x4 hacc[4]={}, z0a[4]={}, z1a[4]={}, z2a[4]={};
  auto stageB = [&](const _Float16* wr){
    *(half8*)&sBh[sr][c0]   = *(const half8*)&wr[0];
    *(half8*)&sBh[sr][c0+8] = *(const half8*)&wr[8];
  };
  auto mfma8 = [&](f32x4* acc){
    #pragma unroll
    for (int kk=0; kk<2; ++kk){
      half8 a = *(const half8*)&sAh[w*16 + (l&15)][kk*32 + (l>>4)*8];
      #pragma unroll
      for (int n16=0; n16<4; ++n16){
        half8 b = *(const half8*)&sBh[n16*16 + (l&15)][kk*32 + (l>>4)*8];
        acc[n16] = __builtin_amdgcn_mfma_f32_16x16x32_f16(a, b, acc[n16], 0, 0, 0);
      }
    }
  };
  {
    *(half8*)&sAh[sr][c0]   = *(const half8*)&hy[(size_t)(rb+sr)*64 + c0];
    *(half8*)&sAh[sr][c0+8] = *(const half8*)&hy[(size_t)(rb+sr)*64 + c0 + 8];
    stageB(&poW16[(size_t)sr*832 + c0]);
  }
  __syncthreads();
  mfma8(hacc);
  for (int kt=0; kt<4; ++kt){
    __syncthreads();
    *(half8*)&sAh[sr][c0]   = *(const half8*)&agg[(size_t)(rb+sr)*256 + kt*64 + c0];
    *(half8*)&sAh[sr][c0+8] = *(const half8*)&agg[(size_t)(rb+sr)*256 + kt*64 + c0 + 8];
    stageB(&poW16[(size_t)sr*832 + 64 + kt*64 + c0]);
    __syncthreads();
    mfma8(z0a);
    __syncthreads();
    stageB(&poW16[(size_t)sr*832 + 64 + 256 + kt*64 + c0]);
    __syncthreads();
    mfma8(z1a);
    __syncthreads();
    stageB(&poW16[(size_t)sr*832 + 64 + 512 + kt*64 + c0]);
    __syncthreads();
    mfma8(z2a);
  }
  __syncthreads();
  #pragma unroll
  for (int n16=0; n16<4; ++n16){
    #pragma unroll
    for (int reg=0; reg<4; ++reg){
      int row = w*16 + (l>>4)*4 + reg;
      int col = n16*16 + (l&15);
      float s1v = sS[row*2], s2v = sS[row*2+1];
      float v = hacc[n16][reg] + z0a[n16][reg] + s1v*z1a[n16][reg] + s2v*z2a[n16][reg] + pob[col];
      sAh[row][col] = (_Float16)v;
    }
  }
  stageB(&clW16[(size_t)sr*64 + c0]);
  __syncthreads();
  f32x4 cacc[4] = {};
  mfma8(cacc);
  float cs_[4], cq_[4];
  #pragma unroll
  for (int n16=0; n16<4; ++n16){ cs_[n16]=0.0f; cq_[n16]=0.0f; }
  #pragma unroll
  for (int n16=0; n16<4; ++n16){
    #pragma unroll
    for (int reg=0; reg<4; ++reg){
      int row = w*16 + (l>>4)*4 + reg;
      int col = n16*16 + (l&15);
      float v = cacc[n16][reg] + clb[col];
      hy[(size_t)(rb+row)*64 + col] = (_Float16)v;
      cs_[n16] += v; cq_[n16] += v*v;
    }
  }
  int slot = w*4 + (l>>4);
  #pragma unroll
  for (int n16=0; n16<4; ++n16){
    int col = n16*16 + (l&15);
    sredS[slot][col] = cs_[n16];
    sredQ[slot][col] = cq_[n16];
  }
  __syncthreads();
  if (t < 64){
    float S=0.0f, Q=0.0f;
    #pragma unroll
    for(int q2=0;q2<16;q2++){ S += sredS[q2][t]; Q += sredQ[q2][t]; }
    part[(size_t)blockIdx.x*128 + t]      = S;
    part[(size_t)blockIdx.x*128 + 64 + t] = Q;
  }
}

// ---- BN finalize: hierarchical (1024 thr = 64 cols x 16 chunks) -----------
__global__ __launch_bounds__(1024) void k_bnfin(const float* part, const float* g, const float* bb,
                                                float* sc, float* sh){
  __shared__ double sS[16][64], sQ[16][64];
  int t = threadIdx.x;
  int c = t&63, chunk = t>>6;
  double S=0.0, Q=0.0;
  for(int b=chunk; b<2048; b+=16){
    S += (double)part[(size_t)b*128 + c];
    Q += (double)part[(size_t)b*128 + 64 + c];
  }
  sS[chunk][c]=S; sQ[chunk][c]=Q;
  __syncthreads();
  if(t<64){
    double St=0.0, Qt=0.0;
    #pragma unroll
    for(int q=0;q<16;q++){ St+=sS[q][t]; Qt+=sQ[q][t]; }
    double mean = St/(double)NN;
    double var  = Qt/(double)NN - mean*mean;
    float scale = g[t] * (float)(1.0/sqrt(var+1e-5));
    sc[t]=scale;
    sh[t]=bb[t] - (float)mean*scale;
  }
}

// ---- final BN apply in place on hy (fp16) ---------------------------------
__global__ void k_bnapply16(_Float16* hy, const float* sc, const float* sh){
  int idx = blockIdx.x*256+threadIdx.x;
  for(int i=idx; i<NN*8; i+=256*2048){
    int c0 = (i&7)*8;
    half8 v = *(const half8*)&hy[(size_t)i*8];
    half8 r;
    #pragma unroll
    for(int q=0;q<8;q++) r[q]=(_Float16)fmaxf((float)v[q]*sc[c0+q]+sh[c0+q],0.0f);
    *(half8*)&hy[(size_t)i*8] = r;
  }
}

// ---- set2set LSTM: 8 graphs/block, float4 weights reused x8, 8 acc chains -
__global__ __launch_bounds__(256) void k_lstm_lit(float* A, float* cs,
      const float* Wih, const float* Whh, const float* bih, const float* bhh){
  __shared__ float sA[8][128];
  __shared__ float sg[8][256];
  int t=threadIdx.x;
  int g0 = blockIdx.x*8;
  for(int i=t;i<1024;i+=256) sA[i>>7][i&127] = A[(size_t)(g0+(i>>7))*128 + (i&127)];
  __syncthreads();
  float bb2 = bih[t]+bhh[t];
  float acc[8];
  #pragma unroll
  for(int g=0;g<8;g++) acc[g]=bb2;
  for(int k=0;k<128;k+=4){
    float4 wv = *(const float4*)&Wih[(size_t)t*128+k];
    #pragma unroll
    for(int g=0;g<8;g++)
      acc[g] += wv.x*sA[g][k] + wv.y*sA[g][k+1] + wv.z*sA[g][k+2] + wv.w*sA[g][k+3];
  }
  for(int k=0;k<64;k+=4){
    float4 wv = *(const float4*)&Whh[(size_t)t*64+k];
    #pragma unroll
    for(int g=0;g<8;g++)
      acc[g] += wv.x*sA[g][k] + wv.y*sA[g][k+1] + wv.z*sA[g][k+2] + wv.w*sA[g][k+3];
  }
  #pragma unroll
  for(int g=0;g<8;g++) sg[g][t]=acc[g];
  __syncthreads();
  for(int i=t;i<512;i+=256){
    int g=i>>6, j=i&63;
    float ig=sg[g][j], fg=sg[g][64+j], gg=sg[g][128+j], og=sg[g][192+j];
    float c = sigmoidf_(fg)*cs[(size_t)(g0+g)*64+j] + sigmoidf_(ig)*tanhf(gg);
    float hv = sigmoidf_(og)*tanhf(c);
    cs[(size_t)(g0+g)*64+j]=c;
    A[(size_t)(g0+g)*128+j]=hv;
  }
}

// ---- fused edot+attn: parallel e-compute (lane i owns node i) -------------
__global__ __launch_bounds__(64) void k_attn_f(const _Float16* h16, const int* gptr, float* A){
  __shared__ _Float16 sH[ACAP][66];
  __shared__ float sE[ACAP];
  __shared__ float saq[64];
  int g=blockIdx.x, j=threadIdx.x;
  int lo=gptr[g], hi=gptr[g+1];
  int cnt=hi-lo;
  if(cnt<=0){ A[(size_t)g*128+64+j]=0.0f; return; }
  float aq = A[(size_t)g*128+j];
  saq[j]=aq;
  if(cnt<=ACAP){
    for(int i=0;i<cnt;++i) sH[i][j] = h16[(size_t)(lo+i)*64+j];
    __syncthreads();
    for(int i=j;i<cnt;i+=64){
      float v=0.0f;
      for(int k=0;k<64;k++) v += (float)sH[i][k]*saq[k];
      sE[i]=v;
    }
    __syncthreads();
    float mx=-1e30f;
    for(int i=j;i<cnt;i+=64) mx=fmaxf(mx,sE[i]);
    #pragma unroll
    for(int m=32;m;m>>=1) mx=fmaxf(mx,__shfl_xor(mx,m,64));
    float s=0.0f;
    for(int i=j;i<cnt;i+=64) s+=expf(sE[i]-mx);
    #pragma unroll
    for(int m=32;m;m>>=1) s+=__shfl_xor(s,m,64);
    float inv=1.0f/(s+1e-16f);
    for(int i=j;i<cnt;i+=64) sE[i]=expf(sE[i]-mx)*inv;
    __syncthreads();
    float r=0.0f;
    for(int i=0;i<cnt;++i) r += sE[i]*(float)sH[i][j];
    A[(size_t)g*128+64+j]=r;
  } else {
    float mx=-1e30f;
    for(int n=lo;n<hi;++n){
      float v=(float)h16[(size_t)n*64+j]*aq;
      #pragma unroll
      for(int m=32;m;m>>=1) v+=__shfl_xor(v,m,64);
      mx=fmaxf(mx,v);
    }
    float s=0.0f;
    for(int n=lo;n<hi;++n){
      float v=(float)h16[(size_t)n*64+j]*aq;
      #pragma unroll
      for(int m=32;m;m>>=1) v+=__shfl_xor(v,m,64);
      s+=expf(v-mx);
    }
    float inv=1.0f/(s+1e-16f);
    float r=0.0f;
    for(int n=lo;n<hi;++n){
      float v=(float)h16[(size_t)n*64+j]*aq;
      #pragma unroll
      for(int m=32;m;m>>=1) v+=__shfl_xor(v,m,64);
      r+=expf(v-mx)*inv*(float)h16[(size_t)n*64+j];
    }
    A[(size_t)g*128+64+j]=r;
  }
}

__global__ __launch_bounds__(64) void k_mlp(const float* A, const float* tt, const float* pp,
     const float* W1,const float* b1,const float* W2,const float* b2,const float* W3,const float* b3,
     float* out){
  __shared__ float si[130]; __shared__ float o1[64]; __shared__ float o2[32];
  int g=blockIdx.x, t=threadIdx.x;
  si[t]=A[g*128+t]; si[64+t]=A[g*128+64+t];
  if(t==0){ si[128]=tt[g]; si[129]=pp[g]; }
  __syncthreads();
  float a=b1[t];
  for(int k=0;k<130;k++) a+=W1[t*130+k]*si[k];
  o1[t]=fmaxf(a,0.0f);
  __syncthreads();
  if(t<32){
    float a2=b2[t];
    #pragma unroll 4
    for(int k=0;k<64;k++) a2+=W2[t*64+k]*o1[k];
    o2[t]=fmaxf(a2,0.0f);
  }
  __syncthreads();
  float v = (t<32)? o2[t]*W3[t] : 0.0f;
  #pragma unroll
  for(int m=32;m;m>>=1) v+=__shfl_xor(v,m,64);
  if(t==0) out[g]=v+b3[0];
}

// ---- host -----------------------------------------------------------------
extern "C" void kernel_launch(void* const* d_in, const int* in_sizes, int n_in,
                              void* d_out, int out_size, void* d_ws, size_t ws_size,
                              hipStream_t stream) {
  static const int want[28] = {4194304,3145728,4096,4096,2048,64,1152,192,36864,192,
                               159744,192,12288,192,192,192,32768,16384,256,256,
                               8320,64,2048,32,32,1,1048576,131072};
  if (n_in != 28 || out_size != GG) return;
  for (int i=0;i<28;i++) if (in_sizes[i] != want[i]) return;

  const float* x     = (const float*)d_in[0];
  const float* ea    = (const float*)d_in[1];
  const float* tt    = (const float*)d_in[2];
  const float* pp    = (const float*)d_in[3];
  const float* lin1W = (const float*)d_in[4];
  const float* lin1b = (const float*)d_in[5];
  const float* edgeW = (const float*)d_in[6];
  const float* edgeb = (const float*)d_in[7];
  const float* preW  = (const float*)d_in[8];
  const float* preb  = (const float*)d_in[9];
  const float* postW = (const float*)d_in[10];
  const float* postb = (const float*)d_in[11];
  const float* clinW = (const float*)d_in[12];
  const float* clinb = (const float*)d_in[13];
  const float* bng   = (const float*)d_in[14];
  const float* bnb   = (const float*)d_in[15];
  const float* Wih   = (const float*)d_in[16];
  const float* Whh   = (const float*)d_in[17];
  const float* bih   = (const float*)d_in[18];
  const float* bhh   = (const float*)d_in[19];
  const float* W1    = (const float*)d_in[20];
  const float* b1    = (const float*)d_in[21];
  const float* W2    = (const float*)d_in[22];
  const float* b2    = (const float*)d_in[23];
  const float* W3    = (const float*)d_in[24];
  const float* b3    = (const float*)d_in[25];
  const int*   eidx  = (const int*)d_in[26];
  const int*   batch = (const int*)d_in[27];
  const int* esrc = eidx;
  const int* edst = eidx + EE;

  char* w = (char*)d_ws;
  auto alloc = [&](size_t bytes)->char*{ char* p=w; w += ((bytes+255)/256)*256; return p; };
  _Float16* agg  = (_Float16*)alloc((size_t)NN*256*2);  // 64MiB fp16
  _Float16* g12  = (_Float16*)alloc((size_t)NN*128*2);  // 32MiB fp16 (set2set scratch aliases)
  _Float16* hy   = (_Float16*)alloc((size_t)NN*64*2);   // 16MiB fp16
  int*   deg    = (int*)alloc((size_t)NN*4);
  int*   cursor = (int*)alloc((size_t)NN*4);
  int*   rowptr = (int*)alloc((size_t)(NN+1)*4);
  int*   spart  = (int*)alloc(512*4);
  int*   srcord = (int*)alloc((size_t)EE*4);
  float* eaord  = (float*)alloc((size_t)EE*6*4);
  float* s12   = (float*)alloc((size_t)NN*2*4);
  float* part  = (float*)alloc((size_t)2048*128*4);
  float* bnsc  = (float*)alloc(256);
  float* bnsh  = (float*)alloc(256);
  float* WfG   = (float*)alloc(3*384*4);
  float* bfG   = (float*)alloc(3*64*4);
  _Float16* preW16 = (_Float16*)alloc(36864*2);
  _Float16* poW16  = (_Float16*)alloc(159744*2);
  _Float16* clW16  = (_Float16*)alloc(12288*2);
  int*   gptr  = (int*)alloc((GG+1)*4);
  size_t need = (size_t)(w - (char*)d_ws);
  if (need > ws_size) return;
  float* A    = (float*)g12;
  float* cs   = (float*)g12 + (size_t)GG*128;

  double num = 13107.0*log(2.0)+26214.0*log(3.0)+65536.0*log(4.0)+26215.0*log(5.0);
  float avgdl = (float)(num/131072.0);

  hipMemsetAsync(deg, 0, (size_t)NN*4, stream);
  hipMemsetAsync(cursor, 0, (size_t)NN*4, stream);
  hipLaunchKernelGGL(k_deg, dim3(2048), dim3(256), 0, stream, edst, deg);
  hipLaunchKernelGGL(k_scan_part, dim3(512), dim3(256), 0, stream, deg, spart);
  hipLaunchKernelGGL(k_scan_top, dim3(1), dim3(512), 0, stream, spart);
  hipLaunchKernelGGL(k_scan_apply, dim3(512), dim3(256), 0, stream, deg, spart, rowptr);
  hipLaunchKernelGGL(k_fill, dim3(2048), dim3(256), 0, stream, edst, esrc, ea, rowptr, cursor, srcord, eaord);

  hipLaunchKernelGGL(k_gptr, dim3(17), dim3(256), 0, stream, batch, gptr);
  hipLaunchKernelGGL(k_prepwf, dim3(3), dim3(448), 0, stream, preW, preb, edgeW, edgeb, WfG, bfG);
  hipLaunchKernelGGL(k_prepw16, dim3(817), dim3(256), 0, stream, preW, postW, clinW, preW16, poW16, clW16);
  hipLaunchKernelGGL(k_lin1_s, dim3(1024), dim3(256), 0, stream, x, lin1W, lin1b, hy);

  for (int i = 0; i < 3; ++i){
    const float* sc_i = (i==0)? nullptr : bnsc;
    const float* sh_i = (i==0)? nullptr : bnsh;
    hipLaunchKernelGGL(k_bnmsg, dim3(2048), dim3(256), 0, stream, hy, sc_i, sh_i,
        preW16 + (size_t)i*12288, g12);
    hipLaunchKernelGGL(k_gather_f, dim3(4096), dim3(256), 0, stream, rowptr, srcord, eaord, g12,
        WfG + (size_t)i*384, bfG + (size_t)i*64, agg, s12, avgdl);
    hipLaunchKernelGGL(k_tower_mfma, dim3(2048), dim3(256), 0, stream, hy, agg, s12,
        poW16 + (size_t)i*53248, postb + i*64, clW16 + (size_t)i*4096, clinb + i*64, part);
    hipLaunchKernelGGL(k_bnfin, dim3(1), dim3(1024), 0, stream, part, bng + i*64, bnb + i*64, bnsc, bnsh);
  }
  hipLaunchKernelGGL(k_bnapply16, dim3(2048), dim3(256), 0, stream, hy, bnsc, bnsh);

  hipMemsetAsync(A, 0, (size_t)GG*128*4, stream);
  hipMemsetAsync(cs, 0, (size_t)GG*64*4, stream);
  for (int s = 0; s < 3; ++s){
    hipLaunchKernelGGL(k_lstm_lit, dim3(512), dim3(256), 0, stream, A, cs, Wih, Whh, bih, bhh);
    hipLaunchKernelGGL(k_attn_f, dim3(GG), dim3(64), 0, stream, hy, gptr, A);
  }
  hipLaunchKernelGGL(k_mlp, dim3(GG), dim3(64), 0, stream, A, tt, pp, W1, b1, W2, b2, W3, b3, (float*)d_out);
}

// Round 26
// 653.929 us; speedup vs baseline: 1.3158x; 1.0623x over previous
//
#include <hip/hip_runtime.h>
#include <hip/hip_bf16.h>
#include <math.h>

#define NN 131072
#define EE 524288
#define GG 4096
#define GCAP 320
#define ACAP 96

typedef __attribute__((ext_vector_type(8))) _Float16 half8;
typedef __attribute__((ext_vector_type(4))) _Float16 half4;
typedef __attribute__((ext_vector_type(4))) float f32x4;

__device__ __forceinline__ float sigmoidf_(float x){ return 1.0f/(1.0f+expf(-x)); }

// ---- grouping / CSR (integer atomics only) --------------------------------
__global__ void k_gptr(const int* batch, int* gptr){
  int g = blockIdx.x*256+threadIdx.x;
  if (g > GG) return;
  if (g == GG){ gptr[GG]=NN; return; }
  int lo=0, hi=NN;
  while(lo<hi){ int mid=(lo+hi)>>1; if(batch[mid]<g) lo=mid+1; else hi=mid; }
  gptr[g]=lo;
}

__global__ void k_deg(const int* dst, int* deg){
  int e = blockIdx.x*256+threadIdx.x;
  if(e<EE) atomicAdd(&deg[dst[e]], 1);
}

// hierarchical scan
__global__ __launch_bounds__(256) void k_scan_part(const int* deg, int* part){
  __shared__ int red[256];
  int b=blockIdx.x, t=threadIdx.x;
  red[t] = deg[b*256+t];
  __syncthreads();
  for(int off=128; off>0; off>>=1){
    if(t<off) red[t]+=red[t+off];
    __syncthreads();
  }
  if(t==0) part[b]=red[0];
}

__global__ __launch_bounds__(512) void k_scan_top(int* part){
  __shared__ int s[512];
  int t=threadIdx.x;
  s[t]=part[t];
  __syncthreads();
  for(int off=1; off<512; off<<=1){
    int v=s[t];
    int add=(t>=off)?s[t-off]:0;
    __syncthreads();
    s[t]=v+add;
    __syncthreads();
  }
  part[t] = (t==0)?0:s[t-1];
}

__global__ __launch_bounds__(256) void k_scan_apply(const int* deg, const int* part, int* rowptr){
  __shared__ int s[256];
  int b=blockIdx.x, t=threadIdx.x;
  int v0=deg[b*256+t];
  s[t]=v0;
  __syncthreads();
  for(int off=1; off<256; off<<=1){
    int v=s[t];
    int add=(t>=off)?s[t-off]:0;
    __syncthreads();
    s[t]=v+add;
    __syncthreads();
  }
  rowptr[b*256+t] = part[b] + s[t]-v0;
  if(b==511 && t==255) rowptr[NN] = part[b] + s[t];
}

// fill CSR-ordered edge streams (ea copy vectorized float2)
__global__ void k_fill(const int* dst, const int* src, const float* ea,
                       const int* rowptr, int* cursor, int* srcord, float* eaord){
  int e = blockIdx.x*256+threadIdx.x;
  if(e>=EE) return;
  int d = dst[e];
  int pos = atomicAdd(&cursor[d], 1);
  int idx = rowptr[d]+pos;
  srcord[idx] = src[e];
  float2 e0 = *(const float2*)&ea[(size_t)e*6];
  float2 e1 = *(const float2*)&ea[(size_t)e*6+2];
  float2 e2 = *(const float2*)&ea[(size_t)e*6+4];
  *(float2*)&eaord[(size_t)idx*6]   = e0;
  *(float2*)&eaord[(size_t)idx*6+2] = e1;
  *(float2*)&eaord[(size_t)idx*6+4] = e2;
}

// ---- all-layers Wf/bf precompute (3 blocks) -------------------------------
__global__ __launch_bounds__(448) void k_prepwf(const float* preW, const float* preb,
      const float* eW, const float* eb, float* WfG, float* bfG){
  int i = blockIdx.x;
  const float* pW = preW + (size_t)i*64*192;
  const float* pb = preb + i*64;
  const float* eWl = eW + (size_t)i*384;
  const float* ebl = eb + i*64;
  int t=threadIdx.x;
  if(t<384){
    int j=t/6, d=t-j*6;
    float a=0.0f;
    for(int k=0;k<64;k++) a += pW[(size_t)j*192+128+k]*eWl[k*6+d];
    WfG[i*384+t]=a;
  } else if(t<448){
    int j=t-384;
    float a=pb[j];
    for(int k=0;k<64;k++) a += pW[(size_t)j*192+128+k]*ebl[k];
    bfG[i*64+j]=a;
  }
}

// ---- weights -> fp16 once (bit-identical to per-use conversion) -----------
__global__ void k_prepw16(const float* preW, const float* poW, const float* clW,
                          _Float16* preW16, _Float16* poW16, _Float16* clW16){
  int i = blockIdx.x*256 + threadIdx.x;
  if(i < 36864) preW16[i] = (_Float16)preW[i];
  else if(i < 36864+159744) poW16[i-36864] = (_Float16)poW[i-36864];
  else if(i < 36864+159744+12288) clW16[i-196608] = (_Float16)clW[i-196608];
}

// ---- y0 = x @ lin1W.T + b (pre-activation, fp16); grid-stride, padded sW --
__global__ __launch_bounds__(256) void k_lin1_s(const float* x, const float* W, const float* b, _Float16* y0){
  __shared__ float sW[2112];
  __shared__ float sb[64];
  int t=threadIdx.x;
  for(int i=t;i<2048;i+=256){ int j=i>>5,k=i&31; sW[j*33+k]=W[i]; }
  if(t<64) sb[t]=b[t];
  __syncthreads();
  int w = t>>6, j = t&63;
  for(int it=0; it<32; ++it){
    int n = (blockIdx.x*4 + w) + it*4096;
    float acc = sb[j];
    #pragma unroll 8
    for(int k=0;k<32;k++) acc += x[(size_t)n*32+k]*sW[j*33+k];
    y0[(size_t)n*64+j] = (_Float16)acc;
  }
}

// ---- k_bnmsg: hy := relu(hy*sc+sh) in place; g12 = h @ [Wd|Ws].T (MFMA) ---
__global__ __launch_bounds__(256) void k_bnmsg(_Float16* hy, const float* sc, const float* sh,
      const _Float16* preW16, _Float16* g12){
  __shared__ _Float16 sAh[64][72];
  __shared__ _Float16 sB0[64][72];
  __shared__ _Float16 sB1[64][72];
  __shared__ float ssc[64], ssh[64];
  int t=threadIdx.x;
  int rb = blockIdx.x*64;
  if(t<64){ ssc[t] = sc? sc[t] : 1.0f; ssh[t] = sh? sh[t] : 0.0f; }
  __syncthreads();
  int sr = t>>2, c0 = (t&3)*16;
  {
    half8 y0 = *(const half8*)&hy[(size_t)(rb+sr)*64 + c0];
    half8 y1 = *(const half8*)&hy[(size_t)(rb+sr)*64 + c0 + 8];
    half8 h0, h1;
    #pragma unroll
    for(int q=0;q<8;q++){
      h0[q] = (_Float16)fmaxf((float)y0[q]*ssc[c0+q]   + ssh[c0+q],   0.0f);
      h1[q] = (_Float16)fmaxf((float)y1[q]*ssc[c0+8+q] + ssh[c0+8+q], 0.0f);
    }
    *(half8*)&sAh[sr][c0]   = h0;
    *(half8*)&sAh[sr][c0+8] = h1;
    *(half8*)&hy[(size_t)(rb+sr)*64 + c0]     = h0;
    *(half8*)&hy[(size_t)(rb+sr)*64 + c0 + 8] = h1;
    const _Float16* w0 = &preW16[(size_t)sr*192 + c0];
    const _Float16* w1 = &preW16[(size_t)sr*192 + 64 + c0];
    *(half8*)&sB0[sr][c0]   = *(const half8*)&w0[0];
    *(half8*)&sB0[sr][c0+8] = *(const half8*)&w0[8];
    *(half8*)&sB1[sr][c0]   = *(const half8*)&w1[0];
    *(half8*)&sB1[sr][c0+8] = *(const half8*)&w1[8];
  }
  __syncthreads();
  int w=t>>6, l=t&63;
  f32x4 acc0[4]={}, acc1[4]={};
  #pragma unroll
  for(int kk=0; kk<2; ++kk){
    half8 a = *(const half8*)&sAh[w*16+(l&15)][kk*32+(l>>4)*8];
    #pragma unroll
    for(int n16=0;n16<4;++n16){
      half8 b0 = *(const half8*)&sB0[n16*16+(l&15)][kk*32+(l>>4)*8];
      half8 b1 = *(const half8*)&sB1[n16*16+(l&15)][kk*32+(l>>4)*8];
      acc0[n16] = __builtin_amdgcn_mfma_f32_16x16x32_f16(a,b0,acc0[n16],0,0,0);
      acc1[n16] = __builtin_amdgcn_mfma_f32_16x16x32_f16(a,b1,acc1[n16],0,0,0);
    }
  }
  #pragma unroll
  for(int n16=0;n16<4;++n16){
    #pragma unroll
    for(int reg=0; reg<4; ++reg){
      int row = w*16+(l>>4)*4+reg;
      int col = n16*16+(l&15);
      g12[(size_t)(rb+row)*128 + col]      = (_Float16)acc0[n16][reg];
      g12[(size_t)(rb+row)*128 + 64 + col] = (_Float16)acc1[n16][reg];
    }
  }
}

// ---- gather: 32 nodes/block; block-level GCAP specialization --------------
__global__ __launch_bounds__(256) void k_gather_f(const int* rowptr, const int* srcord,
      const float* eaord, const _Float16* g12, const float* WfG, const float* bfG,
      _Float16* agg, float* s12, float avgdl){
  __shared__ float sWf[64][6];
  __shared__ float sbf[64];
  __shared__ int   sRow[33];
  __shared__ int   sSrc[GCAP];
  __shared__ float sEA[GCAP][8];
  int t=threadIdx.x;
  int rb = blockIdx.x*32;
  for(int i=t; i<384; i+=256) ((float*)sWf)[i]=WfG[i];
  if(t<64) sbf[t]=bfG[t];
  if(t<33) sRow[t]=rowptr[rb+t];
  __syncthreads();
  int eLo = sRow[0];
  int cnt = sRow[32]-eLo;
  int ccap = (cnt<GCAP)? cnt : GCAP;
  for(int i=t; i<ccap; i+=256) sSrc[i]=srcord[eLo+i];
  for(int i=t; i<ccap; i+=256){
    float2 e0 = *(const float2*)&eaord[(size_t)(eLo+i)*6];
    float2 e1 = *(const float2*)&eaord[(size_t)(eLo+i)*6+2];
    float2 e2 = *(const float2*)&eaord[(size_t)(eLo+i)*6+4];
    *(float2*)&sEA[i][0]=e0;
    *(float2*)&sEA[i][2]=e1;
    *(float2*)&sEA[i][4]=e2;
  }
  __syncthreads();
  int w=t>>6, j=t&63;
  float wf0=sWf[j][0], wf1=sWf[j][1], wf2=sWf[j][2];
  float wf3=sWf[j][3], wf4=sWf[j][4], wf5=sWf[j][5];
  float bfj=sbf[j];
  if(cnt<=GCAP){
    // ---- clean path: all edges in LDS, branch-free inner loop ----
    for(int q=0; q<8; ++q){
      int ln = w*8 + q;
      int n  = rb + ln;
      int lo = sRow[ln]-eLo, hi = sRow[ln+1]-eLo;
      float mdst = (float)g12[(size_t)n*128+j] + bfj;
      float sum=0.0f, sq=0.0f, mn=1e30f, mx=-1e30f;
      int r=lo;
      for(; r+1<hi; r+=2){
        int s0=sSrc[r], s1=sSrc[r+1];
        float4 va = *(const float4*)&sEA[r][0];
        float2 vb = *(const float2*)&sEA[r][4];
        float4 wa = *(const float4*)&sEA[r+1][0];
        float2 wb = *(const float2*)&sEA[r+1][4];
        float g0 = (float)g12[(size_t)s0*128+64+j];
        float g1 = (float)g12[(size_t)s1*128+64+j];
        float m0 = mdst + g0 + va.x*wf0 + va.y*wf1 + va.z*wf2 + va.w*wf3 + vb.x*wf4 + vb.y*wf5;
        float m1 = mdst + g1 + wa.x*wf0 + wa.y*wf1 + wa.z*wf2 + wa.w*wf3 + wb.x*wf4 + wb.y*wf5;
        sum += m0; sq += m0*m0; mn = fminf(mn,m0); mx = fmaxf(mx,m0);
        sum += m1; sq += m1*m1; mn = fminf(mn,m1); mx = fmaxf(mx,m1);
      }
      if(r<hi){
        int s0=sSrc[r];
        float4 va = *(const float4*)&sEA[r][0];
        float2 vb = *(const float2*)&sEA[r][4];
        float g0 = (float)g12[(size_t)s0*128+64+j];
        float m0 = mdst + g0 + va.x*wf0 + va.y*wf1 + va.z*wf2 + va.w*wf3 + vb.x*wf4 + vb.y*wf5;
        sum += m0; sq += m0*m0; mn = fminf(mn,m0); mx = fmaxf(mx,m0);
      }
      int c = hi-lo;
      float cm = fmaxf((float)c, 1.0f);
      float mean = sum/cm;
      float sd = sqrtf(fmaxf(sq/cm - mean*mean, 0.0f)+1e-5f);
      bool has = c>0;
      size_t base = (size_t)n*256;
      agg[base+j]     = (_Float16)mean;
      agg[base+64+j]  = (_Float16)(has?mn:0.0f);
      agg[base+128+j] = (_Float16)(has?mx:0.0f);
      agg[base+192+j] = (_Float16)sd;
      if(j==0){ float ld=logf(cm+1.0f); s12[n*2]=ld/avgdl; s12[n*2+1]=avgdl/ld; }
    }
  } else {
    // ---- fallback (statistically unreachable): original mixed path ----
    for(int q=0; q<8; ++q){
      int ln = w*8 + q;
      int n  = rb + ln;
      int lo = sRow[ln], hi = sRow[ln+1];
      float mdst = (float)g12[(size_t)n*128+j] + bfj;
      float sum=0.0f, sq=0.0f, mn=1e30f, mx=-1e30f;
      int idx=lo;
      for(; idx+1<hi; idx+=2){
        int r0 = idx-eLo, r1 = r0+1;
        int s0, s1;
        float e00,e01,e02,e03,e04,e05, e10,e11,e12,e13,e14,e15;
        if(r1 < GCAP){
          s0=sSrc[r0]; s1=sSrc[r1];
          float4 va = *(const float4*)&sEA[r0][0];
          float2 vb = *(const float2*)&sEA[r0][4];
          float4 wa = *(const float4*)&sEA[r1][0];
          float2 wb = *(const float2*)&sEA[r1][4];
          e00=va.x; e01=va.y; e02=va.z; e03=va.w; e04=vb.x; e05=vb.y;
          e10=wa.x; e11=wa.y; e12=wa.z; e13=wa.w; e14=wb.x; e15=wb.y;
        } else {
          s0=srcord[idx]; s1=srcord[idx+1];
          e00=eaord[(size_t)idx*6+0]; e01=eaord[(size_t)idx*6+1]; e02=eaord[(size_t)idx*6+2];
          e03=eaord[(size_t)idx*6+3]; e04=eaord[(size_t)idx*6+4]; e05=eaord[(size_t)idx*6+5];
          e10=eaord[(size_t)(idx+1)*6+0]; e11=eaord[(size_t)(idx+1)*6+1]; e12=eaord[(size_t)(idx+1)*6+2];
          e13=eaord[(size_t)(idx+1)*6+3]; e14=eaord[(size_t)(idx+1)*6+4]; e15=eaord[(size_t)(idx+1)*6+5];
        }
        float g0 = (float)g12[(size_t)s0*128+64+j];
        float g1 = (float)g12[(size_t)s1*128+64+j];
        float m0 = mdst + g0 + e00*wf0 + e01*wf1 + e02*wf2 + e03*wf3 + e04*wf4 + e05*wf5;
        float m1 = mdst + g1 + e10*wf0 + e11*wf1 + e12*wf2 + e13*wf3 + e14*wf4 + e15*wf5;
        sum += m0; sq += m0*m0; mn = fminf(mn,m0); mx = fmaxf(mx,m0);
        sum += m1; sq += m1*m1; mn = fminf(mn,m1); mx = fmaxf(mx,m1);
      }
      if(idx<hi){
        int r0 = idx-eLo;
        int s0; float e00,e01,e02,e03,e04,e05;
        if(r0 < GCAP){
          s0=sSrc[r0];
          float4 va = *(const float4*)&sEA[r0][0];
          float2 vb = *(const float2*)&sEA[r0][4];
          e00=va.x; e01=va.y; e02=va.z; e03=va.w; e04=vb.x; e05=vb.y;
        } else {
          s0=srcord[idx];
          e00=eaord[(size_t)idx*6+0]; e01=eaord[(size_t)idx*6+1]; e02=eaord[(size_t)idx*6+2];
          e03=eaord[(size_t)idx*6+3]; e04=eaord[(size_t)idx*6+4]; e05=eaord[(size_t)idx*6+5];
        }
        float g0 = (float)g12[(size_t)s0*128+64+j];
        float m0 = mdst + g0 + e00*wf0 + e01*wf1 + e02*wf2 + e03*wf3 + e04*wf4 + e05*wf5;
        sum += m0; sq += m0*m0; mn = fminf(mn,m0); mx = fmaxf(mx,m0);
      }
      int c = hi-lo;
      float cm = fmaxf((float)c, 1.0f);
      float mean = sum/cm;
      float sd = sqrtf(fmaxf(sq/cm - mean*mean, 0.0f)+1e-5f);
      bool has = c>0;
      size_t base = (size_t)n*256;
      agg[base+j]     = (_Float16)mean;
      agg[base+64+j]  = (_Float16)(has?mn:0.0f);
      agg[base+128+j] = (_Float16)(has?mx:0.0f);
      agg[base+192+j] = (_Float16)sd;
      if(j==0){ float ld=logf(cm+1.0f); s12[n*2]=ld/avgdl; s12[n*2+1]=avgdl/ld; }
    }
  }
}

// ---- k_tower_mfma: z-split; fp16 weights (2x half8 staging) ---------------
__global__ __launch_bounds__(256) void k_tower_mfma(_Float16* hy, const _Float16* agg, const float* s12,
        const _Float16* poW16, const float* pob, const _Float16* clW16, const float* clb, float* part){
  __shared__ _Float16 sAh[64][72];
  __shared__ _Float16 sBh[64][72];
  __shared__ float sS[128];
  __shared__ float sredS[16][64];
  __shared__ float sredQ[16][64];
  int t = threadIdx.x;
  int rb = blockIdx.x*64;
  int w = t>>6, l = t&63;
  int sr = t>>2, c0 = (t&3)*16;
  if (t < 128) sS[t] = s12[(size_t)(rb+(t>>1))*2 + (t&1)];
  f32x4 hacc[4]={}, z0a[4]={}, z1a[4]={}, z2a[4]={};
  auto stageB = [&](const _Float16* wr){
    *(half8*)&sBh[sr][c0]   = *(const half8*)&wr[0];
    *(half8*)&sBh[sr][c0+8] = *(const half8*)&wr[8];
  };
  auto mfma8 = [&](f32x4* acc){
    #pragma unroll
    for (int kk=0; kk<2; ++kk){
      half8 a = *(const half8*)&sAh[w*16 + (l&15)][kk*32 + (l>>4)*8];
      #pragma unroll
      for (int n16=0; n16<4; ++n16){
        half8 b = *(const half8*)&sBh[n16*16 + (l&15)][kk*32 + (l>>4)*8];
        acc[n16] = __builtin_amdgcn_mfma_f32_16x16x32_f16(a, b, acc[n16], 0, 0, 0);
      }
    }
  };
  {
    *(half8*)&sAh[sr][c0]   = *(const half8*)&hy[(size_t)(rb+sr)*64 + c0];
    *(half8*)&sAh[sr][c0+8] = *(const half8*)&hy[(size_t)(rb+sr)*64 + c0 + 8];
    stageB(&poW16[(size_t)sr*832 + c0]);
  }
  __syncthreads();
  mfma8(hacc);
  for (int kt=0; kt<4; ++kt){
    __syncthreads();
    *(half8*)&sAh[sr][c0]   = *(const half8*)&agg[(size_t)(rb+sr)*256 + kt*64 + c0];
    *(half8*)&sAh[sr][c0+8] = *(const half8*)&agg[(size_t)(rb+sr)*256 + kt*64 + c0 + 8];
    stageB(&poW16[(size_t)sr*832 + 64 + kt*64 + c0]);
    __syncthreads();
    mfma8(z0a);
    __syncthreads();
    stageB(&poW16[(size_t)sr*832 + 64 + 256 + kt*64 + c0]);
    __syncthreads();
    mfma8(z1a);
    __syncthreads();
    stageB(&poW16[(size_t)sr*832 + 64 + 512 + kt*64 + c0]);
    __syncthreads();
    mfma8(z2a);
  }
  __syncthreads();
  #pragma unroll
  for (int n16=0; n16<4; ++n16){
    #pragma unroll
    for (int reg=0; reg<4; ++reg){
      int row = w*16 + (l>>4)*4 + reg;
      int col = n16*16 + (l&15);
      float s1v = sS[row*2], s2v = sS[row*2+1];
      float v = hacc[n16][reg] + z0a[n16][reg] + s1v*z1a[n16][reg] + s2v*z2a[n16][reg] + pob[col];
      sAh[row][col] = (_Float16)v;
    }
  }
  stageB(&clW16[(size_t)sr*64 + c0]);
  __syncthreads();
  f32x4 cacc[4] = {};
  mfma8(cacc);
  float cs_[4], cq_[4];
  #pragma unroll
  for (int n16=0; n16<4; ++n16){ cs_[n16]=0.0f; cq_[n16]=0.0f; }
  #pragma unroll
  for (int n16=0; n16<4; ++n16){
    #pragma unroll
    for (int reg=0; reg<4; ++reg){
      int row = w*16 + (l>>4)*4 + reg;
      int col = n16*16 + (l&15);
      float v = cacc[n16][reg] + clb[col];
      hy[(size_t)(rb+row)*64 + col] = (_Float16)v;
      cs_[n16] += v; cq_[n16] += v*v;
    }
  }
  int slot = w*4 + (l>>4);
  #pragma unroll
  for (int n16=0; n16<4; ++n16){
    int col = n16*16 + (l&15);
    sredS[slot][col] = cs_[n16];
    sredQ[slot][col] = cq_[n16];
  }
  __syncthreads();
  if (t < 64){
    float S=0.0f, Q=0.0f;
    #pragma unroll
    for(int q2=0;q2<16;q2++){ S += sredS[q2][t]; Q += sredQ[q2][t]; }
    part[(size_t)blockIdx.x*128 + t]      = S;
    part[(size_t)blockIdx.x*128 + 64 + t] = Q;
  }
}

// ---- BN finalize: hierarchical (1024 thr = 64 cols x 16 chunks) -----------
__global__ __launch_bounds__(1024) void k_bnfin(const float* part, const float* g, const float* bb,
                                                float* sc, float* sh){
  __shared__ double sS[16][64], sQ[16][64];
  int t = threadIdx.x;
  int c = t&63, chunk = t>>6;
  double S=0.0, Q=0.0;
  for(int b=chunk; b<2048; b+=16){
    S += (double)part[(size_t)b*128 + c];
    Q += (double)part[(size_t)b*128 + 64 + c];
  }
  sS[chunk][c]=S; sQ[chunk][c]=Q;
  __syncthreads();
  if(t<64){
    double St=0.0, Qt=0.0;
    #pragma unroll
    for(int q=0;q<16;q++){ St+=sS[q][t]; Qt+=sQ[q][t]; }
    double mean = St/(double)NN;
    double var  = Qt/(double)NN - mean*mean;
    float scale = g[t] * (float)(1.0/sqrt(var+1e-5));
    sc[t]=scale;
    sh[t]=bb[t] - (float)mean*scale;
  }
}

// ---- final BN apply in place on hy (fp16) ---------------------------------
__global__ void k_bnapply16(_Float16* hy, const float* sc, const float* sh){
  int idx = blockIdx.x*256+threadIdx.x;
  for(int i=idx; i<NN*8; i+=256*2048){
    int c0 = (i&7)*8;
    half8 v = *(const half8*)&hy[(size_t)i*8];
    half8 r;
    #pragma unroll
    for(int q=0;q<8;q++) r[q]=(_Float16)fmaxf((float)v[q]*sc[c0+q]+sh[c0+q],0.0f);
    *(half8*)&hy[(size_t)i*8] = r;
  }
}

// ---- set2set LSTM: 8 graphs/block, float4 weights reused x8, 8 acc chains -
__global__ __launch_bounds__(256) void k_lstm_lit(float* A, float* cs,
      const float* Wih, const float* Whh, const float* bih, const float* bhh){
  __shared__ float sA[8][128];
  __shared__ float sg[8][256];
  int t=threadIdx.x;
  int g0 = blockIdx.x*8;
  for(int i=t;i<1024;i+=256) sA[i>>7][i&127] = A[(size_t)(g0+(i>>7))*128 + (i&127)];
  __syncthreads();
  float bb2 = bih[t]+bhh[t];
  float acc[8];
  #pragma unroll
  for(int g=0;g<8;g++) acc[g]=bb2;
  for(int k=0;k<128;k+=4){
    float4 wv = *(const float4*)&Wih[(size_t)t*128+k];
    #pragma unroll
    for(int g=0;g<8;g++)
      acc[g] += wv.x*sA[g][k] + wv.y*sA[g][k+1] + wv.z*sA[g][k+2] + wv.w*sA[g][k+3];
  }
  for(int k=0;k<64;k+=4){
    float4 wv = *(const float4*)&Whh[(size_t)t*64+k];
    #pragma unroll
    for(int g=0;g<8;g++)
      acc[g] += wv.x*sA[g][k] + wv.y*sA[g][k+1] + wv.z*sA[g][k+2] + wv.w*sA[g][k+3];
  }
  #pragma unroll
  for(int g=0;g<8;g++) sg[g][t]=acc[g];
  __syncthreads();
  for(int i=t;i<512;i+=256){
    int g=i>>6, j=i&63;
    float ig=sg[g][j], fg=sg[g][64+j], gg=sg[g][128+j], og=sg[g][192+j];
    float c = sigmoidf_(fg)*cs[(size_t)(g0+g)*64+j] + sigmoidf_(ig)*tanhf(gg);
    float hv = sigmoidf_(og)*tanhf(c);
    cs[(size_t)(g0+g)*64+j]=c;
    A[(size_t)(g0+g)*128+j]=hv;
  }
}

// ---- fused edot+attn: parallel e-compute (lane i owns node i) -------------
__global__ __launch_bounds__(64) void k_attn_f(const _Float16* h16, const int* gptr, float* A){
  __shared__ _Float16 sH[ACAP][66];
  __shared__ float sE[ACAP];
  __shared__ float saq[64];
  int g=blockIdx.x, j=threadIdx.x;
  int lo=gptr[g], hi=gptr[g+1];
  int cnt=hi-lo;
  if(cnt<=0){ A[(size_t)g*128+64+j]=0.0f; return; }
  float aq = A[(size_t)g*128+j];
  saq[j]=aq;
  if(cnt<=ACAP){
    for(int i=0;i<cnt;++i) sH[i][j] = h16[(size_t)(lo+i)*64+j];
    __syncthreads();
    for(int i=j;i<cnt;i+=64){
      float v=0.0f;
      for(int k=0;k<64;k++) v += (float)sH[i][k]*saq[k];
      sE[i]=v;
    }
    __syncthreads();
    float mx=-1e30f;
    for(int i=j;i<cnt;i+=64) mx=fmaxf(mx,sE[i]);
    #pragma unroll
    for(int m=32;m;m>>=1) mx=fmaxf(mx,__shfl_xor(mx,m,64));
    float s=0.0f;
    for(int i=j;i<cnt;i+=64) s+=expf(sE[i]-mx);
    #pragma unroll
    for(int m=32;m;m>>=1) s+=__shfl_xor(s,m,64);
    float inv=1.0f/(s+1e-16f);
    for(int i=j;i<cnt;i+=64) sE[i]=expf(sE[i]-mx)*inv;
    __syncthreads();
    float r=0.0f;
    for(int i=0;i<cnt;++i) r += sE[i]*(float)sH[i][j];
    A[(size_t)g*128+64+j]=r;
  } else {
    float mx=-1e30f;
    for(int n=lo;n<hi;++n){
      float v=(float)h16[(size_t)n*64+j]*aq;
      #pragma unroll
      for(int m=32;m;m>>=1) v+=__shfl_xor(v,m,64);
      mx=fmaxf(mx,v);
    }
    float s=0.0f;
    for(int n=lo;n<hi;++n){
      float v=(float)h16[(size_t)n*64+j]*aq;
      #pragma unroll
      for(int m=32;m;m>>=1) v+=__shfl_xor(v,m,64);
      s+=expf(v-mx);
    }
    float inv=1.0f/(s+1e-16f);
    float r=0.0f;
    for(int n=lo;n<hi;++n){
      float v=(float)h16[(size_t)n*64+j]*aq;
      #pragma unroll
      for(int m=32;m;m>>=1) v+=__shfl_xor(v,m,64);
      r+=expf(v-mx)*inv*(float)h16[(size_t)n*64+j];
    }
    A[(size_t)g*128+64+j]=r;
  }
}

__global__ __launch_bounds__(64) void k_mlp(const float* A, const float* tt, const float* pp,
     const float* W1,const float* b1,const float* W2,const float* b2,const float* W3,const float* b3,
     float* out){
  __shared__ float si[130]; __shared__ float o1[64]; __shared__ float o2[32];
  int g=blockIdx.x, t=threadIdx.x;
  si[t]=A[g*128+t]; si[64+t]=A[g*128+64+t];
  if(t==0){ si[128]=tt[g]; si[129]=pp[g]; }
  __syncthreads();
  float a=b1[t];
  for(int k=0;k<130;k++) a+=W1[t*130+k]*si[k];
  o1[t]=fmaxf(a,0.0f);
  __syncthreads();
  if(t<32){
    float a2=b2[t];
    #pragma unroll 4
    for(int k=0;k<64;k++) a2+=W2[t*64+k]*o1[k];
    o2[t]=fmaxf(a2,0.0f);
  }
  __syncthreads();
  float v = (t<32)? o2[t]*W3[t] : 0.0f;
  #pragma unroll
  for(int m=32;m;m>>=1) v+=__shfl_xor(v,m,64);
  if(t==0) out[g]=v+b3[0];
}

// ---- host -----------------------------------------------------------------
extern "C" void kernel_launch(void* const* d_in, const int* in_sizes, int n_in,
                              void* d_out, int out_size, void* d_ws, size_t ws_size,
                              hipStream_t stream) {
  static const int want[28] = {4194304,3145728,4096,4096,2048,64,1152,192,36864,192,
                               159744,192,12288,192,192,192,32768,16384,256,256,
                               8320,64,2048,32,32,1,1048576,131072};
  if (n_in != 28 || out_size != GG) return;
  for (int i=0;i<28;i++) if (in_sizes[i] != want[i]) return;

  const float* x     = (const float*)d_in[0];
  const float* ea    = (const float*)d_in[1];
  const float* tt    = (const float*)d_in[2];
  const float* pp    = (const float*)d_in[3];
  const float* lin1W = (const float*)d_in[4];
  const float* lin1b = (const float*)d_in[5];
  const float* edgeW = (const float*)d_in[6];
  const float* edgeb = (const float*)d_in[7];
  const float* preW  = (const float*)d_in[8];
  const float* preb  = (const float*)d_in[9];
  const float* postW = (const float*)d_in[10];
  const float* postb = (const float*)d_in[11];
  const float* clinW = (const float*)d_in[12];
  const float* clinb = (const float*)d_in[13];
  const float* bng   = (const float*)d_in[14];
  const float* bnb   = (const float*)d_in[15];
  const float* Wih   = (const float*)d_in[16];
  const float* Whh   = (const float*)d_in[17];
  const float* bih   = (const float*)d_in[18];
  const float* bhh   = (const float*)d_in[19];
  const float* W1    = (const float*)d_in[20];
  const float* b1    = (const float*)d_in[21];
  const float* W2    = (const float*)d_in[22];
  const float* b2    = (const float*)d_in[23];
  const float* W3    = (const float*)d_in[24];
  const float* b3    = (const float*)d_in[25];
  const int*   eidx  = (const int*)d_in[26];
  const int*   batch = (const int*)d_in[27];
  const int* esrc = eidx;
  const int* edst = eidx + EE;

  char* w = (char*)d_ws;
  auto alloc = [&](size_t bytes)->char*{ char* p=w; w += ((bytes+255)/256)*256; return p; };
  _Float16* agg  = (_Float16*)alloc((size_t)NN*256*2);  // 64MiB fp16
  _Float16* g12  = (_Float16*)alloc((size_t)NN*128*2);  // 32MiB fp16 (set2set scratch aliases)
  _Float16* hy   = (_Float16*)alloc((size_t)NN*64*2);   // 16MiB fp16
  int*   deg    = (int*)alloc((size_t)NN*4);
  int*   cursor = (int*)alloc((size_t)NN*4);
  int*   rowptr = (int*)alloc((size_t)(NN+1)*4);
  int*   spart  = (int*)alloc(512*4);
  int*   srcord = (int*)alloc((size_t)EE*4);
  float* eaord  = (float*)alloc((size_t)EE*6*4);
  float* s12   = (float*)alloc((size_t)NN*2*4);
  float* part  = (float*)alloc((size_t)2048*128*4);
  float* bnsc  = (float*)alloc(256);
  float* bnsh  = (float*)alloc(256);
  float* WfG   = (float*)alloc(3*384*4);
  float* bfG   = (float*)alloc(3*64*4);
  _Float16* preW16 = (_Float16*)alloc(36864*2);
  _Float16* poW16  = (_Float16*)alloc(159744*2);
  _Float16* clW16  = (_Float16*)alloc(12288*2);
  int*   gptr  = (int*)alloc((GG+1)*4);
  size_t need = (size_t)(w - (char*)d_ws);
  if (need > ws_size) return;
  float* A    = (float*)g12;
  float* cs   = (float*)g12 + (size_t)GG*128;

  double num = 13107.0*log(2.0)+26214.0*log(3.0)+65536.0*log(4.0)+26215.0*log(5.0);
  float avgdl = (float)(num/131072.0);

  // deg and cursor are adjacent 256-aligned allocations: one memset covers both
  hipMemsetAsync(deg, 0, (size_t)NN*4*2, stream);
  hipLaunchKernelGGL(k_deg, dim3(2048), dim3(256), 0, stream, edst, deg);
  hipLaunchKernelGGL(k_scan_part, dim3(512), dim3(256), 0, stream, deg, spart);
  hipLaunchKernelGGL(k_scan_top, dim3(1), dim3(512), 0, stream, spart);
  hipLaunchKernelGGL(k_scan_apply, dim3(512), dim3(256), 0, stream, deg, spart, rowptr);
  hipLaunchKernelGGL(k_fill, dim3(2048), dim3(256), 0, stream, edst, esrc, ea, rowptr, cursor, srcord, eaord);

  hipLaunchKernelGGL(k_gptr, dim3(17), dim3(256), 0, stream, batch, gptr);
  hipLaunchKernelGGL(k_prepwf, dim3(3), dim3(448), 0, stream, preW, preb, edgeW, edgeb, WfG, bfG);
  hipLaunchKernelGGL(k_prepw16, dim3(817), dim3(256), 0, stream, preW, postW, clinW, preW16, poW16, clW16);
  hipLaunchKernelGGL(k_lin1_s, dim3(1024), dim3(256), 0, stream, x, lin1W, lin1b, hy);

  for (int i = 0; i < 3; ++i){
    const float* sc_i = (i==0)? nullptr : bnsc;
    const float* sh_i = (i==0)? nullptr : bnsh;
    hipLaunchKernelGGL(k_bnmsg, dim3(2048), dim3(256), 0, stream, hy, sc_i, sh_i,
        preW16 + (size_t)i*12288, g12);
    hipLaunchKernelGGL(k_gather_f, dim3(4096), dim3(256), 0, stream, rowptr, srcord, eaord, g12,
        WfG + (size_t)i*384, bfG + (size_t)i*64, agg, s12, avgdl);
    hipLaunchKernelGGL(k_tower_mfma, dim3(2048), dim3(256), 0, stream, hy, agg, s12,
        poW16 + (size_t)i*53248, postb + i*64, clW16 + (size_t)i*4096, clinb + i*64, part);
    hipLaunchKernelGGL(k_bnfin, dim3(1), dim3(1024), 0, stream, part, bng + i*64, bnb + i*64, bnsc, bnsh);
  }
  hipLaunchKernelGGL(k_bnapply16, dim3(2048), dim3(256), 0, stream, hy, bnsc, bnsh);

  hipMemsetAsync(A, 0, (size_t)GG*128*4, stream);
  hipMemsetAsync(cs, 0, (size_t)GG*64*4, stream);
  for (int s = 0; s < 3; ++s){
    hipLaunchKernelGGL(k_lstm_lit, dim3(512), dim3(256), 0, stream, A, cs, Wih, Whh, bih, bhh);
    hipLaunchKernelGGL(k_attn_f, dim3(GG), dim3(64), 0, stream, hy, gptr, A);
  }
  hipLaunchKernelGGL(k_mlp, dim3(GG), dim3(64), 0, stream, A, tt, pp, W1, b1, W2, b2, W3, b3, (float*)d_out);
}

// Round 27
// 636.664 us; speedup vs baseline: 1.3515x; 1.0271x over previous
//
#include <hip/hip_runtime.h>
#include <hip/hip_bf16.h>
#include <math.h>

#define NN 131072
#define EE 524288
#define GG 4096
#define GCAP 320
#define ACAP 96

typedef __attribute__((ext_vector_type(8))) _Float16 half8;
typedef __attribute__((ext_vector_type(4))) _Float16 half4;
typedef __attribute__((ext_vector_type(4))) float f32x4;

__device__ __forceinline__ float sigmoidf_(float x){ return 1.0f/(1.0f+expf(-x)); }

// ---- grouping / CSR (integer atomics only) --------------------------------
__global__ void k_gptr(const int* batch, int* gptr){
  int g = blockIdx.x*256+threadIdx.x;
  if (g > GG) return;
  if (g == GG){ gptr[GG]=NN; return; }
  int lo=0, hi=NN;
  while(lo<hi){ int mid=(lo+hi)>>1; if(batch[mid]<g) lo=mid+1; else hi=mid; }
  gptr[g]=lo;
}

__global__ void k_deg(const int* dst, int* deg){
  int e = blockIdx.x*256+threadIdx.x;
  if(e<EE) atomicAdd(&deg[dst[e]], 1);
}

// hierarchical scan
__global__ __launch_bounds__(256) void k_scan_part(const int* deg, int* part){
  __shared__ int red[256];
  int b=blockIdx.x, t=threadIdx.x;
  red[t] = deg[b*256+t];
  __syncthreads();
  for(int off=128; off>0; off>>=1){
    if(t<off) red[t]+=red[t+off];
    __syncthreads();
  }
  if(t==0) part[b]=red[0];
}

__global__ __launch_bounds__(512) void k_scan_top(int* part){
  __shared__ int s[512];
  int t=threadIdx.x;
  s[t]=part[t];
  __syncthreads();
  for(int off=1; off<512; off<<=1){
    int v=s[t];
    int add=(t>=off)?s[t-off]:0;
    __syncthreads();
    s[t]=v+add;
    __syncthreads();
  }
  part[t] = (t==0)?0:s[t-1];
}

__global__ __launch_bounds__(256) void k_scan_apply(const int* deg, const int* part, int* rowptr){
  __shared__ int s[256];
  int b=blockIdx.x, t=threadIdx.x;
  int v0=deg[b*256+t];
  s[t]=v0;
  __syncthreads();
  for(int off=1; off<256; off<<=1){
    int v=s[t];
    int add=(t>=off)?s[t-off]:0;
    __syncthreads();
    s[t]=v+add;
    __syncthreads();
  }
  rowptr[b*256+t] = part[b] + s[t]-v0;
  if(b==511 && t==255) rowptr[NN] = part[b] + s[t];
}

// fill CSR-ordered edge streams (ea copy vectorized float2)
__global__ void k_fill(const int* dst, const int* src, const float* ea,
                       const int* rowptr, int* cursor, int* srcord, float* eaord){
  int e = blockIdx.x*256+threadIdx.x;
  if(e>=EE) return;
  int d = dst[e];
  int pos = atomicAdd(&cursor[d], 1);
  int idx = rowptr[d]+pos;
  srcord[idx] = src[e];
  float2 e0 = *(const float2*)&ea[(size_t)e*6];
  float2 e1 = *(const float2*)&ea[(size_t)e*6+2];
  float2 e2 = *(const float2*)&ea[(size_t)e*6+4];
  *(float2*)&eaord[(size_t)idx*6]   = e0;
  *(float2*)&eaord[(size_t)idx*6+2] = e1;
  *(float2*)&eaord[(size_t)idx*6+4] = e2;
}

// ---- all-layers Wf/bf precompute (3 blocks) -------------------------------
__global__ __launch_bounds__(448) void k_prepwf(const float* preW, const float* preb,
      const float* eW, const float* eb, float* WfG, float* bfG){
  int i = blockIdx.x;
  const float* pW = preW + (size_t)i*64*192;
  const float* pb = preb + i*64;
  const float* eWl = eW + (size_t)i*384;
  const float* ebl = eb + i*64;
  int t=threadIdx.x;
  if(t<384){
    int j=t/6, d=t-j*6;
    float a=0.0f;
    for(int k=0;k<64;k++) a += pW[(size_t)j*192+128+k]*eWl[k*6+d];
    WfG[i*384+t]=a;
  } else if(t<448){
    int j=t-384;
    float a=pb[j];
    for(int k=0;k<64;k++) a += pW[(size_t)j*192+128+k]*ebl[k];
    bfG[i*64+j]=a;
  }
}

// ---- weights -> fp16 once (bit-identical to per-use conversion) -----------
__global__ void k_prepw16(const float* preW, const float* poW, const float* clW,
                          _Float16* preW16, _Float16* poW16, _Float16* clW16){
  int i = blockIdx.x*256 + threadIdx.x;
  if(i < 36864) preW16[i] = (_Float16)preW[i];
  else if(i < 36864+159744) poW16[i-36864] = (_Float16)poW[i-36864];
  else if(i < 36864+159744+12288) clW16[i-196608] = (_Float16)clW[i-196608];
}

// ---- y0 = x @ lin1W.T + b (pre-activation, fp16); grid-stride, padded sW --
__global__ __launch_bounds__(256) void k_lin1_s(const float* x, const float* W, const float* b, _Float16* y0){
  __shared__ float sW[2112];
  __shared__ float sb[64];
  int t=threadIdx.x;
  for(int i=t;i<2048;i+=256){ int j=i>>5,k=i&31; sW[j*33+k]=W[i]; }
  if(t<64) sb[t]=b[t];
  __syncthreads();
  int w = t>>6, j = t&63;
  for(int it=0; it<32; ++it){
    int n = (blockIdx.x*4 + w) + it*4096;
    float acc = sb[j];
    #pragma unroll 8
    for(int k=0;k<32;k++) acc += x[(size_t)n*32+k]*sW[j*33+k];
    y0[(size_t)n*64+j] = (_Float16)acc;
  }
}

// ---- k_bnmsg: hy := relu(hy*sc+sh) in place; g12 = h @ [Wd|Ws].T (MFMA) ---
__global__ __launch_bounds__(256) void k_bnmsg(_Float16* hy, const float* sc, const float* sh,
      const _Float16* preW16, _Float16* g12){
  __shared__ _Float16 sAh[64][72];
  __shared__ _Float16 sB0[64][72];
  __shared__ _Float16 sB1[64][72];
  __shared__ float ssc[64], ssh[64];
  int t=threadIdx.x;
  int rb = blockIdx.x*64;
  if(t<64){ ssc[t] = sc? sc[t] : 1.0f; ssh[t] = sh? sh[t] : 0.0f; }
  __syncthreads();
  int sr = t>>2, c0 = (t&3)*16;
  {
    half8 y0 = *(const half8*)&hy[(size_t)(rb+sr)*64 + c0];
    half8 y1 = *(const half8*)&hy[(size_t)(rb+sr)*64 + c0 + 8];
    half8 h0, h1;
    #pragma unroll
    for(int q=0;q<8;q++){
      h0[q] = (_Float16)fmaxf((float)y0[q]*ssc[c0+q]   + ssh[c0+q],   0.0f);
      h1[q] = (_Float16)fmaxf((float)y1[q]*ssc[c0+8+q] + ssh[c0+8+q], 0.0f);
    }
    *(half8*)&sAh[sr][c0]   = h0;
    *(half8*)&sAh[sr][c0+8] = h1;
    *(half8*)&hy[(size_t)(rb+sr)*64 + c0]     = h0;
    *(half8*)&hy[(size_t)(rb+sr)*64 + c0 + 8] = h1;
    const _Float16* w0 = &preW16[(size_t)sr*192 + c0];
    const _Float16* w1 = &preW16[(size_t)sr*192 + 64 + c0];
    *(half8*)&sB0[sr][c0]   = *(const half8*)&w0[0];
    *(half8*)&sB0[sr][c0+8] = *(const half8*)&w0[8];
    *(half8*)&sB1[sr][c0]   = *(const half8*)&w1[0];
    *(half8*)&sB1[sr][c0+8] = *(const half8*)&w1[8];
  }
  __syncthreads();
  int w=t>>6, l=t&63;
  f32x4 acc0[4]={}, acc1[4]={};
  #pragma unroll
  for(int kk=0; kk<2; ++kk){
    half8 a = *(const half8*)&sAh[w*16+(l&15)][kk*32+(l>>4)*8];
    #pragma unroll
    for(int n16=0;n16<4;++n16){
      half8 b0 = *(const half8*)&sB0[n16*16+(l&15)][kk*32+(l>>4)*8];
      half8 b1 = *(const half8*)&sB1[n16*16+(l&15)][kk*32+(l>>4)*8];
      acc0[n16] = __builtin_amdgcn_mfma_f32_16x16x32_f16(a,b0,acc0[n16],0,0,0);
      acc1[n16] = __builtin_amdgcn_mfma_f32_16x16x32_f16(a,b1,acc1[n16],0,0,0);
    }
  }
  #pragma unroll
  for(int n16=0;n16<4;++n16){
    #pragma unroll
    for(int reg=0; reg<4; ++reg){
      int row = w*16+(l>>4)*4+reg;
      int col = n16*16+(l&15);
      g12[(size_t)(rb+row)*128 + col]      = (_Float16)acc0[n16][reg];
      g12[(size_t)(rb+row)*128 + 64 + col] = (_Float16)acc1[n16][reg];
    }
  }
}

// ---- gather: 32 nodes/block; block-level GCAP specialization --------------
__global__ __launch_bounds__(256) void k_gather_f(const int* rowptr, const int* srcord,
      const float* eaord, const _Float16* g12, const float* WfG, const float* bfG,
      _Float16* agg, float* s12, float avgdl){
  __shared__ float sWf[64][6];
  __shared__ float sbf[64];
  __shared__ int   sRow[33];
  __shared__ int   sSrc[GCAP];
  __shared__ float sEA[GCAP][8];
  int t=threadIdx.x;
  int rb = blockIdx.x*32;
  for(int i=t; i<384; i+=256) ((float*)sWf)[i]=WfG[i];
  if(t<64) sbf[t]=bfG[t];
  if(t<33) sRow[t]=rowptr[rb+t];
  __syncthreads();
  int eLo = sRow[0];
  int cnt = sRow[32]-eLo;
  int ccap = (cnt<GCAP)? cnt : GCAP;
  for(int i=t; i<ccap; i+=256) sSrc[i]=srcord[eLo+i];
  for(int i=t; i<ccap; i+=256){
    float2 e0 = *(const float2*)&eaord[(size_t)(eLo+i)*6];
    float2 e1 = *(const float2*)&eaord[(size_t)(eLo+i)*6+2];
    float2 e2 = *(const float2*)&eaord[(size_t)(eLo+i)*6+4];
    *(float2*)&sEA[i][0]=e0;
    *(float2*)&sEA[i][2]=e1;
    *(float2*)&sEA[i][4]=e2;
  }
  __syncthreads();
  int w=t>>6, j=t&63;
  float wf0=sWf[j][0], wf1=sWf[j][1], wf2=sWf[j][2];
  float wf3=sWf[j][3], wf4=sWf[j][4], wf5=sWf[j][5];
  float bfj=sbf[j];
  if(cnt<=GCAP){
    for(int q=0; q<8; ++q){
      int ln = w*8 + q;
      int n  = rb + ln;
      int lo = sRow[ln]-eLo, hi = sRow[ln+1]-eLo;
      float mdst = (float)g12[(size_t)n*128+j] + bfj;
      float sum=0.0f, sq=0.0f, mn=1e30f, mx=-1e30f;
      int r=lo;
      for(; r+1<hi; r+=2){
        int s0=sSrc[r], s1=sSrc[r+1];
        float4 va = *(const float4*)&sEA[r][0];
        float2 vb = *(const float2*)&sEA[r][4];
        float4 wa = *(const float4*)&sEA[r+1][0];
        float2 wb = *(const float2*)&sEA[r+1][4];
        float g0 = (float)g12[(size_t)s0*128+64+j];
        float g1 = (float)g12[(size_t)s1*128+64+j];
        float m0 = mdst + g0 + va.x*wf0 + va.y*wf1 + va.z*wf2 + va.w*wf3 + vb.x*wf4 + vb.y*wf5;
        float m1 = mdst + g1 + wa.x*wf0 + wa.y*wf1 + wa.z*wf2 + wa.w*wf3 + wb.x*wf4 + wb.y*wf5;
        sum += m0; sq += m0*m0; mn = fminf(mn,m0); mx = fmaxf(mx,m0);
        sum += m1; sq += m1*m1; mn = fminf(mn,m1); mx = fmaxf(mx,m1);
      }
      if(r<hi){
        int s0=sSrc[r];
        float4 va = *(const float4*)&sEA[r][0];
        float2 vb = *(const float2*)&sEA[r][4];
        float g0 = (float)g12[(size_t)s0*128+64+j];
        float m0 = mdst + g0 + va.x*wf0 + va.y*wf1 + va.z*wf2 + va.w*wf3 + vb.x*wf4 + vb.y*wf5;
        sum += m0; sq += m0*m0; mn = fminf(mn,m0); mx = fmaxf(mx,m0);
      }
      int c = hi-lo;
      float cm = fmaxf((float)c, 1.0f);
      float mean = sum/cm;
      float sd = sqrtf(fmaxf(sq/cm - mean*mean, 0.0f)+1e-5f);
      bool has = c>0;
      size_t base = (size_t)n*256;
      agg[base+j]     = (_Float16)mean;
      agg[base+64+j]  = (_Float16)(has?mn:0.0f);
      agg[base+128+j] = (_Float16)(has?mx:0.0f);
      agg[base+192+j] = (_Float16)sd;
      if(j==0){ float ld=logf(cm+1.0f); s12[n*2]=ld/avgdl; s12[n*2+1]=avgdl/ld; }
    }
  } else {
    for(int q=0; q<8; ++q){
      int ln = w*8 + q;
      int n  = rb + ln;
      int lo = sRow[ln], hi = sRow[ln+1];
      float mdst = (float)g12[(size_t)n*128+j] + bfj;
      float sum=0.0f, sq=0.0f, mn=1e30f, mx=-1e30f;
      int idx=lo;
      for(; idx+1<hi; idx+=2){
        int r0 = idx-eLo, r1 = r0+1;
        int s0, s1;
        float e00,e01,e02,e03,e04,e05, e10,e11,e12,e13,e14,e15;
        if(r1 < GCAP){
          s0=sSrc[r0]; s1=sSrc[r1];
          float4 va = *(const float4*)&sEA[r0][0];
          float2 vb = *(const float2*)&sEA[r0][4];
          float4 wa = *(const float4*)&sEA[r1][0];
          float2 wb = *(const float2*)&sEA[r1][4];
          e00=va.x; e01=va.y; e02=va.z; e03=va.w; e04=vb.x; e05=vb.y;
          e10=wa.x; e11=wa.y; e12=wa.z; e13=wa.w; e14=wb.x; e15=wb.y;
        } else {
          s0=srcord[idx]; s1=srcord[idx+1];
          e00=eaord[(size_t)idx*6+0]; e01=eaord[(size_t)idx*6+1]; e02=eaord[(size_t)idx*6+2];
          e03=eaord[(size_t)idx*6+3]; e04=eaord[(size_t)idx*6+4]; e05=eaord[(size_t)idx*6+5];
          e10=eaord[(size_t)(idx+1)*6+0]; e11=eaord[(size_t)(idx+1)*6+1]; e12=eaord[(size_t)(idx+1)*6+2];
          e13=eaord[(size_t)(idx+1)*6+3]; e14=eaord[(size_t)(idx+1)*6+4]; e15=eaord[(size_t)(idx+1)*6+5];
        }
        float g0 = (float)g12[(size_t)s0*128+64+j];
        float g1 = (float)g12[(size_t)s1*128+64+j];
        float m0 = mdst + g0 + e00*wf0 + e01*wf1 + e02*wf2 + e03*wf3 + e04*wf4 + e05*wf5;
        float m1 = mdst + g1 + e10*wf0 + e11*wf1 + e12*wf2 + e13*wf3 + e14*wf4 + e15*wf5;
        sum += m0; sq += m0*m0; mn = fminf(mn,m0); mx = fmaxf(mx,m0);
        sum += m1; sq += m1*m1; mn = fminf(mn,m1); mx = fmaxf(mx,m1);
      }
      if(idx<hi){
        int r0 = idx-eLo;
        int s0; float e00,e01,e02,e03,e04,e05;
        if(r0 < GCAP){
          s0=sSrc[r0];
          float4 va = *(const float4*)&sEA[r0][0];
          float2 vb = *(const float2*)&sEA[r0][4];
          e00=va.x; e01=va.y; e02=va.z; e03=va.w; e04=vb.x; e05=vb.y;
        } else {
          s0=srcord[idx];
          e00=eaord[(size_t)idx*6+0]; e01=eaord[(size_t)idx*6+1]; e02=eaord[(size_t)idx*6+2];
          e03=eaord[(size_t)idx*6+3]; e04=eaord[(size_t)idx*6+4]; e05=eaord[(size_t)idx*6+5];
        }
        float g0 = (float)g12[(size_t)s0*128+64+j];
        float m0 = mdst + g0 + e00*wf0 + e01*wf1 + e02*wf2 + e03*wf3 + e04*wf4 + e05*wf5;
        sum += m0; sq += m0*m0; mn = fminf(mn,m0); mx = fmaxf(mx,m0);
      }
      int c = hi-lo;
      float cm = fmaxf((float)c, 1.0f);
      float mean = sum/cm;
      float sd = sqrtf(fmaxf(sq/cm - mean*mean, 0.0f)+1e-5f);
      bool has = c>0;
      size_t base = (size_t)n*256;
      agg[base+j]     = (_Float16)mean;
      agg[base+64+j]  = (_Float16)(has?mn:0.0f);
      agg[base+128+j] = (_Float16)(has?mx:0.0f);
      agg[base+192+j] = (_Float16)sd;
      if(j==0){ float ld=logf(cm+1.0f); s12[n*2]=ld/avgdl; s12[n*2+1]=avgdl/ld; }
    }
  }
}

// ---- k_tower_mfma v3: 3-plane staging (24 MFMA per barrier pair) ----------
// y1 = h@Wh.T + z0 + s1*z1 + s2*z2 + pob ; y2 = f16(y1)@clinW.T + clb
// MFMA sequence per accumulator identical to v2 -> bit-identical output.
__global__ __launch_bounds__(256) void k_tower_mfma(_Float16* hy, const _Float16* agg, const float* s12,
        const _Float16* poW16, const float* pob, const _Float16* clW16, const float* clb, float* part){
  __shared__ _Float16 sAh[64][72];
  __shared__ _Float16 sB0[64][72];
  __shared__ _Float16 sB1[64][72];
  __shared__ _Float16 sB2[64][72];
  __shared__ float sS[128];
  __shared__ float sredS[16][64];
  __shared__ float sredQ[16][64];
  int t = threadIdx.x;
  int rb = blockIdx.x*64;
  int w = t>>6, l = t&63;
  int sr = t>>2, c0 = (t&3)*16;
  if (t < 128) sS[t] = s12[(size_t)(rb+(t>>1))*2 + (t&1)];
  f32x4 hacc[4]={}, z0a[4]={}, z1a[4]={}, z2a[4]={};
  auto stageTo = [&](_Float16 (*dst)[72], const _Float16* wr){
    *(half8*)&dst[sr][c0]   = *(const half8*)&wr[0];
    *(half8*)&dst[sr][c0+8] = *(const half8*)&wr[8];
  };
  auto mfma8 = [&](f32x4* acc, _Float16 (*B)[72]){
    #pragma unroll
    for (int kk=0; kk<2; ++kk){
      half8 a = *(const half8*)&sAh[w*16 + (l&15)][kk*32 + (l>>4)*8];
      #pragma unroll
      for (int n16=0; n16<4; ++n16){
        half8 b = *(const half8*)&B[n16*16 + (l&15)][kk*32 + (l>>4)*8];
        acc[n16] = __builtin_amdgcn_mfma_f32_16x16x32_f16(a, b, acc[n16], 0, 0, 0);
      }
    }
  };
  // phase h: A=hy, B0 = poW cols 0..63
  stageTo(sAh, &hy[(size_t)(rb+sr)*64 + c0]);
  stageTo(sB0, &poW16[(size_t)sr*832 + c0]);
  __syncthreads();
  mfma8(hacc, sB0);
  // 4 k-tiles: stage A=agg[kt] + 3 weight planes, then 24 MFMA
  for (int kt=0; kt<4; ++kt){
    __syncthreads();   // all reads of sAh/sB* complete
    stageTo(sAh, &agg[(size_t)(rb+sr)*256 + kt*64 + c0]);
    stageTo(sB0, &poW16[(size_t)sr*832 + 64 + kt*64 + c0]);
    stageTo(sB1, &poW16[(size_t)sr*832 + 64 + 256 + kt*64 + c0]);
    stageTo(sB2, &poW16[(size_t)sr*832 + 64 + 512 + kt*64 + c0]);
    __syncthreads();
    mfma8(z0a, sB0);
    mfma8(z1a, sB1);
    mfma8(z2a, sB2);
  }
  __syncthreads();
  // epilogue: y1 -> fp16 into sAh (D layout: col=lane&15, row=(lane>>4)*4+reg)
  #pragma unroll
  for (int n16=0; n16<4; ++n16){
    #pragma unroll
    for (int reg=0; reg<4; ++reg){
      int row = w*16 + (l>>4)*4 + reg;
      int col = n16*16 + (l&15);
      float s1v = sS[row*2], s2v = sS[row*2+1];
      float v = hacc[n16][reg] + z0a[n16][reg] + s1v*z1a[n16][reg] + s2v*z2a[n16][reg] + pob[col];
      sAh[row][col] = (_Float16)v;
    }
  }
  stageTo(sB0, &clW16[(size_t)sr*64 + c0]);
  __syncthreads();
  f32x4 cacc[4] = {};
  mfma8(cacc, sB0);
  float cs_[4], cq_[4];
  #pragma unroll
  for (int n16=0; n16<4; ++n16){ cs_[n16]=0.0f; cq_[n16]=0.0f; }
  #pragma unroll
  for (int n16=0; n16<4; ++n16){
    #pragma unroll
    for (int reg=0; reg<4; ++reg){
      int row = w*16 + (l>>4)*4 + reg;
      int col = n16*16 + (l&15);
      float v = cacc[n16][reg] + clb[col];
      hy[(size_t)(rb+row)*64 + col] = (_Float16)v;
      cs_[n16] += v; cq_[n16] += v*v;
    }
  }
  int slot = w*4 + (l>>4);
  #pragma unroll
  for (int n16=0; n16<4; ++n16){
    int col = n16*16 + (l&15);
    sredS[slot][col] = cs_[n16];
    sredQ[slot][col] = cq_[n16];
  }
  __syncthreads();
  if (t < 64){
    float S=0.0f, Q=0.0f;
    #pragma unroll
    for(int q2=0;q2<16;q2++){ S += sredS[q2][t]; Q += sredQ[q2][t]; }
    part[(size_t)blockIdx.x*128 + t]      = S;
    part[(size_t)blockIdx.x*128 + 64 + t] = Q;
  }
}

// ---- BN finalize: hierarchical (1024 thr = 64 cols x 16 chunks) -----------
__global__ __launch_bounds__(1024) void k_bnfin(const float* part, const float* g, const float* bb,
                                                float* sc, float* sh){
  __shared__ double sS[16][64], sQ[16][64];
  int t = threadIdx.x;
  int c = t&63, chunk = t>>6;
  double S=0.0, Q=0.0;
  for(int b=chunk; b<2048; b+=16){
    S += (double)part[(size_t)b*128 + c];
    Q += (double)part[(size_t)b*128 + 64 + c];
  }
  sS[chunk][c]=S; sQ[chunk][c]=Q;
  __syncthreads();
  if(t<64){
    double St=0.0, Qt=0.0;
    #pragma unroll
    for(int q=0;q<16;q++){ St+=sS[q][t]; Qt+=sQ[q][t]; }
    double mean = St/(double)NN;
    double var  = Qt/(double)NN - mean*mean;
    float scale = g[t] * (float)(1.0/sqrt(var+1e-5));
    sc[t]=scale;
    sh[t]=bb[t] - (float)mean*scale;
  }
}

// ---- final BN apply in place on hy (fp16) ---------------------------------
__global__ void k_bnapply16(_Float16* hy, const float* sc, const float* sh){
  int idx = blockIdx.x*256+threadIdx.x;
  for(int i=idx; i<NN*8; i+=256*2048){
    int c0 = (i&7)*8;
    half8 v = *(const half8*)&hy[(size_t)i*8];
    half8 r;
    #pragma unroll
    for(int q=0;q<8;q++) r[q]=(_Float16)fmaxf((float)v[q]*sc[c0+q]+sh[c0+q],0.0f);
    *(half8*)&hy[(size_t)i*8] = r;
  }
}

// ---- set2set LSTM: 8 graphs/block, float4 weights reused x8, 8 acc chains -
__global__ __launch_bounds__(256) void k_lstm_lit(float* A, float* cs,
      const float* Wih, const float* Whh, const float* bih, const float* bhh){
  __shared__ float sA[8][128];
  __shared__ float sg[8][256];
  int t=threadIdx.x;
  int g0 = blockIdx.x*8;
  for(int i=t;i<1024;i+=256) sA[i>>7][i&127] = A[(size_t)(g0+(i>>7))*128 + (i&127)];
  __syncthreads();
  float bb2 = bih[t]+bhh[t];
  float acc[8];
  #pragma unroll
  for(int g=0;g<8;g++) acc[g]=bb2;
  for(int k=0;k<128;k+=4){
    float4 wv = *(const float4*)&Wih[(size_t)t*128+k];
    #pragma unroll
    for(int g=0;g<8;g++)
      acc[g] += wv.x*sA[g][k] + wv.y*sA[g][k+1] + wv.z*sA[g][k+2] + wv.w*sA[g][k+3];
  }
  for(int k=0;k<64;k+=4){
    float4 wv = *(const float4*)&Whh[(size_t)t*64+k];
    #pragma unroll
    for(int g=0;g<8;g++)
      acc[g] += wv.x*sA[g][k] + wv.y*sA[g][k+1] + wv.z*sA[g][k+2] + wv.w*sA[g][k+3];
  }
  #pragma unroll
  for(int g=0;g<8;g++) sg[g][t]=acc[g];
  __syncthreads();
  for(int i=t;i<512;i+=256){
    int g=i>>6, j=i&63;
    float ig=sg[g][j], fg=sg[g][64+j], gg=sg[g][128+j], og=sg[g][192+j];
    float c = sigmoidf_(fg)*cs[(size_t)(g0+g)*64+j] + sigmoidf_(ig)*tanhf(gg);
    float hv = sigmoidf_(og)*tanhf(c);
    cs[(size_t)(g0+g)*64+j]=c;
    A[(size_t)(g0+g)*128+j]=hv;
  }
}

// ---- fused edot+attn: parallel e-compute (lane i owns node i) -------------
__global__ __launch_bounds__(64) void k_attn_f(const _Float16* h16, const int* gptr, float* A){
  __shared__ _Float16 sH[ACAP][66];
  __shared__ float sE[ACAP];
  __shared__ float saq[64];
  int g=blockIdx.x, j=threadIdx.x;
  int lo=gptr[g], hi=gptr[g+1];
  int cnt=hi-lo;
  if(cnt<=0){ A[(size_t)g*128+64+j]=0.0f; return; }
  float aq = A[(size_t)g*128+j];
  saq[j]=aq;
  if(cnt<=ACAP){
    for(int i=0;i<cnt;++i) sH[i][j] = h16[(size_t)(lo+i)*64+j];
    __syncthreads();
    for(int i=j;i<cnt;i+=64){
      float v=0.0f;
      for(int k=0;k<64;k++) v += (float)sH[i][k]*saq[k];
      sE[i]=v;
    }
    __syncthreads();
    float mx=-1e30f;
    for(int i=j;i<cnt;i+=64) mx=fmaxf(mx,sE[i]);
    #pragma unroll
    for(int m=32;m;m>>=1) mx=fmaxf(mx,__shfl_xor(mx,m,64));
    float s=0.0f;
    for(int i=j;i<cnt;i+=64) s+=expf(sE[i]-mx);
    #pragma unroll
    for(int m=32;m;m>>=1) s+=__shfl_xor(s,m,64);
    float inv=1.0f/(s+1e-16f);
    for(int i=j;i<cnt;i+=64) sE[i]=expf(sE[i]-mx)*inv;
    __syncthreads();
    float r=0.0f;
    for(int i=0;i<cnt;++i) r += sE[i]*(float)sH[i][j];
    A[(size_t)g*128+64+j]=r;
  } else {
    float mx=-1e30f;
    for(int n=lo;n<hi;++n){
      float v=(float)h16[(size_t)n*64+j]*aq;
      #pragma unroll
      for(int m=32;m;m>>=1) v+=__shfl_xor(v,m,64);
      mx=fmaxf(mx,v);
    }
    float s=0.0f;
    for(int n=lo;n<hi;++n){
      float v=(float)h16[(size_t)n*64+j]*aq;
      #pragma unroll
      for(int m=32;m;m>>=1) v+=__shfl_xor(v,m,64);
      s+=expf(v-mx);
    }
    float inv=1.0f/(s+1e-16f);
    float r=0.0f;
    for(int n=lo;n<hi;++n){
      float v=(float)h16[(size_t)n*64+j]*aq;
      #pragma unroll
      for(int m=32;m;m>>=1) v+=__shfl_xor(v,m,64);
      r+=expf(v-mx)*inv*(float)h16[(size_t)n*64+j];
    }
    A[(size_t)g*128+64+j]=r;
  }
}

__global__ __launch_bounds__(64) void k_mlp(const float* A, const float* tt, const float* pp,
     const float* W1,const float* b1,const float* W2,const float* b2,const float* W3,const float* b3,
     float* out){
  __shared__ float si[130]; __shared__ float o1[64]; __shared__ float o2[32];
  int g=blockIdx.x, t=threadIdx.x;
  si[t]=A[g*128+t]; si[64+t]=A[g*128+64+t];
  if(t==0){ si[128]=tt[g]; si[129]=pp[g]; }
  __syncthreads();
  float a=b1[t];
  for(int k=0;k<130;k++) a+=W1[t*130+k]*si[k];
  o1[t]=fmaxf(a,0.0f);
  __syncthreads();
  if(t<32){
    float a2=b2[t];
    #pragma unroll 4
    for(int k=0;k<64;k++) a2+=W2[t*64+k]*o1[k];
    o2[t]=fmaxf(a2,0.0f);
  }
  __syncthreads();
  float v = (t<32)? o2[t]*W3[t] : 0.0f;
  #pragma unroll
  for(int m=32;m;m>>=1) v+=__shfl_xor(v,m,64);
  if(t==0) out[g]=v+b3[0];
}

// ---- host -----------------------------------------------------------------
extern "C" void kernel_launch(void* const* d_in, const int* in_sizes, int n_in,
                              void* d_out, int out_size, void* d_ws, size_t ws_size,
                              hipStream_t stream) {
  static const int want[28] = {4194304,3145728,4096,4096,2048,64,1152,192,36864,192,
                               159744,192,12288,192,192,192,32768,16384,256,256,
                               8320,64,2048,32,32,1,1048576,131072};
  if (n_in != 28 || out_size != GG) return;
  for (int i=0;i<28;i++) if (in_sizes[i] != want[i]) return;

  const float* x     = (const float*)d_in[0];
  const float* ea    = (const float*)d_in[1];
  const float* tt    = (const float*)d_in[2];
  const float* pp    = (const float*)d_in[3];
  const float* lin1W = (const float*)d_in[4];
  const float* lin1b = (const float*)d_in[5];
  const float* edgeW = (const float*)d_in[6];
  const float* edgeb = (const float*)d_in[7];
  const float* preW  = (const float*)d_in[8];
  const float* preb  = (const float*)d_in[9];
  const float* postW = (const float*)d_in[10];
  const float* postb = (const float*)d_in[11];
  const float* clinW = (const float*)d_in[12];
  const float* clinb = (const float*)d_in[13];
  const float* bng   = (const float*)d_in[14];
  const float* bnb   = (const float*)d_in[15];
  const float* Wih   = (const float*)d_in[16];
  const float* Whh   = (const float*)d_in[17];
  const float* bih   = (const float*)d_in[18];
  const float* bhh   = (const float*)d_in[19];
  const float* W1    = (const float*)d_in[20];
  const float* b1    = (const float*)d_in[21];
  const float* W2    = (const float*)d_in[22];
  const float* b2    = (const float*)d_in[23];
  const float* W3    = (const float*)d_in[24];
  const float* b3    = (const float*)d_in[25];
  const int*   eidx  = (const int*)d_in[26];
  const int*   batch = (const int*)d_in[27];
  const int* esrc = eidx;
  const int* edst = eidx + EE;

  char* w = (char*)d_ws;
  auto alloc = [&](size_t bytes)->char*{ char* p=w; w += ((bytes+255)/256)*256; return p; };
  _Float16* agg  = (_Float16*)alloc((size_t)NN*256*2);  // 64MiB fp16
  _Float16* g12  = (_Float16*)alloc((size_t)NN*128*2);  // 32MiB fp16 (set2set scratch aliases)
  _Float16* hy   = (_Float16*)alloc((size_t)NN*64*2);   // 16MiB fp16
  int*   deg    = (int*)alloc((size_t)NN*4);
  int*   cursor = (int*)alloc((size_t)NN*4);
  int*   rowptr = (int*)alloc((size_t)(NN+1)*4);
  int*   spart  = (int*)alloc(512*4);
  int*   srcord = (int*)alloc((size_t)EE*4);
  float* eaord  = (float*)alloc((size_t)EE*6*4);
  float* s12   = (float*)alloc((size_t)NN*2*4);
  float* part  = (float*)alloc((size_t)2048*128*4);
  float* bnsc  = (float*)alloc(256);
  float* bnsh  = (float*)alloc(256);
  float* WfG   = (float*)alloc(3*384*4);
  float* bfG   = (float*)alloc(3*64*4);
  _Float16* preW16 = (_Float16*)alloc(36864*2);
  _Float16* poW16  = (_Float16*)alloc(159744*2);
  _Float16* clW16  = (_Float16*)alloc(12288*2);
  int*   gptr  = (int*)alloc((GG+1)*4);
  size_t need = (size_t)(w - (char*)d_ws);
  if (need > ws_size) return;
  float* A    = (float*)g12;
  float* cs   = (float*)g12 + (size_t)GG*128;

  double num = 13107.0*log(2.0)+26214.0*log(3.0)+65536.0*log(4.0)+26215.0*log(5.0);
  float avgdl = (float)(num/131072.0);

  hipMemsetAsync(deg, 0, (size_t)NN*4*2, stream);
  hipLaunchKernelGGL(k_deg, dim3(2048), dim3(256), 0, stream, edst, deg);
  hipLaunchKernelGGL(k_scan_part, dim3(512), dim3(256), 0, stream, deg, spart);
  hipLaunchKernelGGL(k_scan_top, dim3(1), dim3(512), 0, stream, spart);
  hipLaunchKernelGGL(k_scan_apply, dim3(512), dim3(256), 0, stream, deg, spart, rowptr);
  hipLaunchKernelGGL(k_fill, dim3(2048), dim3(256), 0, stream, edst, esrc, ea, rowptr, cursor, srcord, eaord);

  hipLaunchKernelGGL(k_gptr, dim3(17), dim3(256), 0, stream, batch, gptr);
  hipLaunchKernelGGL(k_prepwf, dim3(3), dim3(448), 0, stream, preW, preb, edgeW, edgeb, WfG, bfG);
  hipLaunchKernelGGL(k_prepw16, dim3(817), dim3(256), 0, stream, preW, postW, clinW, preW16, poW16, clW16);
  hipLaunchKernelGGL(k_lin1_s, dim3(1024), dim3(256), 0, stream, x, lin1W, lin1b, hy);

  for (int i = 0; i < 3; ++i){
    const float* sc_i = (i==0)? nullptr : bnsc;
    const float* sh_i = (i==0)? nullptr : bnsh;
    hipLaunchKernelGGL(k_bnmsg, dim3(2048), dim3(256), 0, stream, hy, sc_i, sh_i,
        preW16 + (size_t)i*12288, g12);
    hipLaunchKernelGGL(k_gather_f, dim3(4096), dim3(256), 0, stream, rowptr, srcord, eaord, g12,
        WfG + (size_t)i*384, bfG + (size_t)i*64, agg, s12, avgdl);
    hipLaunchKernelGGL(k_tower_mfma, dim3(2048), dim3(256), 0, stream, hy, agg, s12,
        poW16 + (size_t)i*53248, postb + i*64, clW16 + (size_t)i*4096, clinb + i*64, part);
    hipLaunchKernelGGL(k_bnfin, dim3(1), dim3(1024), 0, stream, part, bng + i*64, bnb + i*64, bnsc, bnsh);
  }
  hipLaunchKernelGGL(k_bnapply16, dim3(2048), dim3(256), 0, stream, hy, bnsc, bnsh);

  hipMemsetAsync(A, 0, (size_t)GG*128*4, stream);
  hipMemsetAsync(cs, 0, (size_t)GG*64*4, stream);
  for (int s = 0; s < 3; ++s){
    hipLaunchKernelGGL(k_lstm_lit, dim3(512), dim3(256), 0, stream, A, cs, Wih, Whh, bih, bhh);
    hipLaunchKernelGGL(k_attn_f, dim3(GG), dim3(64), 0, stream, hy, gptr, A);
  }
  hipLaunchKernelGGL(k_mlp, dim3(GG), dim3(64), 0, stream, A, tt, pp, W1, b1, W2, b2, W3, b3, (float*)d_out);
}

// Round 28
// 539.760 us; speedup vs baseline: 1.5941x; 1.1795x over previous
//
#include <hip/hip_runtime.h>
#include <hip/hip_bf16.h>
#include <math.h>

#define NN 131072
#define EE 524288
#define GG 4096
#define GCAP 320
#define ACAP 96

typedef __attribute__((ext_vector_type(8))) _Float16 half8;
typedef __attribute__((ext_vector_type(4))) _Float16 half4;
typedef __attribute__((ext_vector_type(4))) float f32x4;

__device__ __forceinline__ float sigmoidf_(float x){ return 1.0f/(1.0f+expf(-x)); }

// ---- grouping / CSR (integer atomics only) --------------------------------
__global__ void k_gptr(const int* batch, int* gptr){
  int g = blockIdx.x*256+threadIdx.x;
  if (g > GG) return;
  if (g == GG){ gptr[GG]=NN; return; }
  int lo=0, hi=NN;
  while(lo<hi){ int mid=(lo+hi)>>1; if(batch[mid]<g) lo=mid+1; else hi=mid; }
  gptr[g]=lo;
}

__global__ void k_deg(const int* dst, int* deg){
  int e = blockIdx.x*256+threadIdx.x;
  if(e<EE) atomicAdd(&deg[dst[e]], 1);
}

// hierarchical scan
__global__ __launch_bounds__(256) void k_scan_part(const int* deg, int* part){
  __shared__ int red[256];
  int b=blockIdx.x, t=threadIdx.x;
  red[t] = deg[b*256+t];
  __syncthreads();
  for(int off=128; off>0; off>>=1){
    if(t<off) red[t]+=red[t+off];
    __syncthreads();
  }
  if(t==0) part[b]=red[0];
}

__global__ __launch_bounds__(512) void k_scan_top(int* part){
  __shared__ int s[512];
  int t=threadIdx.x;
  s[t]=part[t];
  __syncthreads();
  for(int off=1; off<512; off<<=1){
    int v=s[t];
    int add=(t>=off)?s[t-off]:0;
    __syncthreads();
    s[t]=v+add;
    __syncthreads();
  }
  part[t] = (t==0)?0:s[t-1];
}

__global__ __launch_bounds__(256) void k_scan_apply(const int* deg, const int* part, int* rowptr){
  __shared__ int s[256];
  int b=blockIdx.x, t=threadIdx.x;
  int v0=deg[b*256+t];
  s[t]=v0;
  __syncthreads();
  for(int off=1; off<256; off<<=1){
    int v=s[t];
    int add=(t>=off)?s[t-off]:0;
    __syncthreads();
    s[t]=v+add;
    __syncthreads();
  }
  rowptr[b*256+t] = part[b] + s[t]-v0;
  if(b==511 && t==255) rowptr[NN] = part[b] + s[t];
}

// fill CSR-ordered edge streams (ea copy vectorized float2)
__global__ void k_fill(const int* dst, const int* src, const float* ea,
                       const int* rowptr, int* cursor, int* srcord, float* eaord){
  int e = blockIdx.x*256+threadIdx.x;
  if(e>=EE) return;
  int d = dst[e];
  int pos = atomicAdd(&cursor[d], 1);
  int idx = rowptr[d]+pos;
  srcord[idx] = src[e];
  float2 e0 = *(const float2*)&ea[(size_t)e*6];
  float2 e1 = *(const float2*)&ea[(size_t)e*6+2];
  float2 e2 = *(const float2*)&ea[(size_t)e*6+4];
  *(float2*)&eaord[(size_t)idx*6]   = e0;
  *(float2*)&eaord[(size_t)idx*6+2] = e1;
  *(float2*)&eaord[(size_t)idx*6+4] = e2;
}

// ---- all-layers Wf/bf precompute (3 blocks) -------------------------------
__global__ __launch_bounds__(448) void k_prepwf(const float* preW, const float* preb,
      const float* eW, const float* eb, float* WfG, float* bfG){
  int i = blockIdx.x;
  const float* pW = preW + (size_t)i*64*192;
  const float* pb = preb + i*64;
  const float* eWl = eW + (size_t)i*384;
  const float* ebl = eb + i*64;
  int t=threadIdx.x;
  if(t<384){
    int j=t/6, d=t-j*6;
    float a=0.0f;
    for(int k=0;k<64;k++) a += pW[(size_t)j*192+128+k]*eWl[k*6+d];
    WfG[i*384+t]=a;
  } else if(t<448){
    int j=t-384;
    float a=pb[j];
    for(int k=0;k<64;k++) a += pW[(size_t)j*192+128+k]*ebl[k];
    bfG[i*64+j]=a;
  }
}

// ---- weights -> fp16 once (bit-identical to per-use conversion) -----------
__global__ void k_prepw16(const float* preW, const float* poW, const float* clW,
                          _Float16* preW16, _Float16* poW16, _Float16* clW16){
  int i = blockIdx.x*256 + threadIdx.x;
  if(i < 36864) preW16[i] = (_Float16)preW[i];
  else if(i < 36864+159744) poW16[i-36864] = (_Float16)poW[i-36864];
  else if(i < 36864+159744+12288) clW16[i-196608] = (_Float16)clW[i-196608];
}

// ---- y0 = x @ lin1W.T + b (pre-activation, fp16); grid-stride, padded sW --
__global__ __launch_bounds__(256) void k_lin1_s(const float* x, const float* W, const float* b, _Float16* y0){
  __shared__ float sW[2112];
  __shared__ float sb[64];
  int t=threadIdx.x;
  for(int i=t;i<2048;i+=256){ int j=i>>5,k=i&31; sW[j*33+k]=W[i]; }
  if(t<64) sb[t]=b[t];
  __syncthreads();
  int w = t>>6, j = t&63;
  for(int it=0; it<32; ++it){
    int n = (blockIdx.x*4 + w) + it*4096;
    float acc = sb[j];
    #pragma unroll 8
    for(int k=0;k<32;k++) acc += x[(size_t)n*32+k]*sW[j*33+k];
    y0[(size_t)n*64+j] = (_Float16)acc;
  }
}

// ---- k_bnmsg: hy := relu(hy*sc+sh) in place; g12 = h @ [Wd|Ws].T (MFMA) ---
__global__ __launch_bounds__(256) void k_bnmsg(_Float16* hy, const float* sc, const float* sh,
      const _Float16* preW16, _Float16* g12){
  __shared__ _Float16 sAh[64][72];
  __shared__ _Float16 sB0[64][72];
  __shared__ _Float16 sB1[64][72];
  __shared__ float ssc[64], ssh[64];
  int t=threadIdx.x;
  int rb = blockIdx.x*64;
  if(t<64){ ssc[t] = sc? sc[t] : 1.0f; ssh[t] = sh? sh[t] : 0.0f; }
  __syncthreads();
  int sr = t>>2, c0 = (t&3)*16;
  {
    half8 y0 = *(const half8*)&hy[(size_t)(rb+sr)*64 + c0];
    half8 y1 = *(const half8*)&hy[(size_t)(rb+sr)*64 + c0 + 8];
    half8 h0, h1;
    #pragma unroll
    for(int q=0;q<8;q++){
      h0[q] = (_Float16)fmaxf((float)y0[q]*ssc[c0+q]   + ssh[c0+q],   0.0f);
      h1[q] = (_Float16)fmaxf((float)y1[q]*ssc[c0+8+q] + ssh[c0+8+q], 0.0f);
    }
    *(half8*)&sAh[sr][c0]   = h0;
    *(half8*)&sAh[sr][c0+8] = h1;
    *(half8*)&hy[(size_t)(rb+sr)*64 + c0]     = h0;
    *(half8*)&hy[(size_t)(rb+sr)*64 + c0 + 8] = h1;
    const _Float16* w0 = &preW16[(size_t)sr*192 + c0];
    const _Float16* w1 = &preW16[(size_t)sr*192 + 64 + c0];
    *(half8*)&sB0[sr][c0]   = *(const half8*)&w0[0];
    *(half8*)&sB0[sr][c0+8] = *(const half8*)&w0[8];
    *(half8*)&sB1[sr][c0]   = *(const half8*)&w1[0];
    *(half8*)&sB1[sr][c0+8] = *(const half8*)&w1[8];
  }
  __syncthreads();
  int w=t>>6, l=t&63;
  f32x4 acc0[4]={}, acc1[4]={};
  #pragma unroll
  for(int kk=0; kk<2; ++kk){
    half8 a = *(const half8*)&sAh[w*16+(l&15)][kk*32+(l>>4)*8];
    #pragma unroll
    for(int n16=0;n16<4;++n16){
      half8 b0 = *(const half8*)&sB0[n16*16+(l&15)][kk*32+(l>>4)*8];
      half8 b1 = *(const half8*)&sB1[n16*16+(l&15)][kk*32+(l>>4)*8];
      acc0[n16] = __builtin_amdgcn_mfma_f32_16x16x32_f16(a,b0,acc0[n16],0,0,0);
      acc1[n16] = __builtin_amdgcn_mfma_f32_16x16x32_f16(a,b1,acc1[n16],0,0,0);
    }
  }
  #pragma unroll
  for(int n16=0;n16<4;++n16){
    #pragma unroll
    for(int reg=0; reg<4; ++reg){
      int row = w*16+(l>>4)*4+reg;
      int col = n16*16+(l&15);
      g12[(size_t)(rb+row)*128 + col]      = (_Float16)acc0[n16][reg];
      g12[(size_t)(rb+row)*128 + 64 + col] = (_Float16)acc1[n16][reg];
    }
  }
}

// ---- gather: 32 nodes/block; block-level GCAP specialization --------------
__global__ __launch_bounds__(256) void k_gather_f(const int* rowptr, const int* srcord,
      const float* eaord, const _Float16* g12, const float* WfG, const float* bfG,
      _Float16* agg, float* s12, float avgdl){
  __shared__ float sWf[64][6];
  __shared__ float sbf[64];
  __shared__ int   sRow[33];
  __shared__ int   sSrc[GCAP];
  __shared__ float sEA[GCAP][8];
  int t=threadIdx.x;
  int rb = blockIdx.x*32;
  for(int i=t; i<384; i+=256) ((float*)sWf)[i]=WfG[i];
  if(t<64) sbf[t]=bfG[t];
  if(t<33) sRow[t]=rowptr[rb+t];
  __syncthreads();
  int eLo = sRow[0];
  int cnt = sRow[32]-eLo;
  int ccap = (cnt<GCAP)? cnt : GCAP;
  for(int i=t; i<ccap; i+=256) sSrc[i]=srcord[eLo+i];
  for(int i=t; i<ccap; i+=256){
    float2 e0 = *(const float2*)&eaord[(size_t)(eLo+i)*6];
    float2 e1 = *(const float2*)&eaord[(size_t)(eLo+i)*6+2];
    float2 e2 = *(const float2*)&eaord[(size_t)(eLo+i)*6+4];
    *(float2*)&sEA[i][0]=e0;
    *(float2*)&sEA[i][2]=e1;
    *(float2*)&sEA[i][4]=e2;
  }
  __syncthreads();
  int w=t>>6, j=t&63;
  float wf0=sWf[j][0], wf1=sWf[j][1], wf2=sWf[j][2];
  float wf3=sWf[j][3], wf4=sWf[j][4], wf5=sWf[j][5];
  float bfj=sbf[j];
  if(cnt<=GCAP){
    for(int q=0; q<8; ++q){
      int ln = w*8 + q;
      int n  = rb + ln;
      int lo = sRow[ln]-eLo, hi = sRow[ln+1]-eLo;
      float mdst = (float)g12[(size_t)n*128+j] + bfj;
      float sum=0.0f, sq=0.0f, mn=1e30f, mx=-1e30f;
      int r=lo;
      for(; r+1<hi; r+=2){
        int s0=sSrc[r], s1=sSrc[r+1];
        float4 va = *(const float4*)&sEA[r][0];
        float2 vb = *(const float2*)&sEA[r][4];
        float4 wa = *(const float4*)&sEA[r+1][0];
        float2 wb = *(const float2*)&sEA[r+1][4];
        float g0 = (float)g12[(size_t)s0*128+64+j];
        float g1 = (float)g12[(size_t)s1*128+64+j];
        float m0 = mdst + g0 + va.x*wf0 + va.y*wf1 + va.z*wf2 + va.w*wf3 + vb.x*wf4 + vb.y*wf5;
        float m1 = mdst + g1 + wa.x*wf0 + wa.y*wf1 + wa.z*wf2 + wa.w*wf3 + wb.x*wf4 + wb.y*wf5;
        sum += m0; sq += m0*m0; mn = fminf(mn,m0); mx = fmaxf(mx,m0);
        sum += m1; sq += m1*m1; mn = fminf(mn,m1); mx = fmaxf(mx,m1);
      }
      if(r<hi){
        int s0=sSrc[r];
        float4 va = *(const float4*)&sEA[r][0];
        float2 vb = *(const float2*)&sEA[r][4];
        float g0 = (float)g12[(size_t)s0*128+64+j];
        float m0 = mdst + g0 + va.x*wf0 + va.y*wf1 + va.z*wf2 + va.w*wf3 + vb.x*wf4 + vb.y*wf5;
        sum += m0; sq += m0*m0; mn = fminf(mn,m0); mx = fmaxf(mx,m0);
      }
      int c = hi-lo;
      float cm = fmaxf((float)c, 1.0f);
      float mean = sum/cm;
      float sd = sqrtf(fmaxf(sq/cm - mean*mean, 0.0f)+1e-5f);
      bool has = c>0;
      size_t base = (size_t)n*256;
      agg[base+j]     = (_Float16)mean;
      agg[base+64+j]  = (_Float16)(has?mn:0.0f);
      agg[base+128+j] = (_Float16)(has?mx:0.0f);
      agg[base+192+j] = (_Float16)sd;
      if(j==0){ float ld=logf(cm+1.0f); s12[n*2]=ld/avgdl; s12[n*2+1]=avgdl/ld; }
    }
  } else {
    for(int q=0; q<8; ++q){
      int ln = w*8 + q;
      int n  = rb + ln;
      int lo = sRow[ln], hi = sRow[ln+1];
      float mdst = (float)g12[(size_t)n*128+j] + bfj;
      float sum=0.0f, sq=0.0f, mn=1e30f, mx=-1e30f;
      int idx=lo;
      for(; idx+1<hi; idx+=2){
        int r0 = idx-eLo, r1 = r0+1;
        int s0, s1;
        float e00,e01,e02,e03,e04,e05, e10,e11,e12,e13,e14,e15;
        if(r1 < GCAP){
          s0=sSrc[r0]; s1=sSrc[r1];
          float4 va = *(const float4*)&sEA[r0][0];
          float2 vb = *(const float2*)&sEA[r0][4];
          float4 wa = *(const float4*)&sEA[r1][0];
          float2 wb = *(const float2*)&sEA[r1][4];
          e00=va.x; e01=va.y; e02=va.z; e03=va.w; e04=vb.x; e05=vb.y;
          e10=wa.x; e11=wa.y; e12=wa.z; e13=wa.w; e14=wb.x; e15=wb.y;
        } else {
          s0=srcord[idx]; s1=srcord[idx+1];
          e00=eaord[(size_t)idx*6+0]; e01=eaord[(size_t)idx*6+1]; e02=eaord[(size_t)idx*6+2];
          e03=eaord[(size_t)idx*6+3]; e04=eaord[(size_t)idx*6+4]; e05=eaord[(size_t)idx*6+5];
          e10=eaord[(size_t)(idx+1)*6+0]; e11=eaord[(size_t)(idx+1)*6+1]; e12=eaord[(size_t)(idx+1)*6+2];
          e13=eaord[(size_t)(idx+1)*6+3]; e14=eaord[(size_t)(idx+1)*6+4]; e15=eaord[(size_t)(idx+1)*6+5];
        }
        float g0 = (float)g12[(size_t)s0*128+64+j];
        float g1 = (float)g12[(size_t)s1*128+64+j];
        float m0 = mdst + g0 + e00*wf0 + e01*wf1 + e02*wf2 + e03*wf3 + e04*wf4 + e05*wf5;
        float m1 = mdst + g1 + e10*wf0 + e11*wf1 + e12*wf2 + e13*wf3 + e14*wf4 + e15*wf5;
        sum += m0; sq += m0*m0; mn = fminf(mn,m0); mx = fmaxf(mx,m0);
        sum += m1; sq += m1*m1; mn = fminf(mn,m1); mx = fmaxf(mx,m1);
      }
      if(idx<hi){
        int r0 = idx-eLo;
        int s0; float e00,e01,e02,e03,e04,e05;
        if(r0 < GCAP){
          s0=sSrc[r0];
          float4 va = *(const float4*)&sEA[r0][0];
          float2 vb = *(const float2*)&sEA[r0][4];
          e00=va.x; e01=va.y; e02=va.z; e03=va.w; e04=vb.x; e05=vb.y;
        } else {
          s0=srcord[idx];
          e00=eaord[(size_t)idx*6+0]; e01=eaord[(size_t)idx*6+1]; e02=eaord[(size_t)idx*6+2];
          e03=eaord[(size_t)idx*6+3]; e04=eaord[(size_t)idx*6+4]; e05=eaord[(size_t)idx*6+5];
        }
        float g0 = (float)g12[(size_t)s0*128+64+j];
        float m0 = mdst + g0 + e00*wf0 + e01*wf1 + e02*wf2 + e03*wf3 + e04*wf4 + e05*wf5;
        sum += m0; sq += m0*m0; mn = fminf(mn,m0); mx = fmaxf(mx,m0);
      }
      int c = hi-lo;
      float cm = fmaxf((float)c, 1.0f);
      float mean = sum/cm;
      float sd = sqrtf(fmaxf(sq/cm - mean*mean, 0.0f)+1e-5f);
      bool has = c>0;
      size_t base = (size_t)n*256;
      agg[base+j]     = (_Float16)mean;
      agg[base+64+j]  = (_Float16)(has?mn:0.0f);
      agg[base+128+j] = (_Float16)(has?mx:0.0f);
      agg[base+192+j] = (_Float16)sd;
      if(j==0){ float ld=logf(cm+1.0f); s12[n*2]=ld/avgdl; s12[n*2+1]=avgdl/ld; }
    }
  }
}

// ---- k_tower_mfma v3: 3-plane staging (24 MFMA per barrier pair) ----------
__global__ __launch_bounds__(256) void k_tower_mfma(_Float16* hy, const _Float16* agg, const float* s12,
        const _Float16* poW16, const float* pob, const _Float16* clW16, const float* clb, float* part){
  __shared__ _Float16 sAh[64][72];
  __shared__ _Float16 sB0[64][72];
  __shared__ _Float16 sB1[64][72];
  __shared__ _Float16 sB2[64][72];
  __shared__ float sS[128];
  __shared__ float sredS[16][64];
  __shared__ float sredQ[16][64];
  int t = threadIdx.x;
  int rb = blockIdx.x*64;
  int w = t>>6, l = t&63;
  int sr = t>>2, c0 = (t&3)*16;
  if (t < 128) sS[t] = s12[(size_t)(rb+(t>>1))*2 + (t&1)];
  f32x4 hacc[4]={}, z0a[4]={}, z1a[4]={}, z2a[4]={};
  auto stageTo = [&](_Float16 (*dst)[72], const _Float16* wr){
    *(half8*)&dst[sr][c0]   = *(const half8*)&wr[0];
    *(half8*)&dst[sr][c0+8] = *(const half8*)&wr[8];
  };
  auto mfma8 = [&](f32x4* acc, _Float16 (*B)[72]){
    #pragma unroll
    for (int kk=0; kk<2; ++kk){
      half8 a = *(const half8*)&sAh[w*16 + (l&15)][kk*32 + (l>>4)*8];
      #pragma unroll
      for (int n16=0; n16<4; ++n16){
        half8 b = *(const half8*)&B[n16*16 + (l&15)][kk*32 + (l>>4)*8];
        acc[n16] = __builtin_amdgcn_mfma_f32_16x16x32_f16(a, b, acc[n16], 0, 0, 0);
      }
    }
  };
  stageTo(sAh, &hy[(size_t)(rb+sr)*64 + c0]);
  stageTo(sB0, &poW16[(size_t)sr*832 + c0]);
  __syncthreads();
  mfma8(hacc, sB0);
  for (int kt=0; kt<4; ++kt){
    __syncthreads();
    stageTo(sAh, &agg[(size_t)(rb+sr)*256 + kt*64 + c0]);
    stageTo(sB0, &poW16[(size_t)sr*832 + 64 + kt*64 + c0]);
    stageTo(sB1, &poW16[(size_t)sr*832 + 64 + 256 + kt*64 + c0]);
    stageTo(sB2, &poW16[(size_t)sr*832 + 64 + 512 + kt*64 + c0]);
    __syncthreads();
    mfma8(z0a, sB0);
    mfma8(z1a, sB1);
    mfma8(z2a, sB2);
  }
  __syncthreads();
  #pragma unroll
  for (int n16=0; n16<4; ++n16){
    #pragma unroll
    for (int reg=0; reg<4; ++reg){
      int row = w*16 + (l>>4)*4 + reg;
      int col = n16*16 + (l&15);
      float s1v = sS[row*2], s2v = sS[row*2+1];
      float v = hacc[n16][reg] + z0a[n16][reg] + s1v*z1a[n16][reg] + s2v*z2a[n16][reg] + pob[col];
      sAh[row][col] = (_Float16)v;
    }
  }
  stageTo(sB0, &clW16[(size_t)sr*64 + c0]);
  __syncthreads();
  f32x4 cacc[4] = {};
  mfma8(cacc, sB0);
  float cs_[4], cq_[4];
  #pragma unroll
  for (int n16=0; n16<4; ++n16){ cs_[n16]=0.0f; cq_[n16]=0.0f; }
  #pragma unroll
  for (int n16=0; n16<4; ++n16){
    #pragma unroll
    for (int reg=0; reg<4; ++reg){
      int row = w*16 + (l>>4)*4 + reg;
      int col = n16*16 + (l&15);
      float v = cacc[n16][reg] + clb[col];
      hy[(size_t)(rb+row)*64 + col] = (_Float16)v;
      cs_[n16] += v; cq_[n16] += v*v;
    }
  }
  int slot = w*4 + (l>>4);
  #pragma unroll
  for (int n16=0; n16<4; ++n16){
    int col = n16*16 + (l&15);
    sredS[slot][col] = cs_[n16];
    sredQ[slot][col] = cq_[n16];
  }
  __syncthreads();
  if (t < 64){
    float S=0.0f, Q=0.0f;
    #pragma unroll
    for(int q2=0;q2<16;q2++){ S += sredS[q2][t]; Q += sredQ[q2][t]; }
    part[(size_t)blockIdx.x*128 + t]      = S;
    part[(size_t)blockIdx.x*128 + 64 + t] = Q;
  }
}

// ---- BN reduce stage 1: 64 blocks x 128 threads; 32 part-rows each --------
__global__ __launch_bounds__(128) void k_bnred(const float* part, double* part2){
  int b = blockIdx.x, t = threadIdx.x;
  double s = 0.0;
  #pragma unroll 8
  for(int r=0;r<32;r++) s += (double)part[(size_t)(b*32+r)*128 + t];
  part2[(size_t)b*128 + t] = s;
}

// ---- BN finalize: 64 threads, 64 double-rows ------------------------------
__global__ __launch_bounds__(64) void k_bnfin(const double* part2, const float* g, const float* bb,
                                              float* sc, float* sh){
  int c = threadIdx.x;
  double S=0.0, Q=0.0;
  for(int b=0;b<64;b++){
    S += part2[(size_t)b*128 + c];
    Q += part2[(size_t)b*128 + 64 + c];
  }
  double mean = S/(double)NN;
  double var  = Q/(double)NN - mean*mean;
  float scale = g[c] * (float)(1.0/sqrt(var+1e-5));
  sc[c]=scale;
  sh[c]=bb[c] - (float)mean*scale;
}

// ---- final BN apply in place on hy (fp16) ---------------------------------
__global__ void k_bnapply16(_Float16* hy, const float* sc, const float* sh){
  int idx = blockIdx.x*256+threadIdx.x;
  for(int i=idx; i<NN*8; i+=256*2048){
    int c0 = (i&7)*8;
    half8 v = *(const half8*)&hy[(size_t)i*8];
    half8 r;
    #pragma unroll
    for(int q=0;q<8;q++) r[q]=(_Float16)fmaxf((float)v[q]*sc[c0+q]+sh[c0+q],0.0f);
    *(half8*)&hy[(size_t)i*8] = r;
  }
}

// ---- set2set LSTM: 8 graphs/block, float4 weights reused x8, 8 acc chains -
__global__ __launch_bounds__(256) void k_lstm_lit(float* A, float* cs,
      const float* Wih, const float* Whh, const float* bih, const float* bhh){
  __shared__ float sA[8][128];
  __shared__ float sg[8][256];
  int t=threadIdx.x;
  int g0 = blockIdx.x*8;
  for(int i=t;i<1024;i+=256) sA[i>>7][i&127] = A[(size_t)(g0+(i>>7))*128 + (i&127)];
  __syncthreads();
  float bb2 = bih[t]+bhh[t];
  float acc[8];
  #pragma unroll
  for(int g=0;g<8;g++) acc[g]=bb2;
  for(int k=0;k<128;k+=4){
    float4 wv = *(const float4*)&Wih[(size_t)t*128+k];
    #pragma unroll
    for(int g=0;g<8;g++)
      acc[g] += wv.x*sA[g][k] + wv.y*sA[g][k+1] + wv.z*sA[g][k+2] + wv.w*sA[g][k+3];
  }
  for(int k=0;k<64;k+=4){
    float4 wv = *(const float4*)&Whh[(size_t)t*64+k];
    #pragma unroll
    for(int g=0;g<8;g++)
      acc[g] += wv.x*sA[g][k] + wv.y*sA[g][k+1] + wv.z*sA[g][k+2] + wv.w*sA[g][k+3];
  }
  #pragma unroll
  for(int g=0;g<8;g++) sg[g][t]=acc[g];
  __syncthreads();
  for(int i=t;i<512;i+=256){
    int g=i>>6, j=i&63;
    float ig=sg[g][j], fg=sg[g][64+j], gg=sg[g][128+j], og=sg[g][192+j];
    float c = sigmoidf_(fg)*cs[(size_t)(g0+g)*64+j] + sigmoidf_(ig)*tanhf(gg);
    float hv = sigmoidf_(og)*tanhf(c);
    cs[(size_t)(g0+g)*64+j]=c;
    A[(size_t)(g0+g)*128+j]=hv;
  }
}

// ---- fused edot+attn: parallel e-compute (lane i owns node i) -------------
__global__ __launch_bounds__(64) void k_attn_f(const _Float16* h16, const int* gptr, float* A){
  __shared__ _Float16 sH[ACAP][66];
  __shared__ float sE[ACAP];
  __shared__ float saq[64];
  int g=blockIdx.x, j=threadIdx.x;
  int lo=gptr[g], hi=gptr[g+1];
  int cnt=hi-lo;
  if(cnt<=0){ A[(size_t)g*128+64+j]=0.0f; return; }
  float aq = A[(size_t)g*128+j];
  saq[j]=aq;
  if(cnt<=ACAP){
    for(int i=0;i<cnt;++i) sH[i][j] = h16[(size_t)(lo+i)*64+j];
    __syncthreads();
    for(int i=j;i<cnt;i+=64){
      float v=0.0f;
      for(int k=0;k<64;k++) v += (float)sH[i][k]*saq[k];
      sE[i]=v;
    }
    __syncthreads();
    float mx=-1e30f;
    for(int i=j;i<cnt;i+=64) mx=fmaxf(mx,sE[i]);
    #pragma unroll
    for(int m=32;m;m>>=1) mx=fmaxf(mx,__shfl_xor(mx,m,64));
    float s=0.0f;
    for(int i=j;i<cnt;i+=64) s+=expf(sE[i]-mx);
    #pragma unroll
    for(int m=32;m;m>>=1) s+=__shfl_xor(s,m,64);
    float inv=1.0f/(s+1e-16f);
    for(int i=j;i<cnt;i+=64) sE[i]=expf(sE[i]-mx)*inv;
    __syncthreads();
    float r=0.0f;
    for(int i=0;i<cnt;++i) r += sE[i]*(float)sH[i][j];
    A[(size_t)g*128+64+j]=r;
  } else {
    float mx=-1e30f;
    for(int n=lo;n<hi;++n){
      float v=(float)h16[(size_t)n*64+j]*aq;
      #pragma unroll
      for(int m=32;m;m>>=1) v+=__shfl_xor(v,m,64);
      mx=fmaxf(mx,v);
    }
    float s=0.0f;
    for(int n=lo;n<hi;++n){
      float v=(float)h16[(size_t)n*64+j]*aq;
      #pragma unroll
      for(int m=32;m;m>>=1) v+=__shfl_xor(v,m,64);
      s+=expf(v-mx);
    }
    float inv=1.0f/(s+1e-16f);
    float r=0.0f;
    for(int n=lo;n<hi;++n){
      float v=(float)h16[(size_t)n*64+j]*aq;
      #pragma unroll
      for(int m=32;m;m>>=1) v+=__shfl_xor(v,m,64);
      r+=expf(v-mx)*inv*(float)h16[(size_t)n*64+j];
    }
    A[(size_t)g*128+64+j]=r;
  }
}

__global__ __launch_bounds__(64) void k_mlp(const float* A, const float* tt, const float* pp,
     const float* W1,const float* b1,const float* W2,const float* b2,const float* W3,const float* b3,
     float* out){
  __shared__ float si[130]; __shared__ float o1[64]; __shared__ float o2[32];
  int g=blockIdx.x, t=threadIdx.x;
  si[t]=A[g*128+t]; si[64+t]=A[g*128+64+t];
  if(t==0){ si[128]=tt[g]; si[129]=pp[g]; }
  __syncthreads();
  float a=b1[t];
  for(int k=0;k<130;k++) a+=W1[t*130+k]*si[k];
  o1[t]=fmaxf(a,0.0f);
  __syncthreads();
  if(t<32){
    float a2=b2[t];
    #pragma unroll 4
    for(int k=0;k<64;k++) a2+=W2[t*64+k]*o1[k];
    o2[t]=fmaxf(a2,0.0f);
  }
  __syncthreads();
  float v = (t<32)? o2[t]*W3[t] : 0.0f;
  #pragma unroll
  for(int m=32;m;m>>=1) v+=__shfl_xor(v,m,64);
  if(t==0) out[g]=v+b3[0];
}

// ---- host -----------------------------------------------------------------
extern "C" void kernel_launch(void* const* d_in, const int* in_sizes, int n_in,
                              void* d_out, int out_size, void* d_ws, size_t ws_size,
                              hipStream_t stream) {
  static const int want[28] = {4194304,3145728,4096,4096,2048,64,1152,192,36864,192,
                               159744,192,12288,192,192,192,32768,16384,256,256,
                               8320,64,2048,32,32,1,1048576,131072};
  if (n_in != 28 || out_size != GG) return;
  for (int i=0;i<28;i++) if (in_sizes[i] != want[i]) return;

  const float* x     = (const float*)d_in[0];
  const float* ea    = (const float*)d_in[1];
  const float* tt    = (const float*)d_in[2];
  const float* pp    = (const float*)d_in[3];
  const float* lin1W = (const float*)d_in[4];
  const float* lin1b = (const float*)d_in[5];
  const float* edgeW = (const float*)d_in[6];
  const float* edgeb = (const float*)d_in[7];
  const float* preW  = (const float*)d_in[8];
  const float* preb  = (const float*)d_in[9];
  const float* postW = (const float*)d_in[10];
  const float* postb = (const float*)d_in[11];
  const float* clinW = (const float*)d_in[12];
  const float* clinb = (const float*)d_in[13];
  const float* bng   = (const float*)d_in[14];
  const float* bnb   = (const float*)d_in[15];
  const float* Wih   = (const float*)d_in[16];
  const float* Whh   = (const float*)d_in[17];
  const float* bih   = (const float*)d_in[18];
  const float* bhh   = (const float*)d_in[19];
  const float* W1    = (const float*)d_in[20];
  const float* b1    = (const float*)d_in[21];
  const float* W2    = (const float*)d_in[22];
  const float* b2    = (const float*)d_in[23];
  const float* W3    = (const float*)d_in[24];
  const float* b3    = (const float*)d_in[25];
  const int*   eidx  = (const int*)d_in[26];
  const int*   batch = (const int*)d_in[27];
  const int* esrc = eidx;
  const int* edst = eidx + EE;

  char* w = (char*)d_ws;
  auto alloc = [&](size_t bytes)->char*{ char* p=w; w += ((bytes+255)/256)*256; return p; };
  _Float16* agg  = (_Float16*)alloc((size_t)NN*256*2);  // 64MiB fp16
  _Float16* g12  = (_Float16*)alloc((size_t)NN*128*2);  // 32MiB fp16 (set2set scratch aliases)
  _Float16* hy   = (_Float16*)alloc((size_t)NN*64*2);   // 16MiB fp16
  int*   deg    = (int*)alloc((size_t)NN*4);
  int*   cursor = (int*)alloc((size_t)NN*4);
  int*   rowptr = (int*)alloc((size_t)(NN+1)*4);
  int*   spart  = (int*)alloc(512*4);
  int*   srcord = (int*)alloc((size_t)EE*4);
  float* eaord  = (float*)alloc((size_t)EE*6*4);
  float* s12   = (float*)alloc((size_t)NN*2*4);
  float* part  = (float*)alloc((size_t)2048*128*4);
  double* part2 = (double*)alloc((size_t)64*128*8);
  float* bnsc  = (float*)alloc(256);
  float* bnsh  = (float*)alloc(256);
  float* WfG   = (float*)alloc(3*384*4);
  float* bfG   = (float*)alloc(3*64*4);
  _Float16* preW16 = (_Float16*)alloc(36864*2);
  _Float16* poW16  = (_Float16*)alloc(159744*2);
  _Float16* clW16  = (_Float16*)alloc(12288*2);
  int*   gptr  = (int*)alloc((GG+1)*4);
  size_t need = (size_t)(w - (char*)d_ws);
  if (need > ws_size) return;
  float* A    = (float*)g12;
  float* cs   = (float*)g12 + (size_t)GG*128;

  double num = 13107.0*log(2.0)+26214.0*log(3.0)+65536.0*log(4.0)+26215.0*log(5.0);
  float avgdl = (float)(num/131072.0);

  hipMemsetAsync(deg, 0, (size_t)NN*4*2, stream);
  hipLaunchKernelGGL(k_deg, dim3(2048), dim3(256), 0, stream, edst, deg);
  hipLaunchKernelGGL(k_scan_part, dim3(512), dim3(256), 0, stream, deg, spart);
  hipLaunchKernelGGL(k_scan_top, dim3(1), dim3(512), 0, stream, spart);
  hipLaunchKernelGGL(k_scan_apply, dim3(512), dim3(256), 0, stream, deg, spart, rowptr);
  hipLaunchKernelGGL(k_fill, dim3(2048), dim3(256), 0, stream, edst, esrc, ea, rowptr, cursor, srcord, eaord);

  hipLaunchKernelGGL(k_gptr, dim3(17), dim3(256), 0, stream, batch, gptr);
  hipLaunchKernelGGL(k_prepwf, dim3(3), dim3(448), 0, stream, preW, preb, edgeW, edgeb, WfG, bfG);
  hipLaunchKernelGGL(k_prepw16, dim3(817), dim3(256), 0, stream, preW, postW, clinW, preW16, poW16, clW16);
  hipLaunchKernelGGL(k_lin1_s, dim3(1024), dim3(256), 0, stream, x, lin1W, lin1b, hy);

  for (int i = 0; i < 3; ++i){
    const float* sc_i = (i==0)? nullptr : bnsc;
    const float* sh_i = (i==0)? nullptr : bnsh;
    hipLaunchKernelGGL(k_bnmsg, dim3(2048), dim3(256), 0, stream, hy, sc_i, sh_i,
        preW16 + (size_t)i*12288, g12);
    hipLaunchKernelGGL(k_gather_f, dim3(4096), dim3(256), 0, stream, rowptr, srcord, eaord, g12,
        WfG + (size_t)i*384, bfG + (size_t)i*64, agg, s12, avgdl);
    hipLaunchKernelGGL(k_tower_mfma, dim3(2048), dim3(256), 0, stream, hy, agg, s12,
        poW16 + (size_t)i*53248, postb + i*64, clW16 + (size_t)i*4096, clinb + i*64, part);
    hipLaunchKernelGGL(k_bnred, dim3(64), dim3(128), 0, stream, part, part2);
    hipLaunchKernelGGL(k_bnfin, dim3(1), dim3(64), 0, stream, part2, bng + i*64, bnb + i*64, bnsc, bnsh);
  }
  hipLaunchKernelGGL(k_bnapply16, dim3(2048), dim3(256), 0, stream, hy, bnsc, bnsh);

  hipMemsetAsync(A, 0, (size_t)GG*128*4, stream);
  hipMemsetAsync(cs, 0, (size_t)GG*64*4, stream);
  for (int s = 0; s < 3; ++s){
    hipLaunchKernelGGL(k_lstm_lit, dim3(512), dim3(256), 0, stream, A, cs, Wih, Whh, bih, bhh);
    hipLaunchKernelGGL(k_attn_f, dim3(GG), dim3(64), 0, stream, hy, gptr, A);
  }
  hipLaunchKernelGGL(k_mlp, dim3(GG), dim3(64), 0, stream, A, tt, pp, W1, b1, W2, b2, W3, b3, (float*)d_out);
}

// Round 29
// 534.157 us; speedup vs baseline: 1.6108x; 1.0105x over previous
//
#include <hip/hip_runtime.h>
#include <hip/hip_bf16.h>
#include <math.h>

#define NN 131072
#define EE 524288
#define GG 4096
#define GCAP 192
#define ACAP 96

typedef __attribute__((ext_vector_type(8))) _Float16 half8;
typedef __attribute__((ext_vector_type(4))) _Float16 half4;
typedef __attribute__((ext_vector_type(4))) float f32x4;

__device__ __forceinline__ float sigmoidf_(float x){ return 1.0f/(1.0f+expf(-x)); }

// ---- grouping / CSR (integer atomics only) --------------------------------
__global__ void k_gptr(const int* batch, int* gptr){
  int g = blockIdx.x*256+threadIdx.x;
  if (g > GG) return;
  if (g == GG){ gptr[GG]=NN; return; }
  int lo=0, hi=NN;
  while(lo<hi){ int mid=(lo+hi)>>1; if(batch[mid]<g) lo=mid+1; else hi=mid; }
  gptr[g]=lo;
}

__global__ void k_deg(const int* dst, int* deg){
  int e = blockIdx.x*256+threadIdx.x;
  if(e<EE) atomicAdd(&deg[dst[e]], 1);
}

// hierarchical scan
__global__ __launch_bounds__(256) void k_scan_part(const int* deg, int* part){
  __shared__ int red[256];
  int b=blockIdx.x, t=threadIdx.x;
  red[t] = deg[b*256+t];
  __syncthreads();
  for(int off=128; off>0; off>>=1){
    if(t<off) red[t]+=red[t+off];
    __syncthreads();
  }
  if(t==0) part[b]=red[0];
}

__global__ __launch_bounds__(512) void k_scan_top(int* part){
  __shared__ int s[512];
  int t=threadIdx.x;
  s[t]=part[t];
  __syncthreads();
  for(int off=1; off<512; off<<=1){
    int v=s[t];
    int add=(t>=off)?s[t-off]:0;
    __syncthreads();
    s[t]=v+add;
    __syncthreads();
  }
  part[t] = (t==0)?0:s[t-1];
}

__global__ __launch_bounds__(256) void k_scan_apply(const int* deg, const int* part, int* rowptr){
  __shared__ int s[256];
  int b=blockIdx.x, t=threadIdx.x;
  int v0=deg[b*256+t];
  s[t]=v0;
  __syncthreads();
  for(int off=1; off<256; off<<=1){
    int v=s[t];
    int add=(t>=off)?s[t-off]:0;
    __syncthreads();
    s[t]=v+add;
    __syncthreads();
  }
  rowptr[b*256+t] = part[b] + s[t]-v0;
  if(b==511 && t==255) rowptr[NN] = part[b] + s[t];
}

// fill CSR-ordered edge streams (ea copy vectorized float2)
__global__ void k_fill(const int* dst, const int* src, const float* ea,
                       const int* rowptr, int* cursor, int* srcord, float* eaord){
  int e = blockIdx.x*256+threadIdx.x;
  if(e>=EE) return;
  int d = dst[e];
  int pos = atomicAdd(&cursor[d], 1);
  int idx = rowptr[d]+pos;
  srcord[idx] = src[e];
  float2 e0 = *(const float2*)&ea[(size_t)e*6];
  float2 e1 = *(const float2*)&ea[(size_t)e*6+2];
  float2 e2 = *(const float2*)&ea[(size_t)e*6+4];
  *(float2*)&eaord[(size_t)idx*6]   = e0;
  *(float2*)&eaord[(size_t)idx*6+2] = e1;
  *(float2*)&eaord[(size_t)idx*6+4] = e2;
}

// ---- all-layers Wf/bf precompute (3 blocks) -------------------------------
__global__ __launch_bounds__(448) void k_prepwf(const float* preW, const float* preb,
      const float* eW, const float* eb, float* WfG, float* bfG){
  int i = blockIdx.x;
  const float* pW = preW + (size_t)i*64*192;
  const float* pb = preb + i*64;
  const float* eWl = eW + (size_t)i*384;
  const float* ebl = eb + i*64;
  int t=threadIdx.x;
  if(t<384){
    int j=t/6, d=t-j*6;
    float a=0.0f;
    for(int k=0;k<64;k++) a += pW[(size_t)j*192+128+k]*eWl[k*6+d];
    WfG[i*384+t]=a;
  } else if(t<448){
    int j=t-384;
    float a=pb[j];
    for(int k=0;k<64;k++) a += pW[(size_t)j*192+128+k]*ebl[k];
    bfG[i*64+j]=a;
  }
}

// ---- weights -> fp16 once (bit-identical to per-use conversion) -----------
__global__ void k_prepw16(const float* preW, const float* poW, const float* clW,
                          _Float16* preW16, _Float16* poW16, _Float16* clW16){
  int i = blockIdx.x*256 + threadIdx.x;
  if(i < 36864) preW16[i] = (_Float16)preW[i];
  else if(i < 36864+159744) poW16[i-36864] = (_Float16)poW[i-36864];
  else if(i < 36864+159744+12288) clW16[i-196608] = (_Float16)clW[i-196608];
}

// ---- y0 = x @ lin1W.T + b (pre-activation, fp16); grid-stride, padded sW --
__global__ __launch_bounds__(256) void k_lin1_s(const float* x, const float* W, const float* b, _Float16* y0){
  __shared__ float sW[2112];
  __shared__ float sb[64];
  int t=threadIdx.x;
  for(int i=t;i<2048;i+=256){ int j=i>>5,k=i&31; sW[j*33+k]=W[i]; }
  if(t<64) sb[t]=b[t];
  __syncthreads();
  int w = t>>6, j = t&63;
  for(int it=0; it<32; ++it){
    int n = (blockIdx.x*4 + w) + it*4096;
    float acc = sb[j];
    #pragma unroll 8
    for(int k=0;k<32;k++) acc += x[(size_t)n*32+k]*sW[j*33+k];
    y0[(size_t)n*64+j] = (_Float16)acc;
  }
}

// ---- k_bnmsg: hy := relu(hy*sc+sh) in place; g12 = h @ [Wd|Ws].T (MFMA) ---
__global__ __launch_bounds__(256) void k_bnmsg(_Float16* hy, const float* sc, const float* sh,
      const _Float16* preW16, _Float16* g12){
  __shared__ _Float16 sAh[64][72];
  __shared__ _Float16 sB0[64][72];
  __shared__ _Float16 sB1[64][72];
  __shared__ float ssc[64], ssh[64];
  int t=threadIdx.x;
  int rb = blockIdx.x*64;
  if(t<64){ ssc[t] = sc? sc[t] : 1.0f; ssh[t] = sh? sh[t] : 0.0f; }
  __syncthreads();
  int sr = t>>2, c0 = (t&3)*16;
  {
    half8 y0 = *(const half8*)&hy[(size_t)(rb+sr)*64 + c0];
    half8 y1 = *(const half8*)&hy[(size_t)(rb+sr)*64 + c0 + 8];
    half8 h0, h1;
    #pragma unroll
    for(int q=0;q<8;q++){
      h0[q] = (_Float16)fmaxf((float)y0[q]*ssc[c0+q]   + ssh[c0+q],   0.0f);
      h1[q] = (_Float16)fmaxf((float)y1[q]*ssc[c0+8+q] + ssh[c0+8+q], 0.0f);
    }
    *(half8*)&sAh[sr][c0]   = h0;
    *(half8*)&sAh[sr][c0+8] = h1;
    *(half8*)&hy[(size_t)(rb+sr)*64 + c0]     = h0;
    *(half8*)&hy[(size_t)(rb+sr)*64 + c0 + 8] = h1;
    const _Float16* w0 = &preW16[(size_t)sr*192 + c0];
    const _Float16* w1 = &preW16[(size_t)sr*192 + 64 + c0];
    *(half8*)&sB0[sr][c0]   = *(const half8*)&w0[0];
    *(half8*)&sB0[sr][c0+8] = *(const half8*)&w0[8];
    *(half8*)&sB1[sr][c0]   = *(const half8*)&w1[0];
    *(half8*)&sB1[sr][c0+8] = *(const half8*)&w1[8];
  }
  __syncthreads();
  int w=t>>6, l=t&63;
  f32x4 acc0[4]={}, acc1[4]={};
  #pragma unroll
  for(int kk=0; kk<2; ++kk){
    half8 a = *(const half8*)&sAh[w*16+(l&15)][kk*32+(l>>4)*8];
    #pragma unroll
    for(int n16=0;n16<4;++n16){
      half8 b0 = *(const half8*)&sB0[n16*16+(l&15)][kk*32+(l>>4)*8];
      half8 b1 = *(const half8*)&sB1[n16*16+(l&15)][kk*32+(l>>4)*8];
      acc0[n16] = __builtin_amdgcn_mfma_f32_16x16x32_f16(a,b0,acc0[n16],0,0,0);
      acc1[n16] = __builtin_amdgcn_mfma_f32_16x16x32_f16(a,b1,acc1[n16],0,0,0);
    }
  }
  #pragma unroll
  for(int n16=0;n16<4;++n16){
    #pragma unroll
    for(int reg=0; reg<4; ++reg){
      int row = w*16+(l>>4)*4+reg;
      int col = n16*16+(l&15);
      g12[(size_t)(rb+row)*128 + col]      = (_Float16)acc0[n16][reg];
      g12[(size_t)(rb+row)*128 + 64 + col] = (_Float16)acc1[n16][reg];
    }
  }
}

// ---- gather: 16 nodes/block (8192 blocks); block-level GCAP special. ------
__global__ __launch_bounds__(256) void k_gather_f(const int* rowptr, const int* srcord,
      const float* eaord, const _Float16* g12, const float* WfG, const float* bfG,
      _Float16* agg, float* s12, float avgdl){
  __shared__ float sWf[64][6];
  __shared__ float sbf[64];
  __shared__ int   sRow[17];
  __shared__ int   sSrc[GCAP];
  __shared__ float sEA[GCAP][8];
  int t=threadIdx.x;
  int rb = blockIdx.x*16;
  for(int i=t; i<384; i+=256) ((float*)sWf)[i]=WfG[i];
  if(t<64) sbf[t]=bfG[t];
  if(t<17) sRow[t]=rowptr[rb+t];
  __syncthreads();
  int eLo = sRow[0];
  int cnt = sRow[16]-eLo;
  int ccap = (cnt<GCAP)? cnt : GCAP;
  for(int i=t; i<ccap; i+=256) sSrc[i]=srcord[eLo+i];
  for(int i=t; i<ccap; i+=256){
    float2 e0 = *(const float2*)&eaord[(size_t)(eLo+i)*6];
    float2 e1 = *(const float2*)&eaord[(size_t)(eLo+i)*6+2];
    float2 e2 = *(const float2*)&eaord[(size_t)(eLo+i)*6+4];
    *(float2*)&sEA[i][0]=e0;
    *(float2*)&sEA[i][2]=e1;
    *(float2*)&sEA[i][4]=e2;
  }
  __syncthreads();
  int w=t>>6, j=t&63;
  float wf0=sWf[j][0], wf1=sWf[j][1], wf2=sWf[j][2];
  float wf3=sWf[j][3], wf4=sWf[j][4], wf5=sWf[j][5];
  float bfj=sbf[j];
  if(cnt<=GCAP){
    for(int q=0; q<4; ++q){
      int ln = w*4 + q;
      int n  = rb + ln;
      int lo = sRow[ln]-eLo, hi = sRow[ln+1]-eLo;
      float mdst = (float)g12[(size_t)n*128+j] + bfj;
      float sum=0.0f, sq=0.0f, mn=1e30f, mx=-1e30f;
      int r=lo;
      for(; r+1<hi; r+=2){
        int s0=sSrc[r], s1=sSrc[r+1];
        float4 va = *(const float4*)&sEA[r][0];
        float2 vb = *(const float2*)&sEA[r][4];
        float4 wa = *(const float4*)&sEA[r+1][0];
        float2 wb = *(const float2*)&sEA[r+1][4];
        float g0 = (float)g12[(size_t)s0*128+64+j];
        float g1 = (float)g12[(size_t)s1*128+64+j];
        float m0 = mdst + g0 + va.x*wf0 + va.y*wf1 + va.z*wf2 + va.w*wf3 + vb.x*wf4 + vb.y*wf5;
        float m1 = mdst + g1 + wa.x*wf0 + wa.y*wf1 + wa.z*wf2 + wa.w*wf3 + wb.x*wf4 + wb.y*wf5;
        sum += m0; sq += m0*m0; mn = fminf(mn,m0); mx = fmaxf(mx,m0);
        sum += m1; sq += m1*m1; mn = fminf(mn,m1); mx = fmaxf(mx,m1);
      }
      if(r<hi){
        int s0=sSrc[r];
        float4 va = *(const float4*)&sEA[r][0];
        float2 vb = *(const float2*)&sEA[r][4];
        float g0 = (float)g12[(size_t)s0*128+64+j];
        float m0 = mdst + g0 + va.x*wf0 + va.y*wf1 + va.z*wf2 + va.w*wf3 + vb.x*wf4 + vb.y*wf5;
        sum += m0; sq += m0*m0; mn = fminf(mn,m0); mx = fmaxf(mx,m0);
      }
      int c = hi-lo;
      float cm = fmaxf((float)c, 1.0f);
      float mean = sum/cm;
      float sd = sqrtf(fmaxf(sq/cm - mean*mean, 0.0f)+1e-5f);
      bool has = c>0;
      size_t base = (size_t)n*256;
      agg[base+j]     = (_Float16)mean;
      agg[base+64+j]  = (_Float16)(has?mn:0.0f);
      agg[base+128+j] = (_Float16)(has?mx:0.0f);
      agg[base+192+j] = (_Float16)sd;
      if(j==0){ float ld=logf(cm+1.0f); s12[n*2]=ld/avgdl; s12[n*2+1]=avgdl/ld; }
    }
  } else {
    for(int q=0; q<4; ++q){
      int ln = w*4 + q;
      int n  = rb + ln;
      int lo = sRow[ln], hi = sRow[ln+1];
      float mdst = (float)g12[(size_t)n*128+j] + bfj;
      float sum=0.0f, sq=0.0f, mn=1e30f, mx=-1e30f;
      int idx=lo;
      for(; idx+1<hi; idx+=2){
        int r0 = idx-eLo, r1 = r0+1;
        int s0, s1;
        float e00,e01,e02,e03,e04,e05, e10,e11,e12,e13,e14,e15;
        if(r1 < GCAP){
          s0=sSrc[r0]; s1=sSrc[r1];
          float4 va = *(const float4*)&sEA[r0][0];
          float2 vb = *(const float2*)&sEA[r0][4];
          float4 wa = *(const float4*)&sEA[r1][0];
          float2 wb = *(const float2*)&sEA[r1][4];
          e00=va.x; e01=va.y; e02=va.z; e03=va.w; e04=vb.x; e05=vb.y;
          e10=wa.x; e11=wa.y; e12=wa.z; e13=wa.w; e14=wb.x; e15=wb.y;
        } else {
          s0=srcord[idx]; s1=srcord[idx+1];
          e00=eaord[(size_t)idx*6+0]; e01=eaord[(size_t)idx*6+1]; e02=eaord[(size_t)idx*6+2];
          e03=eaord[(size_t)idx*6+3]; e04=eaord[(size_t)idx*6+4]; e05=eaord[(size_t)idx*6+5];
          e10=eaord[(size_t)(idx+1)*6+0]; e11=eaord[(size_t)(idx+1)*6+1]; e12=eaord[(size_t)(idx+1)*6+2];
          e13=eaord[(size_t)(idx+1)*6+3]; e14=eaord[(size_t)(idx+1)*6+4]; e15=eaord[(size_t)(idx+1)*6+5];
        }
        float g0 = (float)g12[(size_t)s0*128+64+j];
        float g1 = (float)g12[(size_t)s1*128+64+j];
        float m0 = mdst + g0 + e00*wf0 + e01*wf1 + e02*wf2 + e03*wf3 + e04*wf4 + e05*wf5;
        float m1 = mdst + g1 + e10*wf0 + e11*wf1 + e12*wf2 + e13*wf3 + e14*wf4 + e15*wf5;
        sum += m0; sq += m0*m0; mn = fminf(mn,m0); mx = fmaxf(mx,m0);
        sum += m1; sq += m1*m1; mn = fminf(mn,m1); mx = fmaxf(mx,m1);
      }
      if(idx<hi){
        int r0 = idx-eLo;
        int s0; float e00,e01,e02,e03,e04,e05;
        if(r0 < GCAP){
          s0=sSrc[r0];
          float4 va = *(const float4*)&sEA[r0][0];
          float2 vb = *(const float2*)&sEA[r0][4];
          e00=va.x; e01=va.y; e02=va.z; e03=va.w; e04=vb.x; e05=vb.y;
        } else {
          s0=srcord[idx];
          e00=eaord[(size_t)idx*6+0]; e01=eaord[(size_t)idx*6+1]; e02=eaord[(size_t)idx*6+2];
          e03=eaord[(size_t)idx*6+3]; e04=eaord[(size_t)idx*6+4]; e05=eaord[(size_t)idx*6+5];
        }
        float g0 = (float)g12[(size_t)s0*128+64+j];
        float m0 = mdst + g0 + e00*wf0 + e01*wf1 + e02*wf2 + e03*wf3 + e04*wf4 + e05*wf5;
        sum += m0; sq += m0*m0; mn = fminf(mn,m0); mx = fmaxf(mx,m0);
      }
      int c = hi-lo;
      float cm = fmaxf((float)c, 1.0f);
      float mean = sum/cm;
      float sd = sqrtf(fmaxf(sq/cm - mean*mean, 0.0f)+1e-5f);
      bool has = c>0;
      size_t base = (size_t)n*256;
      agg[base+j]     = (_Float16)mean;
      agg[base+64+j]  = (_Float16)(has?mn:0.0f);
      agg[base+128+j] = (_Float16)(has?mx:0.0f);
      agg[base+192+j] = (_Float16)sd;
      if(j==0){ float ld=logf(cm+1.0f); s12[n*2]=ld/avgdl; s12[n*2+1]=avgdl/ld; }
    }
  }
}

// ---- k_tower_mfma v3: 3-plane staging (24 MFMA per barrier pair) ----------
__global__ __launch_bounds__(256) void k_tower_mfma(_Float16* hy, const _Float16* agg, const float* s12,
        const _Float16* poW16, const float* pob, const _Float16* clW16, const float* clb, float* part){
  __shared__ _Float16 sAh[64][72];
  __shared__ _Float16 sB0[64][72];
  __shared__ _Float16 sB1[64][72];
  __shared__ _Float16 sB2[64][72];
  __shared__ float sS[128];
  __shared__ float sredS[16][64];
  __shared__ float sredQ[16][64];
  int t = threadIdx.x;
  int rb = blockIdx.x*64;
  int w = t>>6, l = t&63;
  int sr = t>>2, c0 = (t&3)*16;
  if (t < 128) sS[t] = s12[(size_t)(rb+(t>>1))*2 + (t&1)];
  f32x4 hacc[4]={}, z0a[4]={}, z1a[4]={}, z2a[4]={};
  auto stageTo = [&](_Float16 (*dst)[72], const _Float16* wr){
    *(half8*)&dst[sr][c0]   = *(const half8*)&wr[0];
    *(half8*)&dst[sr][c0+8] = *(const half8*)&wr[8];
  };
  auto mfma8 = [&](f32x4* acc, _Float16 (*B)[72]){
    #pragma unroll
    for (int kk=0; kk<2; ++kk){
      half8 a = *(const half8*)&sAh[w*16 + (l&15)][kk*32 + (l>>4)*8];
      #pragma unroll
      for (int n16=0; n16<4; ++n16){
        half8 b = *(const half8*)&B[n16*16 + (l&15)][kk*32 + (l>>4)*8];
        acc[n16] = __builtin_amdgcn_mfma_f32_16x16x32_f16(a, b, acc[n16], 0, 0, 0);
      }
    }
  };
  stageTo(sAh, &hy[(size_t)(rb+sr)*64 + c0]);
  stageTo(sB0, &poW16[(size_t)sr*832 + c0]);
  __syncthreads();
  mfma8(hacc, sB0);
  for (int kt=0; kt<4; ++kt){
    __syncthreads();
    stageTo(sAh, &agg[(size_t)(rb+sr)*256 + kt*64 + c0]);
    stageTo(sB0, &poW16[(size_t)sr*832 + 64 + kt*64 + c0]);
    stageTo(sB1, &poW16[(size_t)sr*832 + 64 + 256 + kt*64 + c0]);
    stageTo(sB2, &poW16[(size_t)sr*832 + 64 + 512 + kt*64 + c0]);
    __syncthreads();
    mfma8(z0a, sB0);
    mfma8(z1a, sB1);
    mfma8(z2a, sB2);
  }
  __syncthreads();
  #pragma unroll
  for (int n16=0; n16<4; ++n16){
    #pragma unroll
    for (int reg=0; reg<4; ++reg){
      int row = w*16 + (l>>4)*4 + reg;
      int col = n16*16 + (l&15);
      float s1v = sS[row*2], s2v = sS[row*2+1];
      float v = hacc[n16][reg] + z0a[n16][reg] + s1v*z1a[n16][reg] + s2v*z2a[n16][reg] + pob[col];
      sAh[row][col] = (_Float16)v;
    }
  }
  stageTo(sB0, &clW16[(size_t)sr*64 + c0]);
  __syncthreads();
  f32x4 cacc[4] = {};
  mfma8(cacc, sB0);
  float cs_[4], cq_[4];
  #pragma unroll
  for (int n16=0; n16<4; ++n16){ cs_[n16]=0.0f; cq_[n16]=0.0f; }
  #pragma unroll
  for (int n16=0; n16<4; ++n16){
    #pragma unroll
    for (int reg=0; reg<4; ++reg){
      int row = w*16 + (l>>4)*4 + reg;
      int col = n16*16 + (l&15);
      float v = cacc[n16][reg] + clb[col];
      hy[(size_t)(rb+row)*64 + col] = (_Float16)v;
      cs_[n16] += v; cq_[n16] += v*v;
    }
  }
  int slot = w*4 + (l>>4);
  #pragma unroll
  for (int n16=0; n16<4; ++n16){
    int col = n16*16 + (l&15);
    sredS[slot][col] = cs_[n16];
    sredQ[slot][col] = cq_[n16];
  }
  __syncthreads();
  if (t < 64){
    float S=0.0f, Q=0.0f;
    #pragma unroll
    for(int q2=0;q2<16;q2++){ S += sredS[q2][t]; Q += sredQ[q2][t]; }
    part[(size_t)blockIdx.x*128 + t]      = S;
    part[(size_t)blockIdx.x*128 + 64 + t] = Q;
  }
}

// ---- BN reduce stage 1: 64 blocks x 128 threads; 32 part-rows each --------
__global__ __launch_bounds__(128) void k_bnred(const float* part, double* part2){
  int b = blockIdx.x, t = threadIdx.x;
  double s = 0.0;
  #pragma unroll 8
  for(int r=0;r<32;r++) s += (double)part[(size_t)(b*32+r)*128 + t];
  part2[(size_t)b*128 + t] = s;
}

// ---- BN finalize: 64 threads, 64 double-rows ------------------------------
__global__ __launch_bounds__(64) void k_bnfin(const double* part2, const float* g, const float* bb,
                                              float* sc, float* sh){
  int c = threadIdx.x;
  double S=0.0, Q=0.0;
  for(int b=0;b<64;b++){
    S += part2[(size_t)b*128 + c];
    Q += part2[(size_t)b*128 + 64 + c];
  }
  double mean = S/(double)NN;
  double var  = Q/(double)NN - mean*mean;
  float scale = g[c] * (float)(1.0/sqrt(var+1e-5));
  sc[c]=scale;
  sh[c]=bb[c] - (float)mean*scale;
}

// ---- final BN apply in place on hy (fp16) ---------------------------------
__global__ void k_bnapply16(_Float16* hy, const float* sc, const float* sh){
  int idx = blockIdx.x*256+threadIdx.x;
  for(int i=idx; i<NN*8; i+=256*2048){
    int c0 = (i&7)*8;
    half8 v = *(const half8*)&hy[(size_t)i*8];
    half8 r;
    #pragma unroll
    for(int q=0;q<8;q++) r[q]=(_Float16)fmaxf((float)v[q]*sc[c0+q]+sh[c0+q],0.0f);
    *(half8*)&hy[(size_t)i*8] = r;
  }
}

// ---- set2set LSTM: 8 graphs/block, float4 weights reused x8, 8 acc chains -
__global__ __launch_bounds__(256) void k_lstm_lit(float* A, float* cs,
      const float* Wih, const float* Whh, const float* bih, const float* bhh){
  __shared__ float sA[8][128];
  __shared__ float sg[8][256];
  int t=threadIdx.x;
  int g0 = blockIdx.x*8;
  for(int i=t;i<1024;i+=256) sA[i>>7][i&127] = A[(size_t)(g0+(i>>7))*128 + (i&127)];
  __syncthreads();
  float bb2 = bih[t]+bhh[t];
  float acc[8];
  #pragma unroll
  for(int g=0;g<8;g++) acc[g]=bb2;
  for(int k=0;k<128;k+=4){
    float4 wv = *(const float4*)&Wih[(size_t)t*128+k];
    #pragma unroll
    for(int g=0;g<8;g++)
      acc[g] += wv.x*sA[g][k] + wv.y*sA[g][k+1] + wv.z*sA[g][k+2] + wv.w*sA[g][k+3];
  }
  for(int k=0;k<64;k+=4){
    float4 wv = *(const float4*)&Whh[(size_t)t*64+k];
    #pragma unroll
    for(int g=0;g<8;g++)
      acc[g] += wv.x*sA[g][k] + wv.y*sA[g][k+1] + wv.z*sA[g][k+2] + wv.w*sA[g][k+3];
  }
  #pragma unroll
  for(int g=0;g<8;g++) sg[g][t]=acc[g];
  __syncthreads();
  for(int i=t;i<512;i+=256){
    int g=i>>6, j=i&63;
    float ig=sg[g][j], fg=sg[g][64+j], gg=sg[g][128+j], og=sg[g][192+j];
    float c = sigmoidf_(fg)*cs[(size_t)(g0+g)*64+j] + sigmoidf_(ig)*tanhf(gg);
    float hv = sigmoidf_(og)*tanhf(c);
    cs[(size_t)(g0+g)*64+j]=c;
    A[(size_t)(g0+g)*128+j]=hv;
  }
}

// ---- fused edot+attn: parallel e-compute (lane i owns node i) -------------
__global__ __launch_bounds__(64) void k_attn_f(const _Float16* h16, const int* gptr, float* A){
  __shared__ _Float16 sH[ACAP][66];
  __shared__ float sE[ACAP];
  __shared__ float saq[64];
  int g=blockIdx.x, j=threadIdx.x;
  int lo=gptr[g], hi=gptr[g+1];
  int cnt=hi-lo;
  if(cnt<=0){ A[(size_t)g*128+64+j]=0.0f; return; }
  float aq = A[(size_t)g*128+j];
  saq[j]=aq;
  if(cnt<=ACAP){
    for(int i=0;i<cnt;++i) sH[i][j] = h16[(size_t)(lo+i)*64+j];
    __syncthreads();
    for(int i=j;i<cnt;i+=64){
      float v=0.0f;
      for(int k=0;k<64;k++) v += (float)sH[i][k]*saq[k];
      sE[i]=v;
    }
    __syncthreads();
    float mx=-1e30f;
    for(int i=j;i<cnt;i+=64) mx=fmaxf(mx,sE[i]);
    #pragma unroll
    for(int m=32;m;m>>=1) mx=fmaxf(mx,__shfl_xor(mx,m,64));
    float s=0.0f;
    for(int i=j;i<cnt;i+=64) s+=expf(sE[i]-mx);
    #pragma unroll
    for(int m=32;m;m>>=1) s+=__shfl_xor(s,m,64);
    float inv=1.0f/(s+1e-16f);
    for(int i=j;i<cnt;i+=64) sE[i]=expf(sE[i]-mx)*inv;
    __syncthreads();
    float r=0.0f;
    for(int i=0;i<cnt;++i) r += sE[i]*(float)sH[i][j];
    A[(size_t)g*128+64+j]=r;
  } else {
    float mx=-1e30f;
    for(int n=lo;n<hi;++n){
      float v=(float)h16[(size_t)n*64+j]*aq;
      #pragma unroll
      for(int m=32;m;m>>=1) v+=__shfl_xor(v,m,64);
      mx=fmaxf(mx,v);
    }
    float s=0.0f;
    for(int n=lo;n<hi;++n){
      float v=(float)h16[(size_t)n*64+j]*aq;
      #pragma unroll
      for(int m=32;m;m>>=1) v+=__shfl_xor(v,m,64);
      s+=expf(v-mx);
    }
    float inv=1.0f/(s+1e-16f);
    float r=0.0f;
    for(int n=lo;n<hi;++n){
      float v=(float)h16[(size_t)n*64+j]*aq;
      #pragma unroll
      for(int m=32;m;m>>=1) v+=__shfl_xor(v,m,64);
      r+=expf(v-mx)*inv*(float)h16[(size_t)n*64+j];
    }
    A[(size_t)g*128+64+j]=r;
  }
}

__global__ __launch_bounds__(64) void k_mlp(const float* A, const float* tt, const float* pp,
     const float* W1,const float* b1,const float* W2,const float* b2,const float* W3,const float* b3,
     float* out){
  __shared__ float si[130]; __shared__ float o1[64]; __shared__ float o2[32];
  int g=blockIdx.x, t=threadIdx.x;
  si[t]=A[g*128+t]; si[64+t]=A[g*128+64+t];
  if(t==0){ si[128]=tt[g]; si[129]=pp[g]; }
  __syncthreads();
  float a=b1[t];
  for(int k=0;k<130;k++) a+=W1[t*130+k]*si[k];
  o1[t]=fmaxf(a,0.0f);
  __syncthreads();
  if(t<32){
    float a2=b2[t];
    #pragma unroll 4
    for(int k=0;k<64;k++) a2+=W2[t*64+k]*o1[k];
    o2[t]=fmaxf(a2,0.0f);
  }
  __syncthreads();
  float v = (t<32)? o2[t]*W3[t] : 0.0f;
  #pragma unroll
  for(int m=32;m;m>>=1) v+=__shfl_xor(v,m,64);
  if(t==0) out[g]=v+b3[0];
}

// ---- host -----------------------------------------------------------------
extern "C" void kernel_launch(void* const* d_in, const int* in_sizes, int n_in,
                              void* d_out, int out_size, void* d_ws, size_t ws_size,
                              hipStream_t stream) {
  static const int want[28] = {4194304,3145728,4096,4096,2048,64,1152,192,36864,192,
                               159744,192,12288,192,192,192,32768,16384,256,256,
                               8320,64,2048,32,32,1,1048576,131072};
  if (n_in != 28 || out_size != GG) return;
  for (int i=0;i<28;i++) if (in_sizes[i] != want[i]) return;

  const float* x     = (const float*)d_in[0];
  const float* ea    = (const float*)d_in[1];
  const float* tt    = (const float*)d_in[2];
  const float* pp    = (const float*)d_in[3];
  const float* lin1W = (const float*)d_in[4];
  const float* lin1b = (const float*)d_in[5];
  const float* edgeW = (const float*)d_in[6];
  const float* edgeb = (const float*)d_in[7];
  const float* preW  = (const float*)d_in[8];
  const float* preb  = (const float*)d_in[9];
  const float* postW = (const float*)d_in[10];
  const float* postb = (const float*)d_in[11];
  const float* clinW = (const float*)d_in[12];
  const float* clinb = (const float*)d_in[13];
  const float* bng   = (const float*)d_in[14];
  const float* bnb   = (const float*)d_in[15];
  const float* Wih   = (const float*)d_in[16];
  const float* Whh   = (const float*)d_in[17];
  const float* bih   = (const float*)d_in[18];
  const float* bhh   = (const float*)d_in[19];
  const float* W1    = (const float*)d_in[20];
  const float* b1    = (const float*)d_in[21];
  const float* W2    = (const float*)d_in[22];
  const float* b2    = (const float*)d_in[23];
  const float* W3    = (const float*)d_in[24];
  const float* b3    = (const float*)d_in[25];
  const int*   eidx  = (const int*)d_in[26];
  const int*   batch = (const int*)d_in[27];
  const int* esrc = eidx;
  const int* edst = eidx + EE;

  char* w = (char*)d_ws;
  auto alloc = [&](size_t bytes)->char*{ char* p=w; w += ((bytes+255)/256)*256; return p; };
  _Float16* agg  = (_Float16*)alloc((size_t)NN*256*2);  // 64MiB fp16
  _Float16* g12  = (_Float16*)alloc((size_t)NN*128*2);  // 32MiB fp16 (set2set scratch aliases)
  _Float16* hy   = (_Float16*)alloc((size_t)NN*64*2);   // 16MiB fp16
  int*   deg    = (int*)alloc((size_t)NN*4);
  int*   cursor = (int*)alloc((size_t)NN*4);
  int*   rowptr = (int*)alloc((size_t)(NN+1)*4);
  int*   spart  = (int*)alloc(512*4);
  int*   srcord = (int*)alloc((size_t)EE*4);
  float* eaord  = (float*)alloc((size_t)EE*6*4);
  float* s12   = (float*)alloc((size_t)NN*2*4);
  float* part  = (float*)alloc((size_t)2048*128*4);
  double* part2 = (double*)alloc((size_t)64*128*8);
  float* bnsc  = (float*)alloc(256);
  float* bnsh  = (float*)alloc(256);
  float* WfG   = (float*)alloc(3*384*4);
  float* bfG   = (float*)alloc(3*64*4);
  _Float16* preW16 = (_Float16*)alloc(36864*2);
  _Float16* poW16  = (_Float16*)alloc(159744*2);
  _Float16* clW16  = (_Float16*)alloc(12288*2);
  int*   gptr  = (int*)alloc((GG+1)*4);
  size_t need = (size_t)(w - (char*)d_ws);
  if (need > ws_size) return;
  float* A    = (float*)g12;
  float* cs   = (float*)g12 + (size_t)GG*128;

  double num = 13107.0*log(2.0)+26214.0*log(3.0)+65536.0*log(4.0)+26215.0*log(5.0);
  float avgdl = (float)(num/131072.0);

  hipMemsetAsync(deg, 0, (size_t)NN*4*2, stream);
  hipLaunchKernelGGL(k_deg, dim3(2048), dim3(256), 0, stream, edst, deg);
  hipLaunchKernelGGL(k_scan_part, dim3(512), dim3(256), 0, stream, deg, spart);
  hipLaunchKernelGGL(k_scan_top, dim3(1), dim3(512), 0, stream, spart);
  hipLaunchKernelGGL(k_scan_apply, dim3(512), dim3(256), 0, stream, deg, spart, rowptr);
  hipLaunchKernelGGL(k_fill, dim3(2048), dim3(256), 0, stream, edst, esrc, ea, rowptr, cursor, srcord, eaord);

  hipLaunchKernelGGL(k_gptr, dim3(17), dim3(256), 0, stream, batch, gptr);
  hipLaunchKernelGGL(k_prepwf, dim3(3), dim3(448), 0, stream, preW, preb, edgeW, edgeb, WfG, bfG);
  hipLaunchKernelGGL(k_prepw16, dim3(817), dim3(256), 0, stream, preW, postW, clinW, preW16, poW16, clW16);
  hipLaunchKernelGGL(k_lin1_s, dim3(1024), dim3(256), 0, stream, x, lin1W, lin1b, hy);

  for (int i = 0; i < 3; ++i){
    const float* sc_i = (i==0)? nullptr : bnsc;
    const float* sh_i = (i==0)? nullptr : bnsh;
    hipLaunchKernelGGL(k_bnmsg, dim3(2048), dim3(256), 0, stream, hy, sc_i, sh_i,
        preW16 + (size_t)i*12288, g12);
    hipLaunchKernelGGL(k_gather_f, dim3(8192), dim3(256), 0, stream, rowptr, srcord, eaord, g12,
        WfG + (size_t)i*384, bfG + (size_t)i*64, agg, s12, avgdl);
    hipLaunchKernelGGL(k_tower_mfma, dim3(2048), dim3(256), 0, stream, hy, agg, s12,
        poW16 + (size_t)i*53248, postb + i*64, clW16 + (size_t)i*4096, clinb + i*64, part);
    hipLaunchKernelGGL(k_bnred, dim3(64), dim3(128), 0, stream, part, part2);
    hipLaunchKernelGGL(k_bnfin, dim3(1), dim3(64), 0, stream, part2, bng + i*64, bnb + i*64, bnsc, bnsh);
  }
  hipLaunchKernelGGL(k_bnapply16, dim3(2048), dim3(256), 0, stream, hy, bnsc, bnsh);

  hipMemsetAsync(A, 0, (size_t)GG*128*4, stream);
  hipMemsetAsync(cs, 0, (size_t)GG*64*4, stream);
  for (int s = 0; s < 3; ++s){
    hipLaunchKernelGGL(k_lstm_lit, dim3(512), dim3(256), 0, stream, A, cs, Wih, Whh, bih, bhh);
    hipLaunchKernelGGL(k_attn_f, dim3(GG), dim3(64), 0, stream, hy, gptr, A);
  }
  hipLaunchKernelGGL(k_mlp, dim3(GG), dim3(64), 0, stream, A, tt, pp, W1, b1, W2, b2, W3, b3, (float*)d_out);
}